// Round 3
// baseline (1511.127 us; speedup 1.0000x reference)
//
#include <hip/hip_runtime.h>
#include <hip/hip_bf16.h>
#include <cstdint>
#include <cstddef>

// ---------- types & helpers ----------
typedef __attribute__((ext_vector_type(8))) short short8;   // 8 x bf16
typedef __attribute__((ext_vector_type(4))) short short4v;  // 4 x bf16 (8B)
typedef __attribute__((ext_vector_type(4))) float f32x4;

#define DEVINL static __device__ __forceinline__

DEVINL float b2f(unsigned short u) {
    union { unsigned int i; float f; } v; v.i = ((unsigned int)u) << 16; return v.f;
}
DEVINL unsigned short f2b(float f) {
    union { float f; unsigned int i; } v; v.f = f;
    unsigned int x = v.i;
    return (unsigned short)((x + 0x7FFFu + ((x >> 16) & 1u)) >> 16);
}

static constexpr int Bsz = 4, Tn = 1024, Cn = 1024, Hn = 16, Nn = 64;
static constexpr int Mrows = Bsz * Tn;             // 4096
static constexpr size_t MX = (size_t)Mrows * Cn;   // 4,194,304

// ---------- f32 -> bf16 convert (weights) ----------
__global__ __launch_bounds__(256) void k_cvt(const float* __restrict__ in,
                                             unsigned short* __restrict__ out, int n)
{
    int i = (blockIdx.x * 256 + threadIdx.x) * 4;
    if (i < n) {
        f32x4 v = *(const f32x4*)(in + i);
        short4v o;
        #pragma unroll
        for (int j = 0; j < 4; ++j) o[j] = (short)f2b(v[j]);
        *(short4v*)(out + i) = o;
    }
}

// ---------- small-weight transpose + convert ----------
__global__ void k_transpose(const float* __restrict__ in,
                            unsigned short* __restrict__ out, int R, int Cc)
{
    int i = blockIdx.x * 256 + threadIdx.x;
    if (i < R * Cc) {
        int r = i / Cc, c = i % Cc;
        out[(size_t)c * R + r] = f2b(in[i]);
    }
}

// ---------- generic MFMA GEMM: C[M,N] = epi(A[M,K] @ Bt[N,K]^T) ----------
// 4 waves/block, each wave computes a 64x64 tile. Block tile = (WR*64) x (WC*64).
// EPI: 0=raw 1=tanh 2=sigmoid 3=bias+sigmoid 4=bias+decay(exp(-e^-0.5*sigmoid))
// AF32: A operand is f32 (else bf16). AMIX (requires AF32): token-shift mix fused:
//       a[m,k] = x[m,k] + (x[m-1,k]-x[m,k])*mix[k]   (x[m-1]=0 at t==0)
template<int WR, int WC, int EPI, int OUTF32, int AF32, int AMIX>
__global__ __launch_bounds__(256) void gemm_bt(
    const void* __restrict__ Av, int lda,
    const float* __restrict__ mixv,
    const unsigned short* __restrict__ Bt, int ldb,
    float* __restrict__ Cf, unsigned short* __restrict__ Cb, int ldc,
    const float* __restrict__ bias, int N, int K)
{
    const int tid = threadIdx.x;
    const int wid = tid >> 6;
    const int lane = tid & 63;
    const int r16 = lane & 15;
    const int k8 = (lane >> 4) * 8;
    const int m0 = blockIdx.x * (WR * 64) + (wid / WC) * 64;
    const int n0 = blockIdx.y * (WC * 64) + (wid % WC) * 64;

    f32x4 acc[4][4];
    #pragma unroll
    for (int a = 0; a < 4; ++a)
        #pragma unroll
        for (int b = 0; b < 4; ++b) acc[a][b] = (f32x4){0.f, 0.f, 0.f, 0.f};

    for (int k0 = 0; k0 < K; k0 += 32) {
        short8 af[4], bf[4];
        float mxf[8];
        if (AMIX) {
            f32x4 m0v = *(const f32x4*)(mixv + k0 + k8);
            f32x4 m1v = *(const f32x4*)(mixv + k0 + k8 + 4);
            #pragma unroll
            for (int j = 0; j < 4; ++j) { mxf[j] = m0v[j]; mxf[4 + j] = m1v[j]; }
        }
        #pragma unroll
        for (int mi = 0; mi < 4; ++mi) {
            int row = m0 + mi * 16 + r16;
            if (AF32) {
                const float* ap = (const float*)Av + (size_t)row * lda + k0 + k8;
                f32x4 x0 = *(const f32x4*)ap;
                f32x4 x1 = *(const f32x4*)(ap + 4);
                float xf[8];
                #pragma unroll
                for (int j = 0; j < 4; ++j) { xf[j] = x0[j]; xf[4 + j] = x1[j]; }
                if (AMIX) {
                    const bool hasp = (row & (Tn - 1)) != 0;
                    float pf[8];
                    if (hasp) {
                        f32x4 p0 = *(const f32x4*)(ap - lda);
                        f32x4 p1 = *(const f32x4*)(ap - lda + 4);
                        #pragma unroll
                        for (int j = 0; j < 4; ++j) { pf[j] = p0[j]; pf[4 + j] = p1[j]; }
                    } else {
                        #pragma unroll
                        for (int j = 0; j < 8; ++j) pf[j] = 0.f;
                    }
                    #pragma unroll
                    for (int j = 0; j < 8; ++j) xf[j] += (pf[j] - xf[j]) * mxf[j];
                }
                short8 o;
                #pragma unroll
                for (int j = 0; j < 8; ++j) o[j] = (short)f2b(xf[j]);
                af[mi] = o;
            } else {
                af[mi] = *(const short8*)((const unsigned short*)Av + (size_t)row * lda + k0 + k8);
            }
        }
        #pragma unroll
        for (int ni = 0; ni < 4; ++ni) {
            int rn = n0 + ni * 16 + r16;
            if (rn >= N) rn = N - 1;
            bf[ni] = *(const short8*)(Bt + (size_t)rn * ldb + k0 + k8);
        }
        #pragma unroll
        for (int mi = 0; mi < 4; ++mi)
            #pragma unroll
            for (int ni = 0; ni < 4; ++ni)
                acc[mi][ni] = __builtin_amdgcn_mfma_f32_16x16x32_bf16(af[mi], bf[ni], acc[mi][ni], 0, 0, 0);
    }

    #pragma unroll
    for (int mi = 0; mi < 4; ++mi)
        #pragma unroll
        for (int ni = 0; ni < 4; ++ni) {
            int col = n0 + ni * 16 + r16;
            if (col < N) {
                float bv = 0.f;
                if (EPI == 3 || EPI == 4) bv = bias[col];
                #pragma unroll
                for (int r = 0; r < 4; ++r) {
                    int row = m0 + mi * 16 + (lane >> 4) * 4 + r;
                    float v = acc[mi][ni][r];
                    if (EPI == 1) v = tanhf(v);
                    else if (EPI == 2) v = 1.f / (1.f + expf(-v));
                    else if (EPI == 3) { v += bv; v = 1.f / (1.f + expf(-v)); }
                    else if (EPI == 4) { v += bv; v = expf(-0.60653066f / (1.f + expf(-v))); }
                    size_t o = (size_t)row * ldc + col;
                    if (OUTF32) Cf[o] = v; else Cb[o] = f2b(v);
                }
            }
        }
}

// ---------- elementwise stage 1 (bf16 buffers in place; vfirst f32) ----------
// K<-k_final, V<-v_final, SV<- -kk (aa), A<- kk*a (bb)
__global__ __launch_bounds__(256) void k_elem1(
    unsigned short* __restrict__ Kb, unsigned short* __restrict__ Ab,
    unsigned short* __restrict__ Vb, unsigned short* __restrict__ SVb,
    const float* __restrict__ v_first,
    const float* __restrict__ kkw, const float* __restrict__ kaw)
{
    int tid = threadIdx.x;
    size_t gh = (size_t)blockIdx.x * 4 + (tid >> 6);   // 0 .. B*T*H-1
    int lane = tid & 63;
    int h = (int)(gh & (Hn - 1));
    size_t idx = (gh >> 4) * Cn + (size_t)h * Nn + lane;
    int c = h * Nn + lane;

    float kp = b2f(Kb[idx]);
    float kkv = kp * kkw[c];
    float s = kkv * kkv;
    #pragma unroll
    for (int m = 1; m < 64; m <<= 1) s += __shfl_xor(s, m, 64);
    float kk = kkv / fmaxf(sqrtf(s), 1e-12f);

    float a = b2f(Ab[idx]);
    float kf = kp * (1.f + (a - 1.f) * kaw[c]);
    float vp = b2f(Vb[idx]), sv = b2f(SVb[idx]), vf = v_first[idx];
    float vfin = vp + (vf - vp) * sv;

    Kb[idx] = f2b(kf);
    Vb[idx] = f2b(vfin);
    SVb[idx] = f2b(-kk);
    Ab[idx] = f2b(kk * a);
}

// ---------- the sequential RWKV-7 scan ----------
// One block per (b,h) chain. 256 threads: thread (i=t>>2, q=t&3) owns S[i][q*16..q*16+16).
// Register prefetch of step t+1; single LDS buffer; 2 barriers/step.
__global__ __launch_bounds__(256, 1) void k_scan(
    const unsigned short* __restrict__ Rp, const float* __restrict__ Wp,
    const unsigned short* __restrict__ Kp, const unsigned short* __restrict__ Vp,
    const unsigned short* __restrict__ Ap, const unsigned short* __restrict__ Bp,
    float* __restrict__ Yp, float* __restrict__ SAp)
{
    __shared__ float lds[6][64];   // 0=r 1=k 2=v 3=aa 4=bb 5=w
    const int tid = threadIdx.x;
    const int bh = blockIdx.x;                          // b*16 + h
    const size_t base0 = ((size_t)(bh >> 4) * Tn) * Cn + (size_t)(bh & 15) * Nn;

    const int q = tid & 3, i = tid >> 2;
    const int aid = tid >> 4, part = tid & 15;
    const bool ldr = (tid < 96);
    const unsigned short* bsrc = nullptr;
    const float* fsrc = nullptr;
    if (ldr) {
        if (aid == 0) bsrc = Rp; else if (aid == 1) bsrc = Kp;
        else if (aid == 2) bsrc = Vp; else if (aid == 3) bsrc = Ap;
        else if (aid == 4) bsrc = Bp; else fsrc = Wp;
        if (bsrc) bsrc += base0 + part * 4; else fsrc += base0 + part * 4;
    }

    // prologue: stage t=0
    if (ldr) {
        float cur[4];
        if (aid < 5) {
            short4v h4 = *(const short4v*)bsrc;
            #pragma unroll
            for (int j = 0; j < 4; ++j) cur[j] = b2f((unsigned short)h4[j]);
        } else {
            f32x4 w4v = *(const f32x4*)fsrc;
            #pragma unroll
            for (int j = 0; j < 4; ++j) cur[j] = w4v[j];
        }
        #pragma unroll
        for (int j = 0; j < 4; ++j) lds[aid][part * 4 + j] = cur[j];
    }
    __syncthreads();

    float S[16];
    #pragma unroll
    for (int u = 0; u < 16; ++u) S[u] = 0.f;

    float* ybase = Yp + base0 + i;
    float* sabase = SAp + base0 + i;

    for (int t = 0; t < Tn; ++t) {
        // prefetch t+1 into registers (latency hidden under compute)
        float nxt[4];
        const bool have = ldr && (t < Tn - 1);
        if (have) {
            if (aid < 5) {
                short4v h4 = *(const short4v*)(bsrc + (size_t)(t + 1) * Cn);
                #pragma unroll
                for (int j = 0; j < 4; ++j) nxt[j] = b2f((unsigned short)h4[j]);
            } else {
                f32x4 w4v = *(const f32x4*)(fsrc + (size_t)(t + 1) * Cn);
                #pragma unroll
                for (int j = 0; j < 4; ++j) nxt[j] = w4v[j];
            }
        }

        f32x4 r4[4], w4[4], k4[4], a4[4], b4[4];
        #pragma unroll
        for (int u = 0; u < 4; ++u) {
            r4[u] = *(const f32x4*)&lds[0][q * 16 + u * 4];
            k4[u] = *(const f32x4*)&lds[1][q * 16 + u * 4];
            a4[u] = *(const f32x4*)&lds[3][q * 16 + u * 4];
            b4[u] = *(const f32x4*)&lds[4][q * 16 + u * 4];
            w4[u] = *(const f32x4*)&lds[5][q * 16 + u * 4];
        }
        float vi = lds[2][i];

        float sa = 0.f;
        #pragma unroll
        for (int u = 0; u < 4; ++u)
            #pragma unroll
            for (int e = 0; e < 4; ++e) sa += S[u * 4 + e] * a4[u][e];
        sa += __shfl_xor(sa, 1, 64);
        sa += __shfl_xor(sa, 2, 64);

        float y = 0.f;
        #pragma unroll
        for (int u = 0; u < 4; ++u)
            #pragma unroll
            for (int e = 0; e < 4; ++e) {
                float s = S[u * 4 + e] * w4[u][e] + sa * b4[u][e] + vi * k4[u][e];
                S[u * 4 + e] = s;
                y += s * r4[u][e];
            }
        y += __shfl_xor(y, 1, 64);
        y += __shfl_xor(y, 2, 64);

        if (q == 0) {
            ybase[(size_t)t * Cn] = y;
            sabase[(size_t)t * Cn] = sa;
        }

        __syncthreads();   // all reads of lds for step t done
        if (have) {
            #pragma unroll
            for (int j = 0; j < 4; ++j) lds[aid][part * 4 + j] = nxt[j];
        }
        __syncthreads();   // step t+1 data visible
    }
}

// ---------- elementwise stage 2: groupnorm + bonus + (x_att*g) -> AG (bf16) ----------
__global__ __launch_bounds__(256) void k_elem2(
    const float* __restrict__ Yb, const unsigned short* __restrict__ Rb,
    const unsigned short* __restrict__ Kb, const unsigned short* __restrict__ Vb,
    const unsigned short* __restrict__ Gb,
    const float* __restrict__ gnw, const float* __restrict__ gnb,
    const float* __restrict__ rk,
    unsigned short* __restrict__ AG)
{
    int tid = threadIdx.x;
    size_t gh = (size_t)blockIdx.x * 4 + (tid >> 6);
    int lane = tid & 63;
    int h = (int)(gh & (Hn - 1));
    size_t idx = (gh >> 4) * Cn + (size_t)h * Nn + lane;
    int c = h * Nn + lane;

    float y = Yb[idx];
    float s1 = y, s2 = y * y;
    float p = b2f(Rb[idx]) * b2f(Kb[idx]) * rk[c];
    #pragma unroll
    for (int m = 1; m < 64; m <<= 1) {
        s1 += __shfl_xor(s1, m, 64);
        s2 += __shfl_xor(s2, m, 64);
        p  += __shfl_xor(p, m, 64);
    }
    float mean = s1 * (1.f / 64.f);
    float var = s2 * (1.f / 64.f) - mean * mean;
    float xn = (y - mean) * rsqrtf(var + 0.00064f) * gnw[c] + gnb[c];
    float xatt = xn + p * b2f(Vb[idx]);
    AG[idx] = f2b(xatt * b2f(Gb[idx]));
}

// ---------- layernorm of sa_out -> state_rep (f32, in place in d_out) ----------
__global__ __launch_bounds__(256) void k_ln(
    const float* __restrict__ SAp,
    const float* __restrict__ lnw, const float* __restrict__ lnb,
    float* __restrict__ outp)
{
    __shared__ float red1[4], red2[4];
    int tid = threadIdx.x;
    size_t row = blockIdx.x;
    f32x4 v = *(const f32x4*)(SAp + row * Cn + tid * 4);
    float s1 = v[0] + v[1] + v[2] + v[3];
    float s2 = v[0] * v[0] + v[1] * v[1] + v[2] * v[2] + v[3] * v[3];
    #pragma unroll
    for (int m = 1; m < 64; m <<= 1) {
        s1 += __shfl_xor(s1, m, 64);
        s2 += __shfl_xor(s2, m, 64);
    }
    if ((tid & 63) == 0) { red1[tid >> 6] = s1; red2[tid >> 6] = s2; }
    __syncthreads();
    s1 = red1[0] + red1[1] + red1[2] + red1[3];
    s2 = red2[0] + red2[1] + red2[2] + red2[3];
    float mean = s1 * (1.f / 1024.f);
    float var = s2 * (1.f / 1024.f) - mean * mean;
    float rs = rsqrtf(var + 1e-5f);
    f32x4 o;
    #pragma unroll
    for (int u = 0; u < 4; ++u) {
        int c = tid * 4 + u;
        o[u] = (v[u] - mean) * rs * lnw[c] + lnb[c];
    }
    *(f32x4*)(outp + row * Cn + tid * 4) = o;
}

// ---------- v_first passthrough copy (f32) ----------
__global__ __launch_bounds__(256) void k_copy(
    const float* __restrict__ in, float* __restrict__ out)
{
    size_t e = ((size_t)blockIdx.x * 256 + threadIdx.x) * 4;
    if (e < MX) *(f32x4*)(out + e) = *(const f32x4*)(in + e);
}

// ---------- launcher ----------
extern "C" void kernel_launch(void* const* d_in, const int* in_sizes, int n_in,
                              void* d_out, int out_size, void* d_ws, size_t ws_size,
                              hipStream_t stream)
{
    (void)in_sizes; (void)n_in; (void)out_size; (void)ws_size;
    const float* x      = (const float*)d_in[0];
    const float* vfirst = (const float*)d_in[1];
    const float* x_r    = (const float*)d_in[2];
    const float* x_w    = (const float*)d_in[3];
    const float* x_k    = (const float*)d_in[4];
    const float* x_v    = (const float*)d_in[5];
    const float* x_a    = (const float*)d_in[6];
    const float* x_g    = (const float*)d_in[7];
    const float* w0     = (const float*)d_in[8];
    const float* w1     = (const float*)d_in[9];
    const float* w2     = (const float*)d_in[10];
    const float* a0     = (const float*)d_in[11];
    const float* a1     = (const float*)d_in[12];
    const float* a2     = (const float*)d_in[13];
    const float* v0     = (const float*)d_in[14];
    const float* v1     = (const float*)d_in[15];
    const float* v2     = (const float*)d_in[16];
    const float* g1     = (const float*)d_in[17];
    const float* g2     = (const float*)d_in[18];
    const float* k_k    = (const float*)d_in[19];
    const float* k_a    = (const float*)d_in[20];
    const float* r_k    = (const float*)d_in[21];
    const float* Wr     = (const float*)d_in[22];
    const float* Wk     = (const float*)d_in[23];
    const float* Wv     = (const float*)d_in[24];
    const float* Wo     = (const float*)d_in[25];
    const float* gn_w   = (const float*)d_in[26];
    const float* gn_b   = (const float*)d_in[27];
    const float* ln_w   = (const float*)d_in[28];
    const float* ln_b   = (const float*)d_in[29];

    char* ws = (char*)d_ws;
    size_t off = 0;
    auto alloc = [&](size_t bytes) -> void* {
        void* p = ws + off;
        off += (bytes + 255) & ~(size_t)255;
        return p;
    };
    // bf16 big buffers (8 MiB each)
    unsigned short* Rb  = (unsigned short*)alloc(MX * 2);  // raw r; reused as AG
    unsigned short* Kb  = (unsigned short*)alloc(MX * 2);  // raw k -> k_final
    unsigned short* Vb  = (unsigned short*)alloc(MX * 2);  // raw v -> v_final
    unsigned short* SVb = (unsigned short*)alloc(MX * 2);  // v-gate sigmoid -> aa
    unsigned short* Ab  = (unsigned short*)alloc(MX * 2);  // a sigmoid -> bb
    unsigned short* Gb  = (unsigned short*)alloc(MX * 2);  // g
    // f32 decay
    float* Wdec = (float*)alloc(MX * 4);
    // small intermediates (bf16)
    unsigned short* hw = (unsigned short*)alloc((size_t)Mrows * 64 * 2);
    unsigned short* ha = (unsigned short*)alloc((size_t)Mrows * 64 * 2);
    unsigned short* hv = (unsigned short*)alloc((size_t)Mrows * 64 * 2);
    unsigned short* hg = (unsigned short*)alloc((size_t)Mrows * 160 * 2);
    // bf16 weights
    unsigned short* WrB = (unsigned short*)alloc(1048576 * 2);
    unsigned short* WkB = (unsigned short*)alloc(1048576 * 2);
    unsigned short* WvB = (unsigned short*)alloc(1048576 * 2);
    unsigned short* WoB = (unsigned short*)alloc(1048576 * 2);
    unsigned short* w1T = (unsigned short*)alloc(65536 * 2);
    unsigned short* w2T = (unsigned short*)alloc(65536 * 2);
    unsigned short* a1T = (unsigned short*)alloc(65536 * 2);
    unsigned short* a2T = (unsigned short*)alloc(65536 * 2);
    unsigned short* v1T = (unsigned short*)alloc(65536 * 2);
    unsigned short* v2T = (unsigned short*)alloc(65536 * 2);
    unsigned short* g1T = (unsigned short*)alloc(163840 * 2);
    unsigned short* g2T = (unsigned short*)alloc(163840 * 2);
    // total ws use: ~75 MiB

    float* out_o  = (float*)d_out;          // final out  (doubles as Yb scratch)
    float* out_vf = out_o + MX;             // v_first copy
    float* out_sr = out_o + 2 * MX;         // state_rep  (doubles as SA scratch)
    float* Yb  = out_o;                     // scan y  -> consumed by k_elem2 before final GEMM
    float* SAb = out_sr;                    // scan sa -> layernormed in place by k_ln
    unsigned short* AG = Rb;                // reuse r buffer for (x_att*g)

    // weight conversions / transposes
    k_cvt<<<dim3(1024), 256, 0, stream>>>(Wr, WrB, 1048576);
    k_cvt<<<dim3(1024), 256, 0, stream>>>(Wk, WkB, 1048576);
    k_cvt<<<dim3(1024), 256, 0, stream>>>(Wv, WvB, 1048576);
    k_cvt<<<dim3(1024), 256, 0, stream>>>(Wo, WoB, 1048576);
    k_transpose<<<dim3(256), 256, 0, stream>>>(w1, w1T, 1024, 64);
    k_transpose<<<dim3(256), 256, 0, stream>>>(w2, w2T, 64, 1024);
    k_transpose<<<dim3(256), 256, 0, stream>>>(a1, a1T, 1024, 64);
    k_transpose<<<dim3(256), 256, 0, stream>>>(a2, a2T, 64, 1024);
    k_transpose<<<dim3(256), 256, 0, stream>>>(v1, v1T, 1024, 64);
    k_transpose<<<dim3(256), 256, 0, stream>>>(v2, v2T, 64, 1024);
    k_transpose<<<dim3(640), 256, 0, stream>>>(g1, g1T, 1024, 160);
    k_transpose<<<dim3(640), 256, 0, stream>>>(g2, g2T, 160, 1024);

    dim3 gBig(Mrows / 128, Cn / 128);     // 32 x 8
    dim3 gS1(Mrows / 256, 1);             // WR=4: 256 rows/block, N=64
    dim3 gG1(Mrows / 128, 2);             // N=160 -> 2 col-tiles w/ masking

    // stage-1 GEMMs (token-shift mix fused into f32 A loads)
    gemm_bt<2, 2, 0, 0, 1, 1><<<gBig, 256, 0, stream>>>(x, Cn, x_r, WrB, Cn, nullptr, Rb, Cn, nullptr, Cn, Cn);
    gemm_bt<2, 2, 0, 0, 1, 1><<<gBig, 256, 0, stream>>>(x, Cn, x_k, WkB, Cn, nullptr, Kb, Cn, nullptr, Cn, Cn);
    gemm_bt<2, 2, 0, 0, 1, 1><<<gBig, 256, 0, stream>>>(x, Cn, x_v, WvB, Cn, nullptr, Vb, Cn, nullptr, Cn, Cn);
    gemm_bt<4, 1, 1, 0, 1, 1><<<gS1, 256, 0, stream>>>(x, Cn, x_w, w1T, Cn, nullptr, hw, 64, nullptr, 64, Cn);
    gemm_bt<4, 1, 0, 0, 1, 1><<<gS1, 256, 0, stream>>>(x, Cn, x_a, a1T, Cn, nullptr, ha, 64, nullptr, 64, Cn);
    gemm_bt<4, 1, 0, 0, 1, 1><<<gS1, 256, 0, stream>>>(x, Cn, x_v, v1T, Cn, nullptr, hv, 64, nullptr, 64, Cn);
    gemm_bt<2, 2, 2, 0, 1, 1><<<gG1, 256, 0, stream>>>(x, Cn, x_g, g1T, Cn, nullptr, hg, 160, nullptr, 160, Cn);

    // stage-2 small GEMMs (bf16 A)
    gemm_bt<2, 2, 4, 1, 0, 0><<<gBig, 256, 0, stream>>>(hw, 64, nullptr, w2T, 64, Wdec, nullptr, Cn, w0, Cn, 64);
    gemm_bt<2, 2, 3, 0, 0, 0><<<gBig, 256, 0, stream>>>(ha, 64, nullptr, a2T, 64, nullptr, Ab, Cn, a0, Cn, 64);
    gemm_bt<2, 2, 3, 0, 0, 0><<<gBig, 256, 0, stream>>>(hv, 64, nullptr, v2T, 64, nullptr, SVb, Cn, v0, Cn, 64);
    gemm_bt<2, 2, 0, 0, 0, 0><<<gBig, 256, 0, stream>>>(hg, 160, nullptr, g2T, 160, nullptr, Gb, Cn, nullptr, Cn, 160);

    k_elem1<<<dim3(16384), 256, 0, stream>>>(Kb, Ab, Vb, SVb, vfirst, k_k, k_a);

    k_scan<<<dim3(64), 256, 0, stream>>>(Rb, Wdec, Kb, Vb, SVb, Ab, Yb, SAb);

    k_elem2<<<dim3(16384), 256, 0, stream>>>(Yb, Rb, Kb, Vb, Gb, gn_w, gn_b, r_k, AG);

    // real outputs (Yb scratch in out_o fully consumed by k_elem2)
    k_ln<<<dim3(4096), 256, 0, stream>>>(SAb, ln_w, ln_b, out_sr);
    k_copy<<<dim3(4096), 256, 0, stream>>>(vfirst, out_vf);
    gemm_bt<2, 2, 0, 1, 0, 0><<<gBig, 256, 0, stream>>>(AG, Cn, nullptr, WoB, Cn, out_o, nullptr, Cn, nullptr, Cn, Cn);
}

// Round 4
// 974.514 us; speedup vs baseline: 1.5506x; 1.5506x over previous
//
#include <hip/hip_runtime.h>
#include <hip/hip_bf16.h>
#include <cstdint>
#include <cstddef>

// ---------- types & helpers ----------
typedef __attribute__((ext_vector_type(8))) short short8;   // 8 x bf16
typedef __attribute__((ext_vector_type(4))) short short4v;  // 4 x bf16 (8B)
typedef __attribute__((ext_vector_type(4))) float f32x4;

#define DEVINL static __device__ __forceinline__

DEVINL float b2f(unsigned short u) {
    union { unsigned int i; float f; } v; v.i = ((unsigned int)u) << 16; return v.f;
}
DEVINL unsigned short f2b(float f) {
    union { float f; unsigned int i; } v; v.f = f;
    unsigned int x = v.i;
    return (unsigned short)((x + 0x7FFFu + ((x >> 16) & 1u)) >> 16);
}

static constexpr int Bsz = 4, Tn = 1024, Cn = 1024, Hn = 16, Nn = 64;
static constexpr int Mrows = Bsz * Tn;             // 4096
static constexpr size_t MX = (size_t)Mrows * Cn;   // 4,194,304
static constexpr int NCHUNK = 16, CL = 64;         // 16 chunks x 64 steps

// ---------- f32 -> bf16 convert (weights) ----------
__global__ __launch_bounds__(256) void k_cvt(const float* __restrict__ in,
                                             unsigned short* __restrict__ out, int n)
{
    int i = (blockIdx.x * 256 + threadIdx.x) * 4;
    if (i < n) {
        f32x4 v = *(const f32x4*)(in + i);
        short4v o;
        #pragma unroll
        for (int j = 0; j < 4; ++j) o[j] = (short)f2b(v[j]);
        *(short4v*)(out + i) = o;
    }
}

// ---------- small-weight transpose + convert ----------
__global__ void k_transpose(const float* __restrict__ in,
                            unsigned short* __restrict__ out, int R, int Cc)
{
    int i = blockIdx.x * 256 + threadIdx.x;
    if (i < R * Cc) {
        int r = i / Cc, c = i % Cc;
        out[(size_t)c * R + r] = f2b(in[i]);
    }
}

// ---------- generic MFMA GEMM: C[M,N] = epi(A[M,K] @ Bt[N,K]^T) ----------
template<int WR, int WC, int EPI, int OUTF32, int AF32, int AMIX>
__global__ __launch_bounds__(256) void gemm_bt(
    const void* __restrict__ Av, int lda,
    const float* __restrict__ mixv,
    const unsigned short* __restrict__ Bt, int ldb,
    float* __restrict__ Cf, unsigned short* __restrict__ Cb, int ldc,
    const float* __restrict__ bias, int N, int K)
{
    const int tid = threadIdx.x;
    const int wid = tid >> 6;
    const int lane = tid & 63;
    const int r16 = lane & 15;
    const int k8 = (lane >> 4) * 8;
    const int m0 = blockIdx.x * (WR * 64) + (wid / WC) * 64;
    const int n0 = blockIdx.y * (WC * 64) + (wid % WC) * 64;

    f32x4 acc[4][4];
    #pragma unroll
    for (int a = 0; a < 4; ++a)
        #pragma unroll
        for (int b = 0; b < 4; ++b) acc[a][b] = (f32x4){0.f, 0.f, 0.f, 0.f};

    for (int k0 = 0; k0 < K; k0 += 32) {
        short8 af[4], bf[4];
        float mxf[8];
        if (AMIX) {
            f32x4 m0v = *(const f32x4*)(mixv + k0 + k8);
            f32x4 m1v = *(const f32x4*)(mixv + k0 + k8 + 4);
            #pragma unroll
            for (int j = 0; j < 4; ++j) { mxf[j] = m0v[j]; mxf[4 + j] = m1v[j]; }
        }
        #pragma unroll
        for (int mi = 0; mi < 4; ++mi) {
            int row = m0 + mi * 16 + r16;
            if (AF32) {
                const float* ap = (const float*)Av + (size_t)row * lda + k0 + k8;
                f32x4 x0 = *(const f32x4*)ap;
                f32x4 x1 = *(const f32x4*)(ap + 4);
                float xf[8];
                #pragma unroll
                for (int j = 0; j < 4; ++j) { xf[j] = x0[j]; xf[4 + j] = x1[j]; }
                if (AMIX) {
                    const bool hasp = (row & (Tn - 1)) != 0;
                    float pf[8];
                    if (hasp) {
                        f32x4 p0 = *(const f32x4*)(ap - lda);
                        f32x4 p1 = *(const f32x4*)(ap - lda + 4);
                        #pragma unroll
                        for (int j = 0; j < 4; ++j) { pf[j] = p0[j]; pf[4 + j] = p1[j]; }
                    } else {
                        #pragma unroll
                        for (int j = 0; j < 8; ++j) pf[j] = 0.f;
                    }
                    #pragma unroll
                    for (int j = 0; j < 8; ++j) xf[j] += (pf[j] - xf[j]) * mxf[j];
                }
                short8 o;
                #pragma unroll
                for (int j = 0; j < 8; ++j) o[j] = (short)f2b(xf[j]);
                af[mi] = o;
            } else {
                af[mi] = *(const short8*)((const unsigned short*)Av + (size_t)row * lda + k0 + k8);
            }
        }
        #pragma unroll
        for (int ni = 0; ni < 4; ++ni) {
            int rn = n0 + ni * 16 + r16;
            if (rn >= N) rn = N - 1;
            bf[ni] = *(const short8*)(Bt + (size_t)rn * ldb + k0 + k8);
        }
        #pragma unroll
        for (int mi = 0; mi < 4; ++mi)
            #pragma unroll
            for (int ni = 0; ni < 4; ++ni)
                acc[mi][ni] = __builtin_amdgcn_mfma_f32_16x16x32_bf16(af[mi], bf[ni], acc[mi][ni], 0, 0, 0);
    }

    #pragma unroll
    for (int mi = 0; mi < 4; ++mi)
        #pragma unroll
        for (int ni = 0; ni < 4; ++ni) {
            int col = n0 + ni * 16 + r16;
            if (col < N) {
                float bv = 0.f;
                if (EPI == 3 || EPI == 4) bv = bias[col];
                #pragma unroll
                for (int r = 0; r < 4; ++r) {
                    int row = m0 + mi * 16 + (lane >> 4) * 4 + r;
                    float v = acc[mi][ni][r];
                    if (EPI == 1) v = tanhf(v);
                    else if (EPI == 2) v = 1.f / (1.f + expf(-v));
                    else if (EPI == 3) { v += bv; v = 1.f / (1.f + expf(-v)); }
                    else if (EPI == 4) { v += bv; v = expf(-0.60653066f / (1.f + expf(-v))); }
                    size_t o = (size_t)row * ldc + col;
                    if (OUTF32) Cf[o] = v; else Cb[o] = f2b(v);
                }
            }
        }
}

// ---------- elementwise stage 1 (bf16 buffers in place; vfirst f32) ----------
__global__ __launch_bounds__(256) void k_elem1(
    unsigned short* __restrict__ Kb, unsigned short* __restrict__ Ab,
    unsigned short* __restrict__ Vb, unsigned short* __restrict__ SVb,
    const float* __restrict__ v_first,
    const float* __restrict__ kkw, const float* __restrict__ kaw)
{
    int tid = threadIdx.x;
    size_t gh = (size_t)blockIdx.x * 4 + (tid >> 6);   // 0 .. B*T*H-1
    int lane = tid & 63;
    int h = (int)(gh & (Hn - 1));
    size_t idx = (gh >> 4) * Cn + (size_t)h * Nn + lane;
    int c = h * Nn + lane;

    float kp = b2f(Kb[idx]);
    float kkv = kp * kkw[c];
    float s = kkv * kkv;
    #pragma unroll
    for (int m = 1; m < 64; m <<= 1) s += __shfl_xor(s, m, 64);
    float kk = kkv / fmaxf(sqrtf(s), 1e-12f);

    float a = b2f(Ab[idx]);
    float kf = kp * (1.f + (a - 1.f) * kaw[c]);
    float vp = b2f(Vb[idx]), sv = b2f(SVb[idx]), vf = v_first[idx];
    float vfin = vp + (vf - vp) * sv;

    Kb[idx] = f2b(kf);
    Vb[idx] = f2b(vfin);
    SVb[idx] = f2b(-kk);
    Ab[idx] = f2b(kk * a);
}

// ================= chunked scan =================
// Phase A: per (chain, chunk): P = prod M_t (M = diag(w)+a b^T), C = local offset.
// Thread (i=tid>>2, q=tid&3) owns row i, cols q*16..q*16+15 of P and C.
__global__ __launch_bounds__(256, 1) void kA_chunk(
    const float* __restrict__ Wp, const unsigned short* __restrict__ Kp,
    const unsigned short* __restrict__ Vp, const unsigned short* __restrict__ Ap,
    const unsigned short* __restrict__ Bp,
    float* __restrict__ Pg, float* __restrict__ Cg)
{
    __shared__ float wS[CL][64];             // 16KB
    __shared__ unsigned short kS[CL][64];    // 8KB
    __shared__ unsigned short vS[CL][64];
    __shared__ unsigned short aS[CL][64];
    __shared__ unsigned short bS[CL][64];    // total 48KB

    const int tid = threadIdx.x;
    const int bx = blockIdx.x;
    const int bh = bx >> 4, c = bx & 15;
    const size_t base0 = ((size_t)(bh >> 4) * Tn + (size_t)c * CL) * Cn + (size_t)(bh & 15) * Nn;

    {   // stage whole chunk into LDS
        const int t = tid >> 2, seg = (tid & 3) * 16;
        const size_t g = base0 + (size_t)t * Cn + seg;
        *(short8*)&kS[t][seg]     = *(const short8*)(Kp + g);
        *(short8*)&kS[t][seg + 8] = *(const short8*)(Kp + g + 8);
        *(short8*)&vS[t][seg]     = *(const short8*)(Vp + g);
        *(short8*)&vS[t][seg + 8] = *(const short8*)(Vp + g + 8);
        *(short8*)&aS[t][seg]     = *(const short8*)(Ap + g);
        *(short8*)&aS[t][seg + 8] = *(const short8*)(Ap + g + 8);
        *(short8*)&bS[t][seg]     = *(const short8*)(Bp + g);
        *(short8*)&bS[t][seg + 8] = *(const short8*)(Bp + g + 8);
        #pragma unroll
        for (int u = 0; u < 4; ++u)
            *(f32x4*)&wS[t][seg + u * 4] = *(const f32x4*)(Wp + g + u * 4);
    }
    __syncthreads();

    const int q = tid & 3, i = tid >> 2;
    float P[16], C[16];
    #pragma unroll
    for (int u = 0; u < 16; ++u) {
        int j = q * 16 + u;
        P[u] = (j == i) ? 1.f : 0.f;
        C[u] = 0.f;
    }

    for (int t = 0; t < CL; ++t) {
        float a16[16], k16[16], b16[16], w16[16];
        short8 t0 = *(const short8*)&aS[t][q * 16];
        short8 t1 = *(const short8*)&aS[t][q * 16 + 8];
        #pragma unroll
        for (int j = 0; j < 8; ++j) { a16[j] = b2f((unsigned short)t0[j]); a16[8 + j] = b2f((unsigned short)t1[j]); }

        float pa = 0.f, ca = 0.f;
        #pragma unroll
        for (int u = 0; u < 16; ++u) { pa += P[u] * a16[u]; ca += C[u] * a16[u]; }
        pa += __shfl_xor(pa, 1, 64); pa += __shfl_xor(pa, 2, 64);
        ca += __shfl_xor(ca, 1, 64); ca += __shfl_xor(ca, 2, 64);

        float vi = b2f(vS[t][i]);
        t0 = *(const short8*)&kS[t][q * 16];
        t1 = *(const short8*)&kS[t][q * 16 + 8];
        #pragma unroll
        for (int j = 0; j < 8; ++j) { k16[j] = b2f((unsigned short)t0[j]); k16[8 + j] = b2f((unsigned short)t1[j]); }
        t0 = *(const short8*)&bS[t][q * 16];
        t1 = *(const short8*)&bS[t][q * 16 + 8];
        #pragma unroll
        for (int j = 0; j < 8; ++j) { b16[j] = b2f((unsigned short)t0[j]); b16[8 + j] = b2f((unsigned short)t1[j]); }
        #pragma unroll
        for (int u = 0; u < 4; ++u) {
            f32x4 w4 = *(const f32x4*)&wS[t][q * 16 + u * 4];
            #pragma unroll
            for (int e = 0; e < 4; ++e) w16[u * 4 + e] = w4[e];
        }

        #pragma unroll
        for (int u = 0; u < 16; ++u) {
            C[u] = C[u] * w16[u] + ca * b16[u] + vi * k16[u];
            P[u] = P[u] * w16[u] + pa * b16[u];
        }
    }

    const size_t ob = (size_t)bx * 4096 + (size_t)i * 64 + q * 16;
    #pragma unroll
    for (int u = 0; u < 4; ++u) {
        *(f32x4*)(Pg + ob + u * 4) = (f32x4){P[u * 4], P[u * 4 + 1], P[u * 4 + 2], P[u * 4 + 3]};
        *(f32x4*)(Cg + ob + u * 4) = (f32x4){C[u * 4], C[u * 4 + 1], C[u * 4 + 2], C[u * 4 + 3]};
    }
}

// Phase B: per chain: sequential chunk combine S <- S*P_c + C_c; emit S_init per chunk.
__global__ __launch_bounds__(256, 1) void kB_combine(
    const float* __restrict__ Pg, const float* __restrict__ Cg,
    float* __restrict__ Sinit)
{
    __shared__ float S[64 * 68];     // stride 68: bank-spread + 16B aligned
    __shared__ float Pl[4096];
    const int tid = threadIdx.x;
    const int bh = blockIdx.x;
    const int i = tid >> 2, q = tid & 3;

    for (int u = tid; u < 64 * 68; u += 256) S[u] = 0.f;
    __syncthreads();

    for (int c = 0; c < NCHUNK; ++c) {
        const size_t ob = ((size_t)(bh * 16 + c)) * 4096;
        // emit S_init for this chunk
        #pragma unroll
        for (int u = 0; u < 4; ++u)
            *(f32x4*)(Sinit + ob + (size_t)i * 64 + q * 16 + u * 4) =
                *(const f32x4*)&S[i * 68 + q * 16 + u * 4];
        if (c == NCHUNK - 1) break;

        #pragma unroll
        for (int u = 0; u < 4; ++u)
            *(f32x4*)&Pl[tid * 16 + u * 4] = *(const f32x4*)(Pg + ob + tid * 16 + u * 4);
        __syncthreads();

        float acc[16];
        #pragma unroll
        for (int u = 0; u < 4; ++u) {
            f32x4 cv = *(const f32x4*)(Cg + ob + (size_t)i * 64 + q * 16 + u * 4);
            #pragma unroll
            for (int e = 0; e < 4; ++e) acc[u * 4 + e] = cv[e];
        }
        for (int m = 0; m < 64; ++m) {
            float s = S[i * 68 + m];
            #pragma unroll
            for (int u = 0; u < 4; ++u) {
                f32x4 p4 = *(const f32x4*)&Pl[m * 64 + q * 16 + u * 4];
                #pragma unroll
                for (int e = 0; e < 4; ++e) acc[u * 4 + e] += s * p4[e];
            }
        }
        __syncthreads();
        #pragma unroll
        for (int u = 0; u < 16; ++u) S[i * 68 + q * 16 + u] = acc[u];
        __syncthreads();
    }
}

// Phase C: per (chain, chunk): run the exact recurrence from S_init, emit y & sa.
__global__ __launch_bounds__(256, 2) void kC_scan(
    const float* __restrict__ Sinit,
    const unsigned short* __restrict__ Rp, const float* __restrict__ Wp,
    const unsigned short* __restrict__ Kp, const unsigned short* __restrict__ Vp,
    const unsigned short* __restrict__ Ap, const unsigned short* __restrict__ Bp,
    float* __restrict__ Yp, float* __restrict__ SAp)
{
    __shared__ float wS[CL][64];             // 16KB
    __shared__ unsigned short rS[CL][64];    // 8KB each
    __shared__ unsigned short kS[CL][64];
    __shared__ unsigned short vS[CL][64];
    __shared__ unsigned short aS[CL][64];
    __shared__ unsigned short bS[CL][64];    // total 56KB

    const int tid = threadIdx.x;
    const int bx = blockIdx.x;
    const int bh = bx >> 4, c = bx & 15;
    const size_t base0 = ((size_t)(bh >> 4) * Tn + (size_t)c * CL) * Cn + (size_t)(bh & 15) * Nn;

    {
        const int t = tid >> 2, seg = (tid & 3) * 16;
        const size_t g = base0 + (size_t)t * Cn + seg;
        *(short8*)&rS[t][seg]     = *(const short8*)(Rp + g);
        *(short8*)&rS[t][seg + 8] = *(const short8*)(Rp + g + 8);
        *(short8*)&kS[t][seg]     = *(const short8*)(Kp + g);
        *(short8*)&kS[t][seg + 8] = *(const short8*)(Kp + g + 8);
        *(short8*)&vS[t][seg]     = *(const short8*)(Vp + g);
        *(short8*)&vS[t][seg + 8] = *(const short8*)(Vp + g + 8);
        *(short8*)&aS[t][seg]     = *(const short8*)(Ap + g);
        *(short8*)&aS[t][seg + 8] = *(const short8*)(Ap + g + 8);
        *(short8*)&bS[t][seg]     = *(const short8*)(Bp + g);
        *(short8*)&bS[t][seg + 8] = *(const short8*)(Bp + g + 8);
        #pragma unroll
        for (int u = 0; u < 4; ++u)
            *(f32x4*)&wS[t][seg + u * 4] = *(const f32x4*)(Wp + g + u * 4);
    }

    const int q = tid & 3, i = tid >> 2;
    float S[16];
    {
        const size_t sb = (size_t)bx * 4096 + (size_t)i * 64 + q * 16;
        #pragma unroll
        for (int u = 0; u < 4; ++u) {
            f32x4 s4 = *(const f32x4*)(Sinit + sb + u * 4);
            #pragma unroll
            for (int e = 0; e < 4; ++e) S[u * 4 + e] = s4[e];
        }
    }
    __syncthreads();

    float* ybase = Yp + base0 + i;
    float* sabase = SAp + base0 + i;

    for (int t = 0; t < CL; ++t) {
        float a16[16], k16[16], b16[16], w16[16], r16[16];
        short8 t0 = *(const short8*)&aS[t][q * 16];
        short8 t1 = *(const short8*)&aS[t][q * 16 + 8];
        #pragma unroll
        for (int j = 0; j < 8; ++j) { a16[j] = b2f((unsigned short)t0[j]); a16[8 + j] = b2f((unsigned short)t1[j]); }

        float sa = 0.f;
        #pragma unroll
        for (int u = 0; u < 16; ++u) sa += S[u] * a16[u];
        sa += __shfl_xor(sa, 1, 64); sa += __shfl_xor(sa, 2, 64);

        float vi = b2f(vS[t][i]);
        t0 = *(const short8*)&kS[t][q * 16];
        t1 = *(const short8*)&kS[t][q * 16 + 8];
        #pragma unroll
        for (int j = 0; j < 8; ++j) { k16[j] = b2f((unsigned short)t0[j]); k16[8 + j] = b2f((unsigned short)t1[j]); }
        t0 = *(const short8*)&bS[t][q * 16];
        t1 = *(const short8*)&bS[t][q * 16 + 8];
        #pragma unroll
        for (int j = 0; j < 8; ++j) { b16[j] = b2f((unsigned short)t0[j]); b16[8 + j] = b2f((unsigned short)t1[j]); }
        t0 = *(const short8*)&rS[t][q * 16];
        t1 = *(const short8*)&rS[t][q * 16 + 8];
        #pragma unroll
        for (int j = 0; j < 8; ++j) { r16[j] = b2f((unsigned short)t0[j]); r16[8 + j] = b2f((unsigned short)t1[j]); }
        #pragma unroll
        for (int u = 0; u < 4; ++u) {
            f32x4 w4 = *(const f32x4*)&wS[t][q * 16 + u * 4];
            #pragma unroll
            for (int e = 0; e < 4; ++e) w16[u * 4 + e] = w4[e];
        }

        float y = 0.f;
        #pragma unroll
        for (int u = 0; u < 16; ++u) {
            float s = S[u] * w16[u] + sa * b16[u] + vi * k16[u];
            S[u] = s;
            y += s * r16[u];
        }
        y += __shfl_xor(y, 1, 64); y += __shfl_xor(y, 2, 64);

        if (q == 0) {
            ybase[(size_t)t * Cn] = y;
            sabase[(size_t)t * Cn] = sa;
        }
    }
}

// ---------- elementwise stage 2: groupnorm + bonus + (x_att*g) -> AG (bf16) ----------
__global__ __launch_bounds__(256) void k_elem2(
    const float* __restrict__ Yb, const unsigned short* __restrict__ Rb,
    const unsigned short* __restrict__ Kb, const unsigned short* __restrict__ Vb,
    const unsigned short* __restrict__ Gb,
    const float* __restrict__ gnw, const float* __restrict__ gnb,
    const float* __restrict__ rk,
    unsigned short* __restrict__ AG)
{
    int tid = threadIdx.x;
    size_t gh = (size_t)blockIdx.x * 4 + (tid >> 6);
    int lane = tid & 63;
    int h = (int)(gh & (Hn - 1));
    size_t idx = (gh >> 4) * Cn + (size_t)h * Nn + lane;
    int c = h * Nn + lane;

    float y = Yb[idx];
    float s1 = y, s2 = y * y;
    float p = b2f(Rb[idx]) * b2f(Kb[idx]) * rk[c];
    #pragma unroll
    for (int m = 1; m < 64; m <<= 1) {
        s1 += __shfl_xor(s1, m, 64);
        s2 += __shfl_xor(s2, m, 64);
        p  += __shfl_xor(p, m, 64);
    }
    float mean = s1 * (1.f / 64.f);
    float var = s2 * (1.f / 64.f) - mean * mean;
    float xn = (y - mean) * rsqrtf(var + 0.00064f) * gnw[c] + gnb[c];
    float xatt = xn + p * b2f(Vb[idx]);
    AG[idx] = f2b(xatt * b2f(Gb[idx]));
}

// ---------- layernorm of sa_out -> state_rep (f32, in place in d_out) ----------
__global__ __launch_bounds__(256) void k_ln(
    const float* __restrict__ SAp,
    const float* __restrict__ lnw, const float* __restrict__ lnb,
    float* __restrict__ outp)
{
    __shared__ float red1[4], red2[4];
    int tid = threadIdx.x;
    size_t row = blockIdx.x;
    f32x4 v = *(const f32x4*)(SAp + row * Cn + tid * 4);
    float s1 = v[0] + v[1] + v[2] + v[3];
    float s2 = v[0] * v[0] + v[1] * v[1] + v[2] * v[2] + v[3] * v[3];
    #pragma unroll
    for (int m = 1; m < 64; m <<= 1) {
        s1 += __shfl_xor(s1, m, 64);
        s2 += __shfl_xor(s2, m, 64);
    }
    if ((tid & 63) == 0) { red1[tid >> 6] = s1; red2[tid >> 6] = s2; }
    __syncthreads();
    s1 = red1[0] + red1[1] + red1[2] + red1[3];
    s2 = red2[0] + red2[1] + red2[2] + red2[3];
    float mean = s1 * (1.f / 1024.f);
    float var = s2 * (1.f / 1024.f) - mean * mean;
    float rs = rsqrtf(var + 1e-5f);
    f32x4 o;
    #pragma unroll
    for (int u = 0; u < 4; ++u) {
        int c = tid * 4 + u;
        o[u] = (v[u] - mean) * rs * lnw[c] + lnb[c];
    }
    *(f32x4*)(outp + row * Cn + tid * 4) = o;
}

// ---------- v_first passthrough copy (f32) ----------
__global__ __launch_bounds__(256) void k_copy(
    const float* __restrict__ in, float* __restrict__ out)
{
    size_t e = ((size_t)blockIdx.x * 256 + threadIdx.x) * 4;
    if (e < MX) *(f32x4*)(out + e) = *(const f32x4*)(in + e);
}

// ---------- launcher ----------
extern "C" void kernel_launch(void* const* d_in, const int* in_sizes, int n_in,
                              void* d_out, int out_size, void* d_ws, size_t ws_size,
                              hipStream_t stream)
{
    (void)in_sizes; (void)n_in; (void)out_size; (void)ws_size;
    const float* x      = (const float*)d_in[0];
    const float* vfirst = (const float*)d_in[1];
    const float* x_r    = (const float*)d_in[2];
    const float* x_w    = (const float*)d_in[3];
    const float* x_k    = (const float*)d_in[4];
    const float* x_v    = (const float*)d_in[5];
    const float* x_a    = (const float*)d_in[6];
    const float* x_g    = (const float*)d_in[7];
    const float* w0     = (const float*)d_in[8];
    const float* w1     = (const float*)d_in[9];
    const float* w2     = (const float*)d_in[10];
    const float* a0     = (const float*)d_in[11];
    const float* a1     = (const float*)d_in[12];
    const float* a2     = (const float*)d_in[13];
    const float* v0     = (const float*)d_in[14];
    const float* v1     = (const float*)d_in[15];
    const float* v2     = (const float*)d_in[16];
    const float* g1     = (const float*)d_in[17];
    const float* g2     = (const float*)d_in[18];
    const float* k_k    = (const float*)d_in[19];
    const float* k_a    = (const float*)d_in[20];
    const float* r_k    = (const float*)d_in[21];
    const float* Wr     = (const float*)d_in[22];
    const float* Wk     = (const float*)d_in[23];
    const float* Wv     = (const float*)d_in[24];
    const float* Wo     = (const float*)d_in[25];
    const float* gn_w   = (const float*)d_in[26];
    const float* gn_b   = (const float*)d_in[27];
    const float* ln_w   = (const float*)d_in[28];
    const float* ln_b   = (const float*)d_in[29];

    char* ws = (char*)d_ws;
    size_t off = 0;
    auto alloc = [&](size_t bytes) -> void* {
        void* p = ws + off;
        off += (bytes + 255) & ~(size_t)255;
        return p;
    };
    // bf16 big buffers (8 MiB each)
    unsigned short* Rb  = (unsigned short*)alloc(MX * 2);  // raw r; reused as AG
    unsigned short* Kb  = (unsigned short*)alloc(MX * 2);  // raw k -> k_final
    unsigned short* Vb  = (unsigned short*)alloc(MX * 2);  // raw v -> v_final
    unsigned short* SVb = (unsigned short*)alloc(MX * 2);  // v-gate sigmoid -> aa
    unsigned short* Ab  = (unsigned short*)alloc(MX * 2);  // a sigmoid -> bb
    unsigned short* Gb  = (unsigned short*)alloc(MX * 2);  // g
    // f32 decay
    float* Wdec = (float*)alloc(MX * 4);
    // chunked-scan offset matrices (16 MiB)
    float* Cg = (float*)alloc(MX * 4);
    // small intermediates (bf16)
    unsigned short* hw = (unsigned short*)alloc((size_t)Mrows * 64 * 2);
    unsigned short* ha = (unsigned short*)alloc((size_t)Mrows * 64 * 2);
    unsigned short* hv = (unsigned short*)alloc((size_t)Mrows * 64 * 2);
    unsigned short* hg = (unsigned short*)alloc((size_t)Mrows * 160 * 2);
    // bf16 weights
    unsigned short* WrB = (unsigned short*)alloc(1048576 * 2);
    unsigned short* WkB = (unsigned short*)alloc(1048576 * 2);
    unsigned short* WvB = (unsigned short*)alloc(1048576 * 2);
    unsigned short* WoB = (unsigned short*)alloc(1048576 * 2);
    unsigned short* w1T = (unsigned short*)alloc(65536 * 2);
    unsigned short* w2T = (unsigned short*)alloc(65536 * 2);
    unsigned short* a1T = (unsigned short*)alloc(65536 * 2);
    unsigned short* a2T = (unsigned short*)alloc(65536 * 2);
    unsigned short* v1T = (unsigned short*)alloc(65536 * 2);
    unsigned short* v2T = (unsigned short*)alloc(65536 * 2);
    unsigned short* g1T = (unsigned short*)alloc(163840 * 2);
    unsigned short* g2T = (unsigned short*)alloc(163840 * 2);
    // total ws use: ~92 MiB

    float* out_o  = (float*)d_out;          // final out
    float* out_vf = out_o + MX;             // v_first copy
    float* out_sr = out_o + 2 * MX;         // state_rep
    // scratch aliases inside d_out (each dead before the real output is written):
    float* Pg    = out_o;                   // phase A transfer matrices (dead after B)
    float* Sinit = out_vf;                  // chunk-initial states (dead after C; k_copy runs later)
    float* Yb    = out_o;                   // phase C y (consumed by k_elem2 before final GEMM)
    float* SAb   = out_sr;                  // phase C sa (layernormed in place)
    unsigned short* AG = Rb;                // reuse r buffer for (x_att*g)

    // weight conversions / transposes
    k_cvt<<<dim3(1024), 256, 0, stream>>>(Wr, WrB, 1048576);
    k_cvt<<<dim3(1024), 256, 0, stream>>>(Wk, WkB, 1048576);
    k_cvt<<<dim3(1024), 256, 0, stream>>>(Wv, WvB, 1048576);
    k_cvt<<<dim3(1024), 256, 0, stream>>>(Wo, WoB, 1048576);
    k_transpose<<<dim3(256), 256, 0, stream>>>(w1, w1T, 1024, 64);
    k_transpose<<<dim3(256), 256, 0, stream>>>(w2, w2T, 64, 1024);
    k_transpose<<<dim3(256), 256, 0, stream>>>(a1, a1T, 1024, 64);
    k_transpose<<<dim3(256), 256, 0, stream>>>(a2, a2T, 64, 1024);
    k_transpose<<<dim3(256), 256, 0, stream>>>(v1, v1T, 1024, 64);
    k_transpose<<<dim3(256), 256, 0, stream>>>(v2, v2T, 64, 1024);
    k_transpose<<<dim3(640), 256, 0, stream>>>(g1, g1T, 1024, 160);
    k_transpose<<<dim3(640), 256, 0, stream>>>(g2, g2T, 160, 1024);

    dim3 gBig(Mrows / 128, Cn / 128);     // 32 x 8
    dim3 gS1(Mrows / 256, 1);             // WR=4: 256 rows/block, N=64
    dim3 gG1(Mrows / 128, 2);             // N=160 -> 2 col-tiles w/ masking

    // stage-1 GEMMs (token-shift mix fused into f32 A loads)
    gemm_bt<2, 2, 0, 0, 1, 1><<<gBig, 256, 0, stream>>>(x, Cn, x_r, WrB, Cn, nullptr, Rb, Cn, nullptr, Cn, Cn);
    gemm_bt<2, 2, 0, 0, 1, 1><<<gBig, 256, 0, stream>>>(x, Cn, x_k, WkB, Cn, nullptr, Kb, Cn, nullptr, Cn, Cn);
    gemm_bt<2, 2, 0, 0, 1, 1><<<gBig, 256, 0, stream>>>(x, Cn, x_v, WvB, Cn, nullptr, Vb, Cn, nullptr, Cn, Cn);
    gemm_bt<4, 1, 1, 0, 1, 1><<<gS1, 256, 0, stream>>>(x, Cn, x_w, w1T, Cn, nullptr, hw, 64, nullptr, 64, Cn);
    gemm_bt<4, 1, 0, 0, 1, 1><<<gS1, 256, 0, stream>>>(x, Cn, x_a, a1T, Cn, nullptr, ha, 64, nullptr, 64, Cn);
    gemm_bt<4, 1, 0, 0, 1, 1><<<gS1, 256, 0, stream>>>(x, Cn, x_v, v1T, Cn, nullptr, hv, 64, nullptr, 64, Cn);
    gemm_bt<2, 2, 2, 0, 1, 1><<<gG1, 256, 0, stream>>>(x, Cn, x_g, g1T, Cn, nullptr, hg, 160, nullptr, 160, Cn);

    // stage-2 small GEMMs (bf16 A)
    gemm_bt<2, 2, 4, 1, 0, 0><<<gBig, 256, 0, stream>>>(hw, 64, nullptr, w2T, 64, Wdec, nullptr, Cn, w0, Cn, 64);
    gemm_bt<2, 2, 3, 0, 0, 0><<<gBig, 256, 0, stream>>>(ha, 64, nullptr, a2T, 64, nullptr, Ab, Cn, a0, Cn, 64);
    gemm_bt<2, 2, 3, 0, 0, 0><<<gBig, 256, 0, stream>>>(hv, 64, nullptr, v2T, 64, nullptr, SVb, Cn, v0, Cn, 64);
    gemm_bt<2, 2, 0, 0, 0, 0><<<gBig, 256, 0, stream>>>(hg, 160, nullptr, g2T, 160, nullptr, Gb, Cn, nullptr, Cn, 160);

    k_elem1<<<dim3(16384), 256, 0, stream>>>(Kb, Ab, Vb, SVb, vfirst, k_k, k_a);

    // chunked scan
    kA_chunk<<<dim3(1024), 256, 0, stream>>>(Wdec, Kb, Vb, SVb, Ab, Pg, Cg);
    kB_combine<<<dim3(64), 256, 0, stream>>>(Pg, Cg, Sinit);
    kC_scan<<<dim3(1024), 256, 0, stream>>>(Sinit, Rb, Wdec, Kb, Vb, SVb, Ab, Yb, SAb);

    k_elem2<<<dim3(16384), 256, 0, stream>>>(Yb, Rb, Kb, Vb, Gb, gn_w, gn_b, r_k, AG);

    // real outputs (all scratch aliases in d_out consumed by here)
    k_ln<<<dim3(4096), 256, 0, stream>>>(SAb, ln_w, ln_b, out_sr);
    k_copy<<<dim3(4096), 256, 0, stream>>>(vfirst, out_vf);
    gemm_bt<2, 2, 0, 1, 0, 0><<<gBig, 256, 0, stream>>>(AG, Cn, nullptr, WoB, Cn, out_o, nullptr, Cn, nullptr, Cn, Cn);
}

// Round 5
// 637.748 us; speedup vs baseline: 2.3695x; 1.5281x over previous
//
#include <hip/hip_runtime.h>
#include <hip/hip_bf16.h>
#include <cstdint>
#include <cstddef>

// ---------- types & helpers ----------
typedef __attribute__((ext_vector_type(8))) short short8;   // 8 x bf16
typedef __attribute__((ext_vector_type(4))) short short4v;  // 4 x bf16 (8B)
typedef __attribute__((ext_vector_type(4))) float f32x4;

#define DEVINL static __device__ __forceinline__

DEVINL float b2f(unsigned short u) {
    union { unsigned int i; float f; } v; v.i = ((unsigned int)u) << 16; return v.f;
}
DEVINL unsigned short f2b(float f) {
    union { float f; unsigned int i; } v; v.f = f;
    unsigned int x = v.i;
    return (unsigned short)((x + 0x7FFFu + ((x >> 16) & 1u)) >> 16);
}

static constexpr int Bsz = 4, Tn = 1024, Cn = 1024, Hn = 16, Nn = 64;
static constexpr int Mrows = Bsz * Tn;             // 4096
static constexpr size_t MX = (size_t)Mrows * Cn;   // 4,194,304
static constexpr int NCHUNK = 16, CL = 64;         // 16 chunks x 64 steps

// ---------- token-shift premix: f32 x -> 6 bf16 mixed buffers ----------
__global__ __launch_bounds__(256) void k_mix(
    const float* __restrict__ x,
    const float* __restrict__ mr, const float* __restrict__ mw,
    const float* __restrict__ mk, const float* __restrict__ mv,
    const float* __restrict__ ma, const float* __restrict__ mg,
    unsigned short* __restrict__ xr, unsigned short* __restrict__ xw,
    unsigned short* __restrict__ xk, unsigned short* __restrict__ xv,
    unsigned short* __restrict__ xa, unsigned short* __restrict__ xg)
{
    size_t e = ((size_t)blockIdx.x * 256 + threadIdx.x) * 8;
    if (e >= MX) return;
    int c = (int)(e & (Cn - 1));
    int t = (int)((e >> 10) & (Tn - 1));
    float xf[8], d[8];
    {
        f32x4 x0 = *(const f32x4*)(x + e);
        f32x4 x1 = *(const f32x4*)(x + e + 4);
        #pragma unroll
        for (int j = 0; j < 4; ++j) { xf[j] = x0[j]; xf[4 + j] = x1[j]; }
    }
    if (t > 0) {
        f32x4 p0 = *(const f32x4*)(x + e - Cn);
        f32x4 p1 = *(const f32x4*)(x + e - Cn + 4);
        #pragma unroll
        for (int j = 0; j < 4; ++j) { d[j] = p0[j] - xf[j]; d[4 + j] = p1[j] - xf[4 + j]; }
    } else {
        #pragma unroll
        for (int j = 0; j < 8; ++j) d[j] = -xf[j];
    }
    const float* ms[6] = { mr, mw, mk, mv, ma, mg };
    unsigned short* ds[6] = { xr, xw, xk, xv, xa, xg };
    #pragma unroll
    for (int p = 0; p < 6; ++p) {
        f32x4 m0 = *(const f32x4*)(ms[p] + c);
        f32x4 m1 = *(const f32x4*)(ms[p] + c + 4);
        short8 o;
        #pragma unroll
        for (int j = 0; j < 4; ++j) {
            o[j]     = (short)f2b(xf[j]     + d[j]     * m0[j]);
            o[4 + j] = (short)f2b(xf[4 + j] + d[4 + j] * m1[j]);
        }
        *(short8*)(ds[p] + e) = o;
    }
}

// ---------- 4 big weights f32->bf16 in one launch ----------
__global__ __launch_bounds__(256) void k_cvt4(
    const float* __restrict__ s0, const float* __restrict__ s1,
    const float* __restrict__ s2, const float* __restrict__ s3,
    unsigned short* __restrict__ d0, unsigned short* __restrict__ d1,
    unsigned short* __restrict__ d2, unsigned short* __restrict__ d3)
{
    int sel = blockIdx.y;
    const float* in = (sel == 0) ? s0 : (sel == 1) ? s1 : (sel == 2) ? s2 : s3;
    unsigned short* out = (sel == 0) ? d0 : (sel == 1) ? d1 : (sel == 2) ? d2 : d3;
    int i = (blockIdx.x * 256 + threadIdx.x) * 4;
    f32x4 v = *(const f32x4*)(in + i);
    short4v o;
    #pragma unroll
    for (int j = 0; j < 4; ++j) o[j] = (short)f2b(v[j]);
    *(short4v*)(out + i) = o;
}

// ---------- all 8 small-weight transposes (+cvt) in one launch ----------
__global__ __launch_bounds__(256) void k_prep(
    const float* __restrict__ w1, const float* __restrict__ w2,
    const float* __restrict__ a1, const float* __restrict__ a2,
    const float* __restrict__ v1, const float* __restrict__ v2,
    const float* __restrict__ g1, const float* __restrict__ g2,
    unsigned short* __restrict__ w1T, unsigned short* __restrict__ w2T,
    unsigned short* __restrict__ a1T, unsigned short* __restrict__ a2T,
    unsigned short* __restrict__ v1T, unsigned short* __restrict__ v2T,
    unsigned short* __restrict__ g1T, unsigned short* __restrict__ g2T)
{
    int idx = blockIdx.x * 256 + threadIdx.x;
    if (idx < 65536) {                       // w1 [1024][64] -> [64][1024]
        int r = idx >> 6, c = idx & 63;
        w1T[c * 1024 + r] = f2b(w1[idx]);
    } else if (idx < 131072) {               // w2 [64][1024] -> [1024][64]
        int j = idx - 65536; int r = j >> 10, c = j & 1023;
        w2T[c * 64 + r] = f2b(w2[j]);
    } else if (idx < 196608) {               // a1
        int j = idx - 131072; int r = j >> 6, c = j & 63;
        a1T[c * 1024 + r] = f2b(a1[j]);
    } else if (idx < 262144) {               // a2
        int j = idx - 196608; int r = j >> 10, c = j & 1023;
        a2T[c * 64 + r] = f2b(a2[j]);
    } else if (idx < 327680) {               // v1
        int j = idx - 262144; int r = j >> 6, c = j & 63;
        v1T[c * 1024 + r] = f2b(v1[j]);
    } else if (idx < 393216) {               // v2
        int j = idx - 327680; int r = j >> 10, c = j & 1023;
        v2T[c * 64 + r] = f2b(v2[j]);
    } else if (idx < 557056) {               // g1 [1024][160] -> [160][1024]
        int j = idx - 393216; int r = j / 160, c = j - r * 160;
        g1T[c * 1024 + r] = f2b(g1[j]);
    } else if (idx < 720896) {               // g2 [160][1024] -> [1024][160]
        int j = idx - 557056; int r = j >> 10, c = j & 1023;
        g2T[c * 160 + r] = f2b(g2[j]);
    }
}

// ---------- shared MFMA GEMM core: 64x64 wave tile, bf16 A/B ----------
DEVINL void gemm_core(const unsigned short* __restrict__ A, int lda,
                      const unsigned short* __restrict__ Bt, int ldb,
                      int m0, int n0, int N, int K, int r16, int k8,
                      f32x4 (&acc)[4][4])
{
    for (int k0 = 0; k0 < K; k0 += 32) {
        short8 af[4], bf[4];
        #pragma unroll
        for (int mi = 0; mi < 4; ++mi)
            af[mi] = *(const short8*)(A + (size_t)(m0 + mi * 16 + r16) * lda + k0 + k8);
        #pragma unroll
        for (int ni = 0; ni < 4; ++ni) {
            int rn = n0 + ni * 16 + r16;
            if (rn >= N) rn = N - 1;
            bf[ni] = *(const short8*)(Bt + (size_t)rn * ldb + k0 + k8);
        }
        #pragma unroll
        for (int mi = 0; mi < 4; ++mi)
            #pragma unroll
            for (int ni = 0; ni < 4; ++ni)
                acc[mi][ni] = __builtin_amdgcn_mfma_f32_16x16x32_bf16(af[mi], bf[ni], acc[mi][ni], 0, 0, 0);
    }
}

// epi: 0=raw 1=tanh 2=sigmoid 3=bias+sigmoid 4=bias+decay
DEVINL void gemm_epi(f32x4 (&acc)[4][4], int m0, int n0, int N, int ldc,
                     float* Cf, unsigned short* Cb, const float* bias,
                     int lane, int epi, bool outf32)
{
    int r16 = lane & 15;
    #pragma unroll
    for (int mi = 0; mi < 4; ++mi)
        #pragma unroll
        for (int ni = 0; ni < 4; ++ni) {
            int col = n0 + ni * 16 + r16;
            if (col < N) {
                float bv = (epi >= 3) ? bias[col] : 0.f;
                #pragma unroll
                for (int r = 0; r < 4; ++r) {
                    int row = m0 + mi * 16 + (lane >> 4) * 4 + r;
                    float v = acc[mi][ni][r];
                    if (epi == 1) v = tanhf(v);
                    else if (epi == 2) v = 1.f / (1.f + expf(-v));
                    else if (epi == 3) { v += bv; v = 1.f / (1.f + expf(-v)); }
                    else if (epi == 4) { v += bv; v = expf(-0.60653066f / (1.f + expf(-v))); }
                    size_t o = (size_t)row * ldc + col;
                    if (outf32) Cf[o] = v; else Cb[o] = f2b(v);
                }
            }
        }
}

// ---------- R/K/V GEMMs in one launch (grid.z selects) ----------
__global__ __launch_bounds__(256) void gemm_rkv(
    const unsigned short* __restrict__ A0, const unsigned short* __restrict__ A1,
    const unsigned short* __restrict__ A2,
    const unsigned short* __restrict__ B0, const unsigned short* __restrict__ B1,
    const unsigned short* __restrict__ B2,
    unsigned short* __restrict__ D0, unsigned short* __restrict__ D1,
    unsigned short* __restrict__ D2)
{
    int z = blockIdx.z;
    const unsigned short* A = (z == 0) ? A0 : (z == 1) ? A1 : A2;
    const unsigned short* Bt = (z == 0) ? B0 : (z == 1) ? B1 : B2;
    unsigned short* D = (z == 0) ? D0 : (z == 1) ? D1 : D2;
    const int tid = threadIdx.x, wid = tid >> 6, lane = tid & 63;
    const int r16 = lane & 15, k8 = (lane >> 4) * 8;
    const int m0 = blockIdx.x * 128 + (wid >> 1) * 64;
    const int n0 = blockIdx.y * 128 + (wid & 1) * 64;
    f32x4 acc[4][4];
    #pragma unroll
    for (int a = 0; a < 4; ++a)
        #pragma unroll
        for (int b = 0; b < 4; ++b) acc[a][b] = (f32x4){0.f, 0.f, 0.f, 0.f};
    gemm_core(A, Cn, Bt, Cn, m0, n0, Cn, Cn, r16, k8, acc);
    gemm_epi(acc, m0, n0, Cn, Cn, nullptr, D, nullptr, lane, 0, false);
}

// ---------- four tall-skinny stage-1 GEMMs in one launch ----------
__global__ __launch_bounds__(256) void gemm_small1(
    const unsigned short* __restrict__ Aw, const unsigned short* __restrict__ Aa,
    const unsigned short* __restrict__ Av, const unsigned short* __restrict__ Ag,
    const unsigned short* __restrict__ Bw, const unsigned short* __restrict__ Ba,
    const unsigned short* __restrict__ Bv, const unsigned short* __restrict__ Bg,
    unsigned short* __restrict__ Dw, unsigned short* __restrict__ Da,
    unsigned short* __restrict__ Dv, unsigned short* __restrict__ Dg)
{
    int z = blockIdx.z;
    if (z < 3 && blockIdx.y > 0) return;
    const unsigned short* A = (z == 0) ? Aw : (z == 1) ? Aa : (z == 2) ? Av : Ag;
    const unsigned short* Bt = (z == 0) ? Bw : (z == 1) ? Ba : (z == 2) ? Bv : Bg;
    unsigned short* D = (z == 0) ? Dw : (z == 1) ? Da : (z == 2) ? Dv : Dg;
    const int N = (z == 3) ? 160 : 64;
    const int epi = (z == 0) ? 1 : (z == 3) ? 2 : 0;
    const int tid = threadIdx.x, wid = tid >> 6, lane = tid & 63;
    const int r16 = lane & 15, k8 = (lane >> 4) * 8;
    const int m0 = blockIdx.x * 256 + wid * 64;
    const int n0 = blockIdx.y * 64;
    f32x4 acc[4][4];
    #pragma unroll
    for (int a = 0; a < 4; ++a)
        #pragma unroll
        for (int b = 0; b < 4; ++b) acc[a][b] = (f32x4){0.f, 0.f, 0.f, 0.f};
    gemm_core(A, Cn, Bt, Cn, m0, n0, N, Cn, r16, k8, acc);
    gemm_epi(acc, m0, n0, N, N, nullptr, D, nullptr, lane, epi, false);
}

// ---------- generic 128x128-tile GEMM (stage-2 + Wo) ----------
__global__ __launch_bounds__(256) void gemm2(
    const unsigned short* __restrict__ A, int lda,
    const unsigned short* __restrict__ Bt, int ldb,
    float* __restrict__ Cf, unsigned short* __restrict__ Cb, int ldc,
    const float* __restrict__ bias, int K, int epi, int outf32)
{
    const int tid = threadIdx.x, wid = tid >> 6, lane = tid & 63;
    const int r16 = lane & 15, k8 = (lane >> 4) * 8;
    const int m0 = blockIdx.x * 128 + (wid >> 1) * 64;
    const int n0 = blockIdx.y * 128 + (wid & 1) * 64;
    f32x4 acc[4][4];
    #pragma unroll
    for (int a = 0; a < 4; ++a)
        #pragma unroll
        for (int b = 0; b < 4; ++b) acc[a][b] = (f32x4){0.f, 0.f, 0.f, 0.f};
    gemm_core(A, lda, Bt, ldb, m0, n0, Cn, K, r16, k8, acc);
    gemm_epi(acc, m0, n0, Cn, ldc, Cf, Cb, bias, lane, epi, outf32 != 0);
}

// ---------- elementwise stage 1 (bf16 buffers in place; vfirst f32) ----------
__global__ __launch_bounds__(256) void k_elem1(
    unsigned short* __restrict__ Kb, unsigned short* __restrict__ Ab,
    unsigned short* __restrict__ Vb, unsigned short* __restrict__ SVb,
    const float* __restrict__ v_first,
    const float* __restrict__ kkw, const float* __restrict__ kaw)
{
    int tid = threadIdx.x;
    size_t gh = (size_t)blockIdx.x * 4 + (tid >> 6);   // 0 .. B*T*H-1
    int lane = tid & 63;
    int h = (int)(gh & (Hn - 1));
    size_t idx = (gh >> 4) * Cn + (size_t)h * Nn + lane;
    int c = h * Nn + lane;

    float kp = b2f(Kb[idx]);
    float kkv = kp * kkw[c];
    float s = kkv * kkv;
    #pragma unroll
    for (int m = 1; m < 64; m <<= 1) s += __shfl_xor(s, m, 64);
    float kk = kkv / fmaxf(sqrtf(s), 1e-12f);

    float a = b2f(Ab[idx]);
    float kf = kp * (1.f + (a - 1.f) * kaw[c]);
    float vp = b2f(Vb[idx]), sv = b2f(SVb[idx]), vf = v_first[idx];
    float vfin = vp + (vf - vp) * sv;

    Kb[idx] = f2b(kf);
    Vb[idx] = f2b(vfin);
    SVb[idx] = f2b(-kk);
    Ab[idx] = f2b(kk * a);
}

// ================= chunked scan =================
// Phase A: per (chain, chunk): P = prod M_t (M = diag(w)+a b^T), C = local offset.
__global__ __launch_bounds__(256, 1) void kA_chunk(
    const float* __restrict__ Wp, const unsigned short* __restrict__ Kp,
    const unsigned short* __restrict__ Vp, const unsigned short* __restrict__ Ap,
    const unsigned short* __restrict__ Bp,
    float* __restrict__ Pg, float* __restrict__ Cg)
{
    __shared__ float wS[CL][64];
    __shared__ unsigned short kS[CL][64];
    __shared__ unsigned short vS[CL][64];
    __shared__ unsigned short aS[CL][64];
    __shared__ unsigned short bS[CL][64];

    const int tid = threadIdx.x;
    const int bx = blockIdx.x;
    const int bh = bx >> 4, c = bx & 15;
    const size_t base0 = ((size_t)(bh >> 4) * Tn + (size_t)c * CL) * Cn + (size_t)(bh & 15) * Nn;

    {
        const int t = tid >> 2, seg = (tid & 3) * 16;
        const size_t g = base0 + (size_t)t * Cn + seg;
        *(short8*)&kS[t][seg]     = *(const short8*)(Kp + g);
        *(short8*)&kS[t][seg + 8] = *(const short8*)(Kp + g + 8);
        *(short8*)&vS[t][seg]     = *(const short8*)(Vp + g);
        *(short8*)&vS[t][seg + 8] = *(const short8*)(Vp + g + 8);
        *(short8*)&aS[t][seg]     = *(const short8*)(Ap + g);
        *(short8*)&aS[t][seg + 8] = *(const short8*)(Ap + g + 8);
        *(short8*)&bS[t][seg]     = *(const short8*)(Bp + g);
        *(short8*)&bS[t][seg + 8] = *(const short8*)(Bp + g + 8);
        #pragma unroll
        for (int u = 0; u < 4; ++u)
            *(f32x4*)&wS[t][seg + u * 4] = *(const f32x4*)(Wp + g + u * 4);
    }
    __syncthreads();

    const int q = tid & 3, i = tid >> 2;
    float P[16], C[16];
    #pragma unroll
    for (int u = 0; u < 16; ++u) {
        int j = q * 16 + u;
        P[u] = (j == i) ? 1.f : 0.f;
        C[u] = 0.f;
    }

    for (int t = 0; t < CL; ++t) {
        float a16[16], k16[16], b16[16], w16[16];
        short8 t0 = *(const short8*)&aS[t][q * 16];
        short8 t1 = *(const short8*)&aS[t][q * 16 + 8];
        #pragma unroll
        for (int j = 0; j < 8; ++j) { a16[j] = b2f((unsigned short)t0[j]); a16[8 + j] = b2f((unsigned short)t1[j]); }

        float pa = 0.f, ca = 0.f;
        #pragma unroll
        for (int u = 0; u < 16; ++u) { pa += P[u] * a16[u]; ca += C[u] * a16[u]; }
        pa += __shfl_xor(pa, 1, 64); pa += __shfl_xor(pa, 2, 64);
        ca += __shfl_xor(ca, 1, 64); ca += __shfl_xor(ca, 2, 64);

        float vi = b2f(vS[t][i]);
        t0 = *(const short8*)&kS[t][q * 16];
        t1 = *(const short8*)&kS[t][q * 16 + 8];
        #pragma unroll
        for (int j = 0; j < 8; ++j) { k16[j] = b2f((unsigned short)t0[j]); k16[8 + j] = b2f((unsigned short)t1[j]); }
        t0 = *(const short8*)&bS[t][q * 16];
        t1 = *(const short8*)&bS[t][q * 16 + 8];
        #pragma unroll
        for (int j = 0; j < 8; ++j) { b16[j] = b2f((unsigned short)t0[j]); b16[8 + j] = b2f((unsigned short)t1[j]); }
        #pragma unroll
        for (int u = 0; u < 4; ++u) {
            f32x4 w4 = *(const f32x4*)&wS[t][q * 16 + u * 4];
            #pragma unroll
            for (int e = 0; e < 4; ++e) w16[u * 4 + e] = w4[e];
        }

        #pragma unroll
        for (int u = 0; u < 16; ++u) {
            C[u] = C[u] * w16[u] + ca * b16[u] + vi * k16[u];
            P[u] = P[u] * w16[u] + pa * b16[u];
        }
    }

    const size_t ob = (size_t)bx * 4096 + (size_t)i * 64 + q * 16;
    #pragma unroll
    for (int u = 0; u < 4; ++u) {
        *(f32x4*)(Pg + ob + u * 4) = (f32x4){P[u * 4], P[u * 4 + 1], P[u * 4 + 2], P[u * 4 + 3]};
        *(f32x4*)(Cg + ob + u * 4) = (f32x4){C[u * 4], C[u * 4 + 1], C[u * 4 + 2], C[u * 4 + 3]};
    }
}

// Phase B: sequential chunk combine S <- S*P_c + C_c; emit S_init per chunk.
// S kept in regs (row layout) + transposed LDS copy St[m][i] for the m-loop
// (bank = i%32 -> conflict-free broadcast).
__global__ __launch_bounds__(256, 1) void kB_combine(
    const float* __restrict__ Pg, const float* __restrict__ Cg,
    float* __restrict__ Sinit)
{
    __shared__ float St[64 * 68];    // St[m*68 + i] = S[i][m]
    __shared__ float Pl[4096];
    const int tid = threadIdx.x;
    const int bh = blockIdx.x;
    const int i = tid >> 2, q = tid & 3;

    for (int u = tid; u < 64 * 68; u += 256) St[u] = 0.f;

    float Sreg[16];
    #pragma unroll
    for (int u = 0; u < 16; ++u) Sreg[u] = 0.f;
    __syncthreads();

    for (int c = 0; c < NCHUNK; ++c) {
        const size_t ob = ((size_t)(bh * 16 + c)) * 4096;
        // emit S_init for this chunk (from regs)
        #pragma unroll
        for (int u = 0; u < 4; ++u)
            *(f32x4*)(Sinit + ob + (size_t)i * 64 + q * 16 + u * 4) =
                (f32x4){Sreg[u * 4], Sreg[u * 4 + 1], Sreg[u * 4 + 2], Sreg[u * 4 + 3]};
        if (c == NCHUNK - 1) break;

        __syncthreads();   // prior m-loop reads of Pl done
        #pragma unroll
        for (int u = 0; u < 4; ++u)
            *(f32x4*)&Pl[tid * 16 + u * 4] = *(const f32x4*)(Pg + ob + tid * 16 + u * 4);

        float acc[16];
        #pragma unroll
        for (int u = 0; u < 4; ++u) {
            f32x4 cv = *(const f32x4*)(Cg + ob + (size_t)i * 64 + q * 16 + u * 4);
            #pragma unroll
            for (int e = 0; e < 4; ++e) acc[u * 4 + e] = cv[e];
        }
        __syncthreads();   // Pl + St writes visible

        #pragma unroll 8
        for (int m = 0; m < 64; ++m) {
            float s = St[m * 68 + i];
            #pragma unroll
            for (int u = 0; u < 4; ++u) {
                f32x4 p4 = *(const f32x4*)&Pl[m * 64 + q * 16 + u * 4];
                #pragma unroll
                for (int e = 0; e < 4; ++e) acc[u * 4 + e] += s * p4[e];
            }
        }
        __syncthreads();   // m-loop reads of St done before overwrite
        #pragma unroll
        for (int u = 0; u < 16; ++u) {
            Sreg[u] = acc[u];
            St[(q * 16 + u) * 68 + i] = acc[u];
        }
    }
}

// Phase C: per (chain, chunk): run the exact recurrence from S_init, emit y & sa.
__global__ __launch_bounds__(256, 2) void kC_scan(
    const float* __restrict__ Sinit,
    const unsigned short* __restrict__ Rp, const float* __restrict__ Wp,
    const unsigned short* __restrict__ Kp, const unsigned short* __restrict__ Vp,
    const unsigned short* __restrict__ Ap, const unsigned short* __restrict__ Bp,
    float* __restrict__ Yp, float* __restrict__ SAp)
{
    __shared__ float wS[CL][64];
    __shared__ unsigned short rS[CL][64];
    __shared__ unsigned short kS[CL][64];
    __shared__ unsigned short vS[CL][64];
    __shared__ unsigned short aS[CL][64];
    __shared__ unsigned short bS[CL][64];

    const int tid = threadIdx.x;
    const int bx = blockIdx.x;
    const int bh = bx >> 4, c = bx & 15;
    const size_t base0 = ((size_t)(bh >> 4) * Tn + (size_t)c * CL) * Cn + (size_t)(bh & 15) * Nn;

    {
        const int t = tid >> 2, seg = (tid & 3) * 16;
        const size_t g = base0 + (size_t)t * Cn + seg;
        *(short8*)&rS[t][seg]     = *(const short8*)(Rp + g);
        *(short8*)&rS[t][seg + 8] = *(const short8*)(Rp + g + 8);
        *(short8*)&kS[t][seg]     = *(const short8*)(Kp + g);
        *(short8*)&kS[t][seg + 8] = *(const short8*)(Kp + g + 8);
        *(short8*)&vS[t][seg]     = *(const short8*)(Vp + g);
        *(short8*)&vS[t][seg + 8] = *(const short8*)(Vp + g + 8);
        *(short8*)&aS[t][seg]     = *(const short8*)(Ap + g);
        *(short8*)&aS[t][seg + 8] = *(const short8*)(Ap + g + 8);
        *(short8*)&bS[t][seg]     = *(const short8*)(Bp + g);
        *(short8*)&bS[t][seg + 8] = *(const short8*)(Bp + g + 8);
        #pragma unroll
        for (int u = 0; u < 4; ++u)
            *(f32x4*)&wS[t][seg + u * 4] = *(const f32x4*)(Wp + g + u * 4);
    }

    const int q = tid & 3, i = tid >> 2;
    float S[16];
    {
        const size_t sb = (size_t)bx * 4096 + (size_t)i * 64 + q * 16;
        #pragma unroll
        for (int u = 0; u < 4; ++u) {
            f32x4 s4 = *(const f32x4*)(Sinit + sb + u * 4);
            #pragma unroll
            for (int e = 0; e < 4; ++e) S[u * 4 + e] = s4[e];
        }
    }
    __syncthreads();

    float* ybase = Yp + base0 + i;
    float* sabase = SAp + base0 + i;

    for (int t = 0; t < CL; ++t) {
        float a16[16], k16[16], b16[16], w16[16], r16[16];
        short8 t0 = *(const short8*)&aS[t][q * 16];
        short8 t1 = *(const short8*)&aS[t][q * 16 + 8];
        #pragma unroll
        for (int j = 0; j < 8; ++j) { a16[j] = b2f((unsigned short)t0[j]); a16[8 + j] = b2f((unsigned short)t1[j]); }

        float sa = 0.f;
        #pragma unroll
        for (int u = 0; u < 16; ++u) sa += S[u] * a16[u];
        sa += __shfl_xor(sa, 1, 64); sa += __shfl_xor(sa, 2, 64);

        float vi = b2f(vS[t][i]);
        t0 = *(const short8*)&kS[t][q * 16];
        t1 = *(const short8*)&kS[t][q * 16 + 8];
        #pragma unroll
        for (int j = 0; j < 8; ++j) { k16[j] = b2f((unsigned short)t0[j]); k16[8 + j] = b2f((unsigned short)t1[j]); }
        t0 = *(const short8*)&bS[t][q * 16];
        t1 = *(const short8*)&bS[t][q * 16 + 8];
        #pragma unroll
        for (int j = 0; j < 8; ++j) { b16[j] = b2f((unsigned short)t0[j]); b16[8 + j] = b2f((unsigned short)t1[j]); }
        t0 = *(const short8*)&rS[t][q * 16];
        t1 = *(const short8*)&rS[t][q * 16 + 8];
        #pragma unroll
        for (int j = 0; j < 8; ++j) { r16[j] = b2f((unsigned short)t0[j]); r16[8 + j] = b2f((unsigned short)t1[j]); }
        #pragma unroll
        for (int u = 0; u < 4; ++u) {
            f32x4 w4 = *(const f32x4*)&wS[t][q * 16 + u * 4];
            #pragma unroll
            for (int e = 0; e < 4; ++e) w16[u * 4 + e] = w4[e];
        }

        float y = 0.f;
        #pragma unroll
        for (int u = 0; u < 16; ++u) {
            float s = S[u] * w16[u] + sa * b16[u] + vi * k16[u];
            S[u] = s;
            y += s * r16[u];
        }
        y += __shfl_xor(y, 1, 64); y += __shfl_xor(y, 2, 64);

        if (q == 0) {
            ybase[(size_t)t * Cn] = y;
            sabase[(size_t)t * Cn] = sa;
        }
    }
}

// ---------- elementwise stage 2: groupnorm + bonus + (x_att*g) -> AG (bf16) ----------
__global__ __launch_bounds__(256) void k_elem2(
    const float* __restrict__ Yb, const unsigned short* __restrict__ Rb,
    const unsigned short* __restrict__ Kb, const unsigned short* __restrict__ Vb,
    const unsigned short* __restrict__ Gb,
    const float* __restrict__ gnw, const float* __restrict__ gnb,
    const float* __restrict__ rk,
    unsigned short* __restrict__ AG)
{
    int tid = threadIdx.x;
    size_t gh = (size_t)blockIdx.x * 4 + (tid >> 6);
    int lane = tid & 63;
    int h = (int)(gh & (Hn - 1));
    size_t idx = (gh >> 4) * Cn + (size_t)h * Nn + lane;
    int c = h * Nn + lane;

    float y = Yb[idx];
    float s1 = y, s2 = y * y;
    float p = b2f(Rb[idx]) * b2f(Kb[idx]) * rk[c];
    #pragma unroll
    for (int m = 1; m < 64; m <<= 1) {
        s1 += __shfl_xor(s1, m, 64);
        s2 += __shfl_xor(s2, m, 64);
        p  += __shfl_xor(p, m, 64);
    }
    float mean = s1 * (1.f / 64.f);
    float var = s2 * (1.f / 64.f) - mean * mean;
    float xn = (y - mean) * rsqrtf(var + 0.00064f) * gnw[c] + gnb[c];
    float xatt = xn + p * b2f(Vb[idx]);
    AG[idx] = f2b(xatt * b2f(Gb[idx]));
}

// ---------- layernorm of sa_out -> state_rep (f32, in place in d_out) ----------
__global__ __launch_bounds__(256) void k_ln(
    const float* __restrict__ SAp,
    const float* __restrict__ lnw, const float* __restrict__ lnb,
    float* __restrict__ outp)
{
    __shared__ float red1[4], red2[4];
    int tid = threadIdx.x;
    size_t row = blockIdx.x;
    f32x4 v = *(const f32x4*)(SAp + row * Cn + tid * 4);
    float s1 = v[0] + v[1] + v[2] + v[3];
    float s2 = v[0] * v[0] + v[1] * v[1] + v[2] * v[2] + v[3] * v[3];
    #pragma unroll
    for (int m = 1; m < 64; m <<= 1) {
        s1 += __shfl_xor(s1, m, 64);
        s2 += __shfl_xor(s2, m, 64);
    }
    if ((tid & 63) == 0) { red1[tid >> 6] = s1; red2[tid >> 6] = s2; }
    __syncthreads();
    s1 = red1[0] + red1[1] + red1[2] + red1[3];
    s2 = red2[0] + red2[1] + red2[2] + red2[3];
    float mean = s1 * (1.f / 1024.f);
    float var = s2 * (1.f / 1024.f) - mean * mean;
    float rs = rsqrtf(var + 1e-5f);
    f32x4 o;
    #pragma unroll
    for (int u = 0; u < 4; ++u) {
        int c = tid * 4 + u;
        o[u] = (v[u] - mean) * rs * lnw[c] + lnb[c];
    }
    *(f32x4*)(outp + row * Cn + tid * 4) = o;
}

// ---------- v_first passthrough copy (f32) ----------
__global__ __launch_bounds__(256) void k_copy(
    const float* __restrict__ in, float* __restrict__ out)
{
    size_t e = ((size_t)blockIdx.x * 256 + threadIdx.x) * 4;
    if (e < MX) *(f32x4*)(out + e) = *(const f32x4*)(in + e);
}

// ---------- launcher ----------
extern "C" void kernel_launch(void* const* d_in, const int* in_sizes, int n_in,
                              void* d_out, int out_size, void* d_ws, size_t ws_size,
                              hipStream_t stream)
{
    (void)in_sizes; (void)n_in; (void)out_size; (void)ws_size;
    const float* x      = (const float*)d_in[0];
    const float* vfirst = (const float*)d_in[1];
    const float* x_r    = (const float*)d_in[2];
    const float* x_w    = (const float*)d_in[3];
    const float* x_k    = (const float*)d_in[4];
    const float* x_v    = (const float*)d_in[5];
    const float* x_a    = (const float*)d_in[6];
    const float* x_g    = (const float*)d_in[7];
    const float* w0     = (const float*)d_in[8];
    const float* w1     = (const float*)d_in[9];
    const float* w2     = (const float*)d_in[10];
    const float* a0     = (const float*)d_in[11];
    const float* a1     = (const float*)d_in[12];
    const float* a2     = (const float*)d_in[13];
    const float* v0     = (const float*)d_in[14];
    const float* v1     = (const float*)d_in[15];
    const float* v2     = (const float*)d_in[16];
    const float* g1     = (const float*)d_in[17];
    const float* g2     = (const float*)d_in[18];
    const float* k_k    = (const float*)d_in[19];
    const float* k_a    = (const float*)d_in[20];
    const float* r_k    = (const float*)d_in[21];
    const float* Wr     = (const float*)d_in[22];
    const float* Wk     = (const float*)d_in[23];
    const float* Wv     = (const float*)d_in[24];
    const float* Wo     = (const float*)d_in[25];
    const float* gn_w   = (const float*)d_in[26];
    const float* gn_b   = (const float*)d_in[27];
    const float* ln_w   = (const float*)d_in[28];
    const float* ln_b   = (const float*)d_in[29];

    char* ws = (char*)d_ws;
    size_t off = 0;
    auto alloc = [&](size_t bytes) -> void* {
        void* p = ws + off;
        off += (bytes + 255) & ~(size_t)255;
        return p;
    };
    // bf16 big buffers (8 MiB each)
    unsigned short* Rb  = (unsigned short*)alloc(MX * 2);  // raw r; reused as AG
    unsigned short* Kb  = (unsigned short*)alloc(MX * 2);
    unsigned short* Vb  = (unsigned short*)alloc(MX * 2);
    unsigned short* SVb = (unsigned short*)alloc(MX * 2);  // v-gate sigmoid -> aa
    unsigned short* Ab  = (unsigned short*)alloc(MX * 2);  // a sigmoid -> bb
    unsigned short* Gb  = (unsigned short*)alloc(MX * 2);  // g
    float* Wdec = (float*)alloc(MX * 4);                   // decay (f32)
    float* Cg   = (float*)alloc(MX * 4);                   // chunk offsets
    // small intermediates (bf16)
    unsigned short* hw = (unsigned short*)alloc((size_t)Mrows * 64 * 2);
    unsigned short* ha = (unsigned short*)alloc((size_t)Mrows * 64 * 2);
    unsigned short* hv = (unsigned short*)alloc((size_t)Mrows * 64 * 2);
    unsigned short* hg = (unsigned short*)alloc((size_t)Mrows * 160 * 2);
    // bf16 weights
    unsigned short* WrB = (unsigned short*)alloc(1048576 * 2);
    unsigned short* WkB = (unsigned short*)alloc(1048576 * 2);
    unsigned short* WvB = (unsigned short*)alloc(1048576 * 2);
    unsigned short* WoB = (unsigned short*)alloc(1048576 * 2);
    unsigned short* w1T = (unsigned short*)alloc(65536 * 2);
    unsigned short* w2T = (unsigned short*)alloc(65536 * 2);
    unsigned short* a1T = (unsigned short*)alloc(65536 * 2);
    unsigned short* a2T = (unsigned short*)alloc(65536 * 2);
    unsigned short* v1T = (unsigned short*)alloc(65536 * 2);
    unsigned short* v2T = (unsigned short*)alloc(65536 * 2);
    unsigned short* g1T = (unsigned short*)alloc(163840 * 2);
    unsigned short* g2T = (unsigned short*)alloc(163840 * 2);
    // ~92 MiB total

    // premix buffers alias later-written regions (dead before those writes):
    unsigned short* xrB = (unsigned short*)Cg;             // dead before kA writes Cg
    unsigned short* xkB = (unsigned short*)Cg + MX;
    unsigned short* xvB = (unsigned short*)Wdec;           // dead before gemm2-Wdec
    unsigned short* xgB = (unsigned short*)Wdec + MX;
    unsigned short* xwB = Ab;                              // dead before gemm2-Ab
    unsigned short* xaB = Gb;                              // dead before gemm2-Gb

    float* out_o  = (float*)d_out;
    float* out_vf = out_o + MX;
    float* out_sr = out_o + 2 * MX;
    float* Pg    = out_o;                   // phase A transfer mats (dead after kB)
    float* Sinit = out_vf;                  // chunk-initial states (dead after kC)
    float* Yb    = out_o;                   // phase C y (consumed by k_elem2)
    float* SAb   = out_sr;                  // phase C sa (layernormed in place)
    unsigned short* AG = Rb;

    // prep
    k_mix<<<dim3(2048), 256, 0, stream>>>(x, x_r, x_w, x_k, x_v, x_a, x_g,
                                          xrB, xwB, xkB, xvB, xaB, xgB);
    k_cvt4<<<dim3(1024, 4), 256, 0, stream>>>(Wr, Wk, Wv, Wo, WrB, WkB, WvB, WoB);
    k_prep<<<dim3(2816), 256, 0, stream>>>(w1, w2, a1, a2, v1, v2, g1, g2,
                                           w1T, w2T, a1T, a2T, v1T, v2T, g1T, g2T);

    // stage-1 GEMMs (small first: consumes xw/xa/xv/xg before rkv writes R/K/V)
    gemm_small1<<<dim3(16, 3, 4), 256, 0, stream>>>(xwB, xaB, xvB, xgB,
                                                    w1T, a1T, v1T, g1T,
                                                    hw, ha, hv, hg);
    gemm_rkv<<<dim3(32, 8, 3), 256, 0, stream>>>(xrB, xkB, xvB, WrB, WkB, WvB,
                                                 Rb, Kb, Vb);

    // stage-2 small GEMMs
    gemm2<<<dim3(32, 8), 256, 0, stream>>>(hw, 64, w2T, 64, Wdec, nullptr, Cn, w0, 64, 4, 1);
    gemm2<<<dim3(32, 8), 256, 0, stream>>>(ha, 64, a2T, 64, nullptr, Ab, Cn, a0, 64, 3, 0);
    gemm2<<<dim3(32, 8), 256, 0, stream>>>(hv, 64, v2T, 64, nullptr, SVb, Cn, v0, 64, 3, 0);
    gemm2<<<dim3(32, 8), 256, 0, stream>>>(hg, 160, g2T, 160, nullptr, Gb, Cn, nullptr, 160, 0, 0);

    k_elem1<<<dim3(16384), 256, 0, stream>>>(Kb, Ab, Vb, SVb, vfirst, k_k, k_a);

    // chunked scan
    kA_chunk<<<dim3(1024), 256, 0, stream>>>(Wdec, Kb, Vb, SVb, Ab, Pg, Cg);
    kB_combine<<<dim3(64), 256, 0, stream>>>(Pg, Cg, Sinit);
    kC_scan<<<dim3(1024), 256, 0, stream>>>(Sinit, Rb, Wdec, Kb, Vb, SVb, Ab, Yb, SAb);

    k_elem2<<<dim3(16384), 256, 0, stream>>>(Yb, Rb, Kb, Vb, Gb, gn_w, gn_b, r_k, AG);

    // real outputs
    k_ln<<<dim3(4096), 256, 0, stream>>>(SAb, ln_w, ln_b, out_sr);
    k_copy<<<dim3(4096), 256, 0, stream>>>(vfirst, out_vf);
    gemm2<<<dim3(32, 8), 256, 0, stream>>>(AG, Cn, WoB, Cn, out_o, nullptr, Cn, nullptr, Cn, 0, 1);
}

// Round 6
// 536.683 us; speedup vs baseline: 2.8157x; 1.1883x over previous
//
#include <hip/hip_runtime.h>
#include <hip/hip_bf16.h>
#include <cstdint>
#include <cstddef>

// ---------- types & helpers ----------
typedef __attribute__((ext_vector_type(8))) short short8;   // 8 x bf16
typedef __attribute__((ext_vector_type(4))) short short4v;  // 4 x bf16 (8B)
typedef __attribute__((ext_vector_type(4))) float f32x4;

#define DEVINL static __device__ __forceinline__

DEVINL float b2f(unsigned short u) {
    union { unsigned int i; float f; } v; v.i = ((unsigned int)u) << 16; return v.f;
}
DEVINL unsigned short f2b(float f) {
    union { float f; unsigned int i; } v; v.f = f;
    unsigned int x = v.i;
    return (unsigned short)((x + 0x7FFFu + ((x >> 16) & 1u)) >> 16);
}
// hardware cvt (compiler emits single-instr bf16 convert)
DEVINL unsigned short f2bh(float f) {
    __hip_bfloat16 h = __float2bfloat16(f);
    union { __hip_bfloat16 h; unsigned short u; } v; v.h = h; return v.u;
}

static constexpr int Bsz = 4, Tn = 1024, Cn = 1024, Hn = 16, Nn = 64;
static constexpr int Mrows = Bsz * Tn;             // 4096
static constexpr size_t MX = (size_t)Mrows * Cn;   // 4,194,304
static constexpr int NCHUNK = 16, CL = 64;         // 16 chunks x 64 steps

// ---------- token-shift premix: f32 x -> 6 bf16 mixed buffers ----------
__global__ __launch_bounds__(256) void k_mix(
    const float* __restrict__ x,
    const float* __restrict__ mr, const float* __restrict__ mw,
    const float* __restrict__ mk, const float* __restrict__ mv,
    const float* __restrict__ ma, const float* __restrict__ mg,
    unsigned short* __restrict__ xr, unsigned short* __restrict__ xw,
    unsigned short* __restrict__ xk, unsigned short* __restrict__ xv,
    unsigned short* __restrict__ xa, unsigned short* __restrict__ xg)
{
    size_t e = ((size_t)blockIdx.x * 256 + threadIdx.x) * 8;
    if (e >= MX) return;
    int c = (int)(e & (Cn - 1));
    int t = (int)((e >> 10) & (Tn - 1));
    float xf[8], d[8];
    {
        f32x4 x0 = *(const f32x4*)(x + e);
        f32x4 x1 = *(const f32x4*)(x + e + 4);
        #pragma unroll
        for (int j = 0; j < 4; ++j) { xf[j] = x0[j]; xf[4 + j] = x1[j]; }
    }
    if (t > 0) {
        f32x4 p0 = *(const f32x4*)(x + e - Cn);
        f32x4 p1 = *(const f32x4*)(x + e - Cn + 4);
        #pragma unroll
        for (int j = 0; j < 4; ++j) { d[j] = p0[j] - xf[j]; d[4 + j] = p1[j] - xf[4 + j]; }
    } else {
        #pragma unroll
        for (int j = 0; j < 8; ++j) d[j] = -xf[j];
    }
    const float* ms[6] = { mr, mw, mk, mv, ma, mg };
    unsigned short* ds[6] = { xr, xw, xk, xv, xa, xg };
    #pragma unroll
    for (int p = 0; p < 6; ++p) {
        f32x4 m0 = *(const f32x4*)(ms[p] + c);
        f32x4 m1 = *(const f32x4*)(ms[p] + c + 4);
        short8 o;
        #pragma unroll
        for (int j = 0; j < 4; ++j) {
            o[j]     = (short)f2b(xf[j]     + d[j]     * m0[j]);
            o[4 + j] = (short)f2b(xf[4 + j] + d[4 + j] * m1[j]);
        }
        *(short8*)(ds[p] + e) = o;
    }
}

// ---------- 4 big weights f32->bf16 in one launch ----------
__global__ __launch_bounds__(256) void k_cvt4(
    const float* __restrict__ s0, const float* __restrict__ s1,
    const float* __restrict__ s2, const float* __restrict__ s3,
    unsigned short* __restrict__ d0, unsigned short* __restrict__ d1,
    unsigned short* __restrict__ d2, unsigned short* __restrict__ d3)
{
    int sel = blockIdx.y;
    const float* in = (sel == 0) ? s0 : (sel == 1) ? s1 : (sel == 2) ? s2 : s3;
    unsigned short* out = (sel == 0) ? d0 : (sel == 1) ? d1 : (sel == 2) ? d2 : d3;
    int i = (blockIdx.x * 256 + threadIdx.x) * 4;
    f32x4 v = *(const f32x4*)(in + i);
    short4v o;
    #pragma unroll
    for (int j = 0; j < 4; ++j) o[j] = (short)f2b(v[j]);
    *(short4v*)(out + i) = o;
}

// ---------- all 8 small-weight transposes (+cvt) in one launch ----------
__global__ __launch_bounds__(256) void k_prep(
    const float* __restrict__ w1, const float* __restrict__ w2,
    const float* __restrict__ a1, const float* __restrict__ a2,
    const float* __restrict__ v1, const float* __restrict__ v2,
    const float* __restrict__ g1, const float* __restrict__ g2,
    unsigned short* __restrict__ w1T, unsigned short* __restrict__ w2T,
    unsigned short* __restrict__ a1T, unsigned short* __restrict__ a2T,
    unsigned short* __restrict__ v1T, unsigned short* __restrict__ v2T,
    unsigned short* __restrict__ g1T, unsigned short* __restrict__ g2T)
{
    int idx = blockIdx.x * 256 + threadIdx.x;
    if (idx < 65536) {                       // w1 [1024][64] -> [64][1024]
        int r = idx >> 6, c = idx & 63;
        w1T[c * 1024 + r] = f2b(w1[idx]);
    } else if (idx < 131072) {               // w2 [64][1024] -> [1024][64]
        int j = idx - 65536; int r = j >> 10, c = j & 1023;
        w2T[c * 64 + r] = f2b(w2[j]);
    } else if (idx < 196608) {               // a1
        int j = idx - 131072; int r = j >> 6, c = j & 63;
        a1T[c * 1024 + r] = f2b(a1[j]);
    } else if (idx < 262144) {               // a2
        int j = idx - 196608; int r = j >> 10, c = j & 1023;
        a2T[c * 64 + r] = f2b(a2[j]);
    } else if (idx < 327680) {               // v1
        int j = idx - 262144; int r = j >> 6, c = j & 63;
        v1T[c * 1024 + r] = f2b(v1[j]);
    } else if (idx < 393216) {               // v2
        int j = idx - 327680; int r = j >> 10, c = j & 1023;
        v2T[c * 64 + r] = f2b(v2[j]);
    } else if (idx < 557056) {               // g1 [1024][160] -> [160][1024]
        int j = idx - 393216; int r = j / 160, c = j - r * 160;
        g1T[c * 1024 + r] = f2b(g1[j]);
    } else if (idx < 720896) {               // g2 [160][1024] -> [1024][160]
        int j = idx - 557056; int r = j >> 10, c = j & 1023;
        g2T[c * 160 + r] = f2b(g2[j]);
    }
}

// ---------- shared MFMA GEMM core: 64x64 wave tile, bf16 A/B ----------
DEVINL void gemm_core(const unsigned short* __restrict__ A, int lda,
                      const unsigned short* __restrict__ Bt, int ldb,
                      int m0, int n0, int N, int K, int r16, int k8,
                      f32x4 (&acc)[4][4])
{
    for (int k0 = 0; k0 < K; k0 += 32) {
        short8 af[4], bf[4];
        #pragma unroll
        for (int mi = 0; mi < 4; ++mi)
            af[mi] = *(const short8*)(A + (size_t)(m0 + mi * 16 + r16) * lda + k0 + k8);
        #pragma unroll
        for (int ni = 0; ni < 4; ++ni) {
            int rn = n0 + ni * 16 + r16;
            if (rn >= N) rn = N - 1;
            bf[ni] = *(const short8*)(Bt + (size_t)rn * ldb + k0 + k8);
        }
        #pragma unroll
        for (int mi = 0; mi < 4; ++mi)
            #pragma unroll
            for (int ni = 0; ni < 4; ++ni)
                acc[mi][ni] = __builtin_amdgcn_mfma_f32_16x16x32_bf16(af[mi], bf[ni], acc[mi][ni], 0, 0, 0);
    }
}

// epi: 0=raw 1=tanh 2=sigmoid 3=bias+sigmoid 4=bias+decay
DEVINL void gemm_epi(f32x4 (&acc)[4][4], int m0, int n0, int N, int ldc,
                     float* Cf, unsigned short* Cb, const float* bias,
                     int lane, int epi, bool outf32)
{
    int r16 = lane & 15;
    #pragma unroll
    for (int mi = 0; mi < 4; ++mi)
        #pragma unroll
        for (int ni = 0; ni < 4; ++ni) {
            int col = n0 + ni * 16 + r16;
            if (col < N) {
                float bv = (epi >= 3) ? bias[col] : 0.f;
                #pragma unroll
                for (int r = 0; r < 4; ++r) {
                    int row = m0 + mi * 16 + (lane >> 4) * 4 + r;
                    float v = acc[mi][ni][r];
                    if (epi == 1) v = tanhf(v);
                    else if (epi == 2) v = 1.f / (1.f + expf(-v));
                    else if (epi == 3) { v += bv; v = 1.f / (1.f + expf(-v)); }
                    else if (epi == 4) { v += bv; v = expf(-0.60653066f / (1.f + expf(-v))); }
                    size_t o = (size_t)row * ldc + col;
                    if (outf32) Cf[o] = v; else Cb[o] = f2b(v);
                }
            }
        }
}

// ---------- R/K/V GEMMs in one launch (grid.z selects) ----------
__global__ __launch_bounds__(256) void gemm_rkv(
    const unsigned short* __restrict__ A0, const unsigned short* __restrict__ A1,
    const unsigned short* __restrict__ A2,
    const unsigned short* __restrict__ B0, const unsigned short* __restrict__ B1,
    const unsigned short* __restrict__ B2,
    unsigned short* __restrict__ D0, unsigned short* __restrict__ D1,
    unsigned short* __restrict__ D2)
{
    int z = blockIdx.z;
    const unsigned short* A = (z == 0) ? A0 : (z == 1) ? A1 : A2;
    const unsigned short* Bt = (z == 0) ? B0 : (z == 1) ? B1 : B2;
    unsigned short* D = (z == 0) ? D0 : (z == 1) ? D1 : D2;
    const int tid = threadIdx.x, wid = tid >> 6, lane = tid & 63;
    const int r16 = lane & 15, k8 = (lane >> 4) * 8;
    const int m0 = blockIdx.x * 128 + (wid >> 1) * 64;
    const int n0 = blockIdx.y * 128 + (wid & 1) * 64;
    f32x4 acc[4][4];
    #pragma unroll
    for (int a = 0; a < 4; ++a)
        #pragma unroll
        for (int b = 0; b < 4; ++b) acc[a][b] = (f32x4){0.f, 0.f, 0.f, 0.f};
    gemm_core(A, Cn, Bt, Cn, m0, n0, Cn, Cn, r16, k8, acc);
    gemm_epi(acc, m0, n0, Cn, Cn, nullptr, D, nullptr, lane, 0, false);
}

// ---------- four tall-skinny stage-1 GEMMs in one launch ----------
__global__ __launch_bounds__(256) void gemm_small1(
    const unsigned short* __restrict__ Aw, const unsigned short* __restrict__ Aa,
    const unsigned short* __restrict__ Av, const unsigned short* __restrict__ Ag,
    const unsigned short* __restrict__ Bw, const unsigned short* __restrict__ Ba,
    const unsigned short* __restrict__ Bv, const unsigned short* __restrict__ Bg,
    unsigned short* __restrict__ Dw, unsigned short* __restrict__ Da,
    unsigned short* __restrict__ Dv, unsigned short* __restrict__ Dg)
{
    int z = blockIdx.z;
    if (z < 3 && blockIdx.y > 0) return;
    const unsigned short* A = (z == 0) ? Aw : (z == 1) ? Aa : (z == 2) ? Av : Ag;
    const unsigned short* Bt = (z == 0) ? Bw : (z == 1) ? Ba : (z == 2) ? Bv : Bg;
    unsigned short* D = (z == 0) ? Dw : (z == 1) ? Da : (z == 2) ? Dv : Dg;
    const int N = (z == 3) ? 160 : 64;
    const int epi = (z == 0) ? 1 : (z == 3) ? 2 : 0;
    const int tid = threadIdx.x, wid = tid >> 6, lane = tid & 63;
    const int r16 = lane & 15, k8 = (lane >> 4) * 8;
    const int m0 = blockIdx.x * 256 + wid * 64;
    const int n0 = blockIdx.y * 64;
    f32x4 acc[4][4];
    #pragma unroll
    for (int a = 0; a < 4; ++a)
        #pragma unroll
        for (int b = 0; b < 4; ++b) acc[a][b] = (f32x4){0.f, 0.f, 0.f, 0.f};
    gemm_core(A, Cn, Bt, Cn, m0, n0, N, Cn, r16, k8, acc);
    gemm_epi(acc, m0, n0, N, N, nullptr, D, nullptr, lane, epi, false);
}

// ---------- generic 128x128-tile GEMM (stage-2 + Wo) ----------
__global__ __launch_bounds__(256) void gemm2(
    const unsigned short* __restrict__ A, int lda,
    const unsigned short* __restrict__ Bt, int ldb,
    float* __restrict__ Cf, unsigned short* __restrict__ Cb, int ldc,
    const float* __restrict__ bias, int K, int epi, int outf32)
{
    const int tid = threadIdx.x, wid = tid >> 6, lane = tid & 63;
    const int r16 = lane & 15, k8 = (lane >> 4) * 8;
    const int m0 = blockIdx.x * 128 + (wid >> 1) * 64;
    const int n0 = blockIdx.y * 128 + (wid & 1) * 64;
    f32x4 acc[4][4];
    #pragma unroll
    for (int a = 0; a < 4; ++a)
        #pragma unroll
        for (int b = 0; b < 4; ++b) acc[a][b] = (f32x4){0.f, 0.f, 0.f, 0.f};
    gemm_core(A, lda, Bt, ldb, m0, n0, Cn, K, r16, k8, acc);
    gemm_epi(acc, m0, n0, Cn, ldc, Cf, Cb, bias, lane, epi, outf32 != 0);
}

// ---------- elementwise stage 1 (bf16 buffers in place; vfirst f32) ----------
__global__ __launch_bounds__(256) void k_elem1(
    unsigned short* __restrict__ Kb, unsigned short* __restrict__ Ab,
    unsigned short* __restrict__ Vb, unsigned short* __restrict__ SVb,
    const float* __restrict__ v_first,
    const float* __restrict__ kkw, const float* __restrict__ kaw)
{
    int tid = threadIdx.x;
    size_t gh = (size_t)blockIdx.x * 4 + (tid >> 6);   // 0 .. B*T*H-1
    int lane = tid & 63;
    int h = (int)(gh & (Hn - 1));
    size_t idx = (gh >> 4) * Cn + (size_t)h * Nn + lane;
    int c = h * Nn + lane;

    float kp = b2f(Kb[idx]);
    float kkv = kp * kkw[c];
    float s = kkv * kkv;
    #pragma unroll
    for (int m = 1; m < 64; m <<= 1) s += __shfl_xor(s, m, 64);
    float kk = kkv / fmaxf(sqrtf(s), 1e-12f);

    float a = b2f(Ab[idx]);
    float kf = kp * (1.f + (a - 1.f) * kaw[c]);
    float vp = b2f(Vb[idx]), sv = b2f(SVb[idx]), vf = v_first[idx];
    float vfin = vp + (vf - vp) * sv;

    Kb[idx] = f2b(kf);
    Vb[idx] = f2b(vfin);
    SVb[idx] = f2b(-kk);
    Ab[idx] = f2b(kk * a);
}

// ================= chunked scan =================
// Phase A: per (chain, chunk): P = prod M_t (M = diag(w)+a b^T), C = local offset.
__global__ __launch_bounds__(256, 1) void kA_chunk(
    const float* __restrict__ Wp, const unsigned short* __restrict__ Kp,
    const unsigned short* __restrict__ Vp, const unsigned short* __restrict__ Ap,
    const unsigned short* __restrict__ Bp,
    float* __restrict__ Pg, float* __restrict__ Cg)
{
    __shared__ float wS[CL][64];
    __shared__ unsigned short kS[CL][64];
    __shared__ unsigned short vS[CL][64];
    __shared__ unsigned short aS[CL][64];
    __shared__ unsigned short bS[CL][64];

    const int tid = threadIdx.x;
    const int bx = blockIdx.x;
    const int bh = bx >> 4, c = bx & 15;
    const size_t base0 = ((size_t)(bh >> 4) * Tn + (size_t)c * CL) * Cn + (size_t)(bh & 15) * Nn;

    {
        const int t = tid >> 2, seg = (tid & 3) * 16;
        const size_t g = base0 + (size_t)t * Cn + seg;
        *(short8*)&kS[t][seg]     = *(const short8*)(Kp + g);
        *(short8*)&kS[t][seg + 8] = *(const short8*)(Kp + g + 8);
        *(short8*)&vS[t][seg]     = *(const short8*)(Vp + g);
        *(short8*)&vS[t][seg + 8] = *(const short8*)(Vp + g + 8);
        *(short8*)&aS[t][seg]     = *(const short8*)(Ap + g);
        *(short8*)&aS[t][seg + 8] = *(const short8*)(Ap + g + 8);
        *(short8*)&bS[t][seg]     = *(const short8*)(Bp + g);
        *(short8*)&bS[t][seg + 8] = *(const short8*)(Bp + g + 8);
        #pragma unroll
        for (int u = 0; u < 4; ++u)
            *(f32x4*)&wS[t][seg + u * 4] = *(const f32x4*)(Wp + g + u * 4);
    }
    __syncthreads();

    const int q = tid & 3, i = tid >> 2;
    float P[16], C[16];
    #pragma unroll
    for (int u = 0; u < 16; ++u) {
        int j = q * 16 + u;
        P[u] = (j == i) ? 1.f : 0.f;
        C[u] = 0.f;
    }

    for (int t = 0; t < CL; ++t) {
        float a16[16], k16[16], b16[16], w16[16];
        short8 t0 = *(const short8*)&aS[t][q * 16];
        short8 t1 = *(const short8*)&aS[t][q * 16 + 8];
        #pragma unroll
        for (int j = 0; j < 8; ++j) { a16[j] = b2f((unsigned short)t0[j]); a16[8 + j] = b2f((unsigned short)t1[j]); }

        float pa = 0.f, ca = 0.f;
        #pragma unroll
        for (int u = 0; u < 16; ++u) { pa += P[u] * a16[u]; ca += C[u] * a16[u]; }
        pa += __shfl_xor(pa, 1, 64); pa += __shfl_xor(pa, 2, 64);
        ca += __shfl_xor(ca, 1, 64); ca += __shfl_xor(ca, 2, 64);

        float vi = b2f(vS[t][i]);
        t0 = *(const short8*)&kS[t][q * 16];
        t1 = *(const short8*)&kS[t][q * 16 + 8];
        #pragma unroll
        for (int j = 0; j < 8; ++j) { k16[j] = b2f((unsigned short)t0[j]); k16[8 + j] = b2f((unsigned short)t1[j]); }
        t0 = *(const short8*)&bS[t][q * 16];
        t1 = *(const short8*)&bS[t][q * 16 + 8];
        #pragma unroll
        for (int j = 0; j < 8; ++j) { b16[j] = b2f((unsigned short)t0[j]); b16[8 + j] = b2f((unsigned short)t1[j]); }
        #pragma unroll
        for (int u = 0; u < 4; ++u) {
            f32x4 w4 = *(const f32x4*)&wS[t][q * 16 + u * 4];
            #pragma unroll
            for (int e = 0; e < 4; ++e) w16[u * 4 + e] = w4[e];
        }

        #pragma unroll
        for (int u = 0; u < 16; ++u) {
            C[u] = C[u] * w16[u] + ca * b16[u] + vi * k16[u];
            P[u] = P[u] * w16[u] + pa * b16[u];
        }
    }

    const size_t ob = (size_t)bx * 4096 + (size_t)i * 64 + q * 16;
    #pragma unroll
    for (int u = 0; u < 4; ++u) {
        *(f32x4*)(Pg + ob + u * 4) = (f32x4){P[u * 4], P[u * 4 + 1], P[u * 4 + 2], P[u * 4 + 3]};
        *(f32x4*)(Cg + ob + u * 4) = (f32x4){C[u * 4], C[u * 4 + 1], C[u * 4 + 2], C[u * 4 + 3]};
    }
}

// Phase B (MFMA version): sequential chunk combine S <- S*P_c + C_c via matrix
// pipe. S held in MFMA C/D fragment layout in registers; per chunk an LDS
// round-trip converts S -> A-frags and P -> B-frags (PT transposed on write,
// ld=65 -> 2-way conflicts only). hi/lo bf16 split of S AND P (6 MFMA/tile)
// keeps the combine at ~f32 accuracy. Next chunk's P/C prefetched from global.
__global__ __launch_bounds__(256, 1) void kB_combine(
    const float* __restrict__ Pg, const float* __restrict__ Cg,
    float* __restrict__ Sinit)
{
    __shared__ float Sl[64 * 65];    // S rows for A-frags
    __shared__ float PT[64 * 65];    // P^T rows for B-frags
    const int tid = threadIdx.x;
    const int w = tid >> 6;          // wave -> owns S rows [16w,16w+16)
    const int l = tid & 63;
    const int lr = l & 15;
    const int lg = l >> 4;
    const int bh = blockIdx.x;

    // acc[t][r] = S[16w + 4*lg + r][16t + lr]   (C/D layout, 4 col-tiles)
    f32x4 acc[4];
    #pragma unroll
    for (int t = 0; t < 4; ++t) acc[t] = (f32x4){0.f, 0.f, 0.f, 0.f};

    // prefetch chunk 0's P (row-linear) and C (C/D layout)
    f32x4 pr[4]; f32x4 cr[4];
    {
        const size_t ob = (size_t)(bh * 16) * 4096;
        #pragma unroll
        for (int u = 0; u < 4; ++u)
            pr[u] = *(const f32x4*)(Pg + ob + (size_t)tid * 16 + u * 4);
        #pragma unroll
        for (int t = 0; t < 4; ++t)
            #pragma unroll
            for (int r = 0; r < 4; ++r)
                cr[t][r] = Cg[ob + (size_t)(16 * w + 4 * lg + r) * 64 + 16 * t + lr];
    }

    for (int c = 0; c < NCHUNK; ++c) {
        // emit S_init for this chunk
        const size_t ob = (size_t)(bh * 16 + c) * 4096;
        #pragma unroll
        for (int t = 0; t < 4; ++t)
            #pragma unroll
            for (int r = 0; r < 4; ++r)
                Sinit[ob + (size_t)(16 * w + 4 * lg + r) * 64 + 16 * t + lr] = acc[t][r];
        if (c == NCHUNK - 1) break;

        // stage S and P^T into LDS
        #pragma unroll
        for (int t = 0; t < 4; ++t)
            #pragma unroll
            for (int r = 0; r < 4; ++r)
                Sl[(16 * w + 4 * lg + r) * 65 + 16 * t + lr] = acc[t][r];
        {
            const int m = tid >> 2, j0 = (tid & 3) * 16;
            #pragma unroll
            for (int u = 0; u < 4; ++u)
                #pragma unroll
                for (int e = 0; e < 4; ++e)
                    PT[(j0 + u * 4 + e) * 65 + m] = pr[u][e];
        }
        __syncthreads();

        // prefetch next chunk's P/C while we compute
        f32x4 prn[4] = {}, crn[4] = {};
        if (c + 1 < NCHUNK - 1) {
            const size_t obn = (size_t)(bh * 16 + c + 1) * 4096;
            #pragma unroll
            for (int u = 0; u < 4; ++u)
                prn[u] = *(const f32x4*)(Pg + obn + (size_t)tid * 16 + u * 4);
            #pragma unroll
            for (int t = 0; t < 4; ++t)
                #pragma unroll
                for (int r = 0; r < 4; ++r)
                    crn[t][r] = Cg[obn + (size_t)(16 * w + 4 * lg + r) * 64 + 16 * t + lr];
        }

        // A-frags (hi/lo) from Sl: row = 16w+lr, k = 32*k0 + 8*lg .. +7
        short8 ahi[2], alo[2];
        #pragma unroll
        for (int k0 = 0; k0 < 2; ++k0) {
            const float* sp = &Sl[(16 * w + lr) * 65 + k0 * 32 + lg * 8];
            #pragma unroll
            for (int j = 0; j < 8; ++j) {
                float s = sp[j];
                unsigned short h = f2bh(s);
                ahi[k0][j] = (short)h;
                alo[k0][j] = (short)f2bh(s - b2f(h));
            }
        }

        // per output col-tile: B-frags (hi/lo) + 6 MFMA
        #pragma unroll
        for (int t = 0; t < 4; ++t) {
            f32x4 nacc = cr[t];
            #pragma unroll
            for (int k0 = 0; k0 < 2; ++k0) {
                short8 bhi, blo;
                const float* pp = &PT[(16 * t + lr) * 65 + k0 * 32 + lg * 8];
                #pragma unroll
                for (int j = 0; j < 8; ++j) {
                    float p = pp[j];
                    unsigned short h = f2bh(p);
                    bhi[j] = (short)h;
                    blo[j] = (short)f2bh(p - b2f(h));
                }
                nacc = __builtin_amdgcn_mfma_f32_16x16x32_bf16(ahi[k0], bhi, nacc, 0, 0, 0);
                nacc = __builtin_amdgcn_mfma_f32_16x16x32_bf16(ahi[k0], blo, nacc, 0, 0, 0);
                nacc = __builtin_amdgcn_mfma_f32_16x16x32_bf16(alo[k0], bhi, nacc, 0, 0, 0);
            }
            acc[t] = nacc;
        }
        __syncthreads();   // protect Sl/PT before next iteration's writes
        #pragma unroll
        for (int u = 0; u < 4; ++u) { pr[u] = prn[u]; cr[u] = crn[u]; }
    }
}

// Phase C: per (chain, chunk): run the exact recurrence from S_init, emit y & sa.
__global__ __launch_bounds__(256, 2) void kC_scan(
    const float* __restrict__ Sinit,
    const unsigned short* __restrict__ Rp, const float* __restrict__ Wp,
    const unsigned short* __restrict__ Kp, const unsigned short* __restrict__ Vp,
    const unsigned short* __restrict__ Ap, const unsigned short* __restrict__ Bp,
    float* __restrict__ Yp, float* __restrict__ SAp)
{
    __shared__ float wS[CL][64];
    __shared__ unsigned short rS[CL][64];
    __shared__ unsigned short kS[CL][64];
    __shared__ unsigned short vS[CL][64];
    __shared__ unsigned short aS[CL][64];
    __shared__ unsigned short bS[CL][64];

    const int tid = threadIdx.x;
    const int bx = blockIdx.x;
    const int bh = bx >> 4, c = bx & 15;
    const size_t base0 = ((size_t)(bh >> 4) * Tn + (size_t)c * CL) * Cn + (size_t)(bh & 15) * Nn;

    {
        const int t = tid >> 2, seg = (tid & 3) * 16;
        const size_t g = base0 + (size_t)t * Cn + seg;
        *(short8*)&rS[t][seg]     = *(const short8*)(Rp + g);
        *(short8*)&rS[t][seg + 8] = *(const short8*)(Rp + g + 8);
        *(short8*)&kS[t][seg]     = *(const short8*)(Kp + g);
        *(short8*)&kS[t][seg + 8] = *(const short8*)(Kp + g + 8);
        *(short8*)&vS[t][seg]     = *(const short8*)(Vp + g);
        *(short8*)&vS[t][seg + 8] = *(const short8*)(Vp + g + 8);
        *(short8*)&aS[t][seg]     = *(const short8*)(Ap + g);
        *(short8*)&aS[t][seg + 8] = *(const short8*)(Ap + g + 8);
        *(short8*)&bS[t][seg]     = *(const short8*)(Bp + g);
        *(short8*)&bS[t][seg + 8] = *(const short8*)(Bp + g + 8);
        #pragma unroll
        for (int u = 0; u < 4; ++u)
            *(f32x4*)&wS[t][seg + u * 4] = *(const f32x4*)(Wp + g + u * 4);
    }

    const int q = tid & 3, i = tid >> 2;
    float S[16];
    {
        const size_t sb = (size_t)bx * 4096 + (size_t)i * 64 + q * 16;
        #pragma unroll
        for (int u = 0; u < 4; ++u) {
            f32x4 s4 = *(const f32x4*)(Sinit + sb + u * 4);
            #pragma unroll
            for (int e = 0; e < 4; ++e) S[u * 4 + e] = s4[e];
        }
    }
    __syncthreads();

    float* ybase = Yp + base0 + i;
    float* sabase = SAp + base0 + i;

    for (int t = 0; t < CL; ++t) {
        float a16[16], k16[16], b16[16], w16[16], r16[16];
        short8 t0 = *(const short8*)&aS[t][q * 16];
        short8 t1 = *(const short8*)&aS[t][q * 16 + 8];
        #pragma unroll
        for (int j = 0; j < 8; ++j) { a16[j] = b2f((unsigned short)t0[j]); a16[8 + j] = b2f((unsigned short)t1[j]); }

        float sa = 0.f;
        #pragma unroll
        for (int u = 0; u < 16; ++u) sa += S[u] * a16[u];
        sa += __shfl_xor(sa, 1, 64); sa += __shfl_xor(sa, 2, 64);

        float vi = b2f(vS[t][i]);
        t0 = *(const short8*)&kS[t][q * 16];
        t1 = *(const short8*)&kS[t][q * 16 + 8];
        #pragma unroll
        for (int j = 0; j < 8; ++j) { k16[j] = b2f((unsigned short)t0[j]); k16[8 + j] = b2f((unsigned short)t1[j]); }
        t0 = *(const short8*)&bS[t][q * 16];
        t1 = *(const short8*)&bS[t][q * 16 + 8];
        #pragma unroll
        for (int j = 0; j < 8; ++j) { b16[j] = b2f((unsigned short)t0[j]); b16[8 + j] = b2f((unsigned short)t1[j]); }
        t0 = *(const short8*)&rS[t][q * 16];
        t1 = *(const short8*)&rS[t][q * 16 + 8];
        #pragma unroll
        for (int j = 0; j < 8; ++j) { r16[j] = b2f((unsigned short)t0[j]); r16[8 + j] = b2f((unsigned short)t1[j]); }
        #pragma unroll
        for (int u = 0; u < 4; ++u) {
            f32x4 w4 = *(const f32x4*)&wS[t][q * 16 + u * 4];
            #pragma unroll
            for (int e = 0; e < 4; ++e) w16[u * 4 + e] = w4[e];
        }

        float y = 0.f;
        #pragma unroll
        for (int u = 0; u < 16; ++u) {
            float s = S[u] * w16[u] + sa * b16[u] + vi * k16[u];
            S[u] = s;
            y += s * r16[u];
        }
        y += __shfl_xor(y, 1, 64); y += __shfl_xor(y, 2, 64);

        if (q == 0) {
            ybase[(size_t)t * Cn] = y;
            sabase[(size_t)t * Cn] = sa;
        }
    }
}

// ---------- elementwise stage 2: groupnorm + bonus + (x_att*g) -> AG (bf16) ----------
__global__ __launch_bounds__(256) void k_elem2(
    const float* __restrict__ Yb, const unsigned short* __restrict__ Rb,
    const unsigned short* __restrict__ Kb, const unsigned short* __restrict__ Vb,
    const unsigned short* __restrict__ Gb,
    const float* __restrict__ gnw, const float* __restrict__ gnb,
    const float* __restrict__ rk,
    unsigned short* __restrict__ AG)
{
    int tid = threadIdx.x;
    size_t gh = (size_t)blockIdx.x * 4 + (tid >> 6);
    int lane = tid & 63;
    int h = (int)(gh & (Hn - 1));
    size_t idx = (gh >> 4) * Cn + (size_t)h * Nn + lane;
    int c = h * Nn + lane;

    float y = Yb[idx];
    float s1 = y, s2 = y * y;
    float p = b2f(Rb[idx]) * b2f(Kb[idx]) * rk[c];
    #pragma unroll
    for (int m = 1; m < 64; m <<= 1) {
        s1 += __shfl_xor(s1, m, 64);
        s2 += __shfl_xor(s2, m, 64);
        p  += __shfl_xor(p, m, 64);
    }
    float mean = s1 * (1.f / 64.f);
    float var = s2 * (1.f / 64.f) - mean * mean;
    float xn = (y - mean) * rsqrtf(var + 0.00064f) * gnw[c] + gnb[c];
    float xatt = xn + p * b2f(Vb[idx]);
    AG[idx] = f2b(xatt * b2f(Gb[idx]));
}

// ---------- layernorm of sa_out -> state_rep (f32, in place in d_out) ----------
__global__ __launch_bounds__(256) void k_ln(
    const float* __restrict__ SAp,
    const float* __restrict__ lnw, const float* __restrict__ lnb,
    float* __restrict__ outp)
{
    __shared__ float red1[4], red2[4];
    int tid = threadIdx.x;
    size_t row = blockIdx.x;
    f32x4 v = *(const f32x4*)(SAp + row * Cn + tid * 4);
    float s1 = v[0] + v[1] + v[2] + v[3];
    float s2 = v[0] * v[0] + v[1] * v[1] + v[2] * v[2] + v[3] * v[3];
    #pragma unroll
    for (int m = 1; m < 64; m <<= 1) {
        s1 += __shfl_xor(s1, m, 64);
        s2 += __shfl_xor(s2, m, 64);
    }
    if ((tid & 63) == 0) { red1[tid >> 6] = s1; red2[tid >> 6] = s2; }
    __syncthreads();
    s1 = red1[0] + red1[1] + red1[2] + red1[3];
    s2 = red2[0] + red2[1] + red2[2] + red2[3];
    float mean = s1 * (1.f / 1024.f);
    float var = s2 * (1.f / 1024.f) - mean * mean;
    float rs = rsqrtf(var + 1e-5f);
    f32x4 o;
    #pragma unroll
    for (int u = 0; u < 4; ++u) {
        int c = tid * 4 + u;
        o[u] = (v[u] - mean) * rs * lnw[c] + lnb[c];
    }
    *(f32x4*)(outp + row * Cn + tid * 4) = o;
}

// ---------- v_first passthrough copy (f32) ----------
__global__ __launch_bounds__(256) void k_copy(
    const float* __restrict__ in, float* __restrict__ out)
{
    size_t e = ((size_t)blockIdx.x * 256 + threadIdx.x) * 4;
    if (e < MX) *(f32x4*)(out + e) = *(const f32x4*)(in + e);
}

// ---------- launcher ----------
extern "C" void kernel_launch(void* const* d_in, const int* in_sizes, int n_in,
                              void* d_out, int out_size, void* d_ws, size_t ws_size,
                              hipStream_t stream)
{
    (void)in_sizes; (void)n_in; (void)out_size; (void)ws_size;
    const float* x      = (const float*)d_in[0];
    const float* vfirst = (const float*)d_in[1];
    const float* x_r    = (const float*)d_in[2];
    const float* x_w    = (const float*)d_in[3];
    const float* x_k    = (const float*)d_in[4];
    const float* x_v    = (const float*)d_in[5];
    const float* x_a    = (const float*)d_in[6];
    const float* x_g    = (const float*)d_in[7];
    const float* w0     = (const float*)d_in[8];
    const float* w1     = (const float*)d_in[9];
    const float* w2     = (const float*)d_in[10];
    const float* a0     = (const float*)d_in[11];
    const float* a1     = (const float*)d_in[12];
    const float* a2     = (const float*)d_in[13];
    const float* v0     = (const float*)d_in[14];
    const float* v1     = (const float*)d_in[15];
    const float* v2     = (const float*)d_in[16];
    const float* g1     = (const float*)d_in[17];
    const float* g2     = (const float*)d_in[18];
    const float* k_k    = (const float*)d_in[19];
    const float* k_a    = (const float*)d_in[20];
    const float* r_k    = (const float*)d_in[21];
    const float* Wr     = (const float*)d_in[22];
    const float* Wk     = (const float*)d_in[23];
    const float* Wv     = (const float*)d_in[24];
    const float* Wo     = (const float*)d_in[25];
    const float* gn_w   = (const float*)d_in[26];
    const float* gn_b   = (const float*)d_in[27];
    const float* ln_w   = (const float*)d_in[28];
    const float* ln_b   = (const float*)d_in[29];

    char* ws = (char*)d_ws;
    size_t off = 0;
    auto alloc = [&](size_t bytes) -> void* {
        void* p = ws + off;
        off += (bytes + 255) & ~(size_t)255;
        return p;
    };
    // bf16 big buffers (8 MiB each)
    unsigned short* Rb  = (unsigned short*)alloc(MX * 2);  // raw r; reused as AG
    unsigned short* Kb  = (unsigned short*)alloc(MX * 2);
    unsigned short* Vb  = (unsigned short*)alloc(MX * 2);
    unsigned short* SVb = (unsigned short*)alloc(MX * 2);  // v-gate sigmoid -> aa
    unsigned short* Ab  = (unsigned short*)alloc(MX * 2);  // a sigmoid -> bb
    unsigned short* Gb  = (unsigned short*)alloc(MX * 2);  // g
    float* Wdec = (float*)alloc(MX * 4);                   // decay (f32)
    float* Cg   = (float*)alloc(MX * 4);                   // chunk offsets
    // small intermediates (bf16)
    unsigned short* hw = (unsigned short*)alloc((size_t)Mrows * 64 * 2);
    unsigned short* ha = (unsigned short*)alloc((size_t)Mrows * 64 * 2);
    unsigned short* hv = (unsigned short*)alloc((size_t)Mrows * 64 * 2);
    unsigned short* hg = (unsigned short*)alloc((size_t)Mrows * 160 * 2);
    // bf16 weights
    unsigned short* WrB = (unsigned short*)alloc(1048576 * 2);
    unsigned short* WkB = (unsigned short*)alloc(1048576 * 2);
    unsigned short* WvB = (unsigned short*)alloc(1048576 * 2);
    unsigned short* WoB = (unsigned short*)alloc(1048576 * 2);
    unsigned short* w1T = (unsigned short*)alloc(65536 * 2);
    unsigned short* w2T = (unsigned short*)alloc(65536 * 2);
    unsigned short* a1T = (unsigned short*)alloc(65536 * 2);
    unsigned short* a2T = (unsigned short*)alloc(65536 * 2);
    unsigned short* v1T = (unsigned short*)alloc(65536 * 2);
    unsigned short* v2T = (unsigned short*)alloc(65536 * 2);
    unsigned short* g1T = (unsigned short*)alloc(163840 * 2);
    unsigned short* g2T = (unsigned short*)alloc(163840 * 2);
    // ~92 MiB total

    // premix buffers alias later-written regions (dead before those writes):
    unsigned short* xrB = (unsigned short*)Cg;             // dead before kA writes Cg
    unsigned short* xkB = (unsigned short*)Cg + MX;
    unsigned short* xvB = (unsigned short*)Wdec;           // dead before gemm2-Wdec
    unsigned short* xgB = (unsigned short*)Wdec + MX;
    unsigned short* xwB = Ab;                              // dead before gemm2-Ab
    unsigned short* xaB = Gb;                              // dead before gemm2-Gb

    float* out_o  = (float*)d_out;
    float* out_vf = out_o + MX;
    float* out_sr = out_o + 2 * MX;
    float* Pg    = out_o;                   // phase A transfer mats (dead after kB)
    float* Sinit = out_vf;                  // chunk-initial states (dead after kC)
    float* Yb    = out_o;                   // phase C y (consumed by k_elem2)
    float* SAb   = out_sr;                  // phase C sa (layernormed in place)
    unsigned short* AG = Rb;

    // prep
    k_mix<<<dim3(2048), 256, 0, stream>>>(x, x_r, x_w, x_k, x_v, x_a, x_g,
                                          xrB, xwB, xkB, xvB, xaB, xgB);
    k_cvt4<<<dim3(1024, 4), 256, 0, stream>>>(Wr, Wk, Wv, Wo, WrB, WkB, WvB, WoB);
    k_prep<<<dim3(2816), 256, 0, stream>>>(w1, w2, a1, a2, v1, v2, g1, g2,
                                           w1T, w2T, a1T, a2T, v1T, v2T, g1T, g2T);

    // stage-1 GEMMs (small first: consumes xw/xa/xv/xg before rkv writes R/K/V)
    gemm_small1<<<dim3(16, 3, 4), 256, 0, stream>>>(xwB, xaB, xvB, xgB,
                                                    w1T, a1T, v1T, g1T,
                                                    hw, ha, hv, hg);
    gemm_rkv<<<dim3(32, 8, 3), 256, 0, stream>>>(xrB, xkB, xvB, WrB, WkB, WvB,
                                                 Rb, Kb, Vb);

    // stage-2 small GEMMs
    gemm2<<<dim3(32, 8), 256, 0, stream>>>(hw, 64, w2T, 64, Wdec, nullptr, Cn, w0, 64, 4, 1);
    gemm2<<<dim3(32, 8), 256, 0, stream>>>(ha, 64, a2T, 64, nullptr, Ab, Cn, a0, 64, 3, 0);
    gemm2<<<dim3(32, 8), 256, 0, stream>>>(hv, 64, v2T, 64, nullptr, SVb, Cn, v0, 64, 3, 0);
    gemm2<<<dim3(32, 8), 256, 0, stream>>>(hg, 160, g2T, 160, nullptr, Gb, Cn, nullptr, 160, 0, 0);

    k_elem1<<<dim3(16384), 256, 0, stream>>>(Kb, Ab, Vb, SVb, vfirst, k_k, k_a);

    // chunked scan
    kA_chunk<<<dim3(1024), 256, 0, stream>>>(Wdec, Kb, Vb, SVb, Ab, Pg, Cg);
    kB_combine<<<dim3(64), 256, 0, stream>>>(Pg, Cg, Sinit);
    kC_scan<<<dim3(1024), 256, 0, stream>>>(Sinit, Rb, Wdec, Kb, Vb, SVb, Ab, Yb, SAb);

    k_elem2<<<dim3(16384), 256, 0, stream>>>(Yb, Rb, Kb, Vb, Gb, gn_w, gn_b, r_k, AG);

    // real outputs
    k_ln<<<dim3(4096), 256, 0, stream>>>(SAb, ln_w, ln_b, out_sr);
    k_copy<<<dim3(4096), 256, 0, stream>>>(vfirst, out_vf);
    gemm2<<<dim3(32, 8), 256, 0, stream>>>(AG, Cn, WoB, Cn, out_o, nullptr, Cn, nullptr, Cn, 0, 1);
}

// Round 7
// 409.087 us; speedup vs baseline: 3.6939x; 1.3119x over previous
//
#include <hip/hip_runtime.h>
#include <hip/hip_bf16.h>
#include <cstdint>
#include <cstddef>

// ---------- types & helpers ----------
typedef __attribute__((ext_vector_type(8))) short short8;   // 8 x bf16
typedef __attribute__((ext_vector_type(4))) short short4v;  // 4 x bf16 (8B)
typedef __attribute__((ext_vector_type(4))) float f32x4;

#define DEVINL static __device__ __forceinline__

DEVINL float b2f(unsigned short u) {
    union { unsigned int i; float f; } v; v.i = ((unsigned int)u) << 16; return v.f;
}
DEVINL unsigned short f2b(float f) {
    union { float f; unsigned int i; } v; v.f = f;
    unsigned int x = v.i;
    return (unsigned short)((x + 0x7FFFu + ((x >> 16) & 1u)) >> 16);
}
// hardware cvt (compiler emits single-instr bf16 convert)
DEVINL unsigned short f2bh(float f) {
    __hip_bfloat16 h = __float2bfloat16(f);
    union { __hip_bfloat16 h; unsigned short u; } v; v.h = h; return v.u;
}
// async global->LDS, 16B per lane; LDS dest is wave-uniform base + lane*16
DEVINL void stage16(const unsigned short* g, unsigned short* l) {
    __builtin_amdgcn_global_load_lds(
        (const __attribute__((address_space(1))) unsigned int*)g,
        (__attribute__((address_space(3))) unsigned int*)l,
        16, 0, 0);
}

static constexpr int Bsz = 4, Tn = 1024, Cn = 1024, Hn = 16, Nn = 64;
static constexpr int Mrows = Bsz * Tn;             // 4096
static constexpr size_t MX = (size_t)Mrows * Cn;   // 4,194,304
static constexpr int NCHUNK = 16, CL = 64;         // 16 chunks x 64 steps

// ---------- token-shift premix: f32 x -> 6 bf16 mixed buffers ----------
__global__ __launch_bounds__(256) void k_mix(
    const float* __restrict__ x,
    const float* __restrict__ mr, const float* __restrict__ mw,
    const float* __restrict__ mk, const float* __restrict__ mv,
    const float* __restrict__ ma, const float* __restrict__ mg,
    unsigned short* __restrict__ xr, unsigned short* __restrict__ xw,
    unsigned short* __restrict__ xk, unsigned short* __restrict__ xv,
    unsigned short* __restrict__ xa, unsigned short* __restrict__ xg)
{
    size_t e = ((size_t)blockIdx.x * 256 + threadIdx.x) * 8;
    if (e >= MX) return;
    int c = (int)(e & (Cn - 1));
    int t = (int)((e >> 10) & (Tn - 1));
    float xf[8], d[8];
    {
        f32x4 x0 = *(const f32x4*)(x + e);
        f32x4 x1 = *(const f32x4*)(x + e + 4);
        #pragma unroll
        for (int j = 0; j < 4; ++j) { xf[j] = x0[j]; xf[4 + j] = x1[j]; }
    }
    if (t > 0) {
        f32x4 p0 = *(const f32x4*)(x + e - Cn);
        f32x4 p1 = *(const f32x4*)(x + e - Cn + 4);
        #pragma unroll
        for (int j = 0; j < 4; ++j) { d[j] = p0[j] - xf[j]; d[4 + j] = p1[j] - xf[4 + j]; }
    } else {
        #pragma unroll
        for (int j = 0; j < 8; ++j) d[j] = -xf[j];
    }
    const float* ms[6] = { mr, mw, mk, mv, ma, mg };
    unsigned short* ds[6] = { xr, xw, xk, xv, xa, xg };
    #pragma unroll
    for (int p = 0; p < 6; ++p) {
        f32x4 m0 = *(const f32x4*)(ms[p] + c);
        f32x4 m1 = *(const f32x4*)(ms[p] + c + 4);
        short8 o;
        #pragma unroll
        for (int j = 0; j < 4; ++j) {
            o[j]     = (short)f2b(xf[j]     + d[j]     * m0[j]);
            o[4 + j] = (short)f2b(xf[4 + j] + d[4 + j] * m1[j]);
        }
        *(short8*)(ds[p] + e) = o;
    }
}

// ---------- 4 big weights f32->bf16 in one launch ----------
__global__ __launch_bounds__(256) void k_cvt4(
    const float* __restrict__ s0, const float* __restrict__ s1,
    const float* __restrict__ s2, const float* __restrict__ s3,
    unsigned short* __restrict__ d0, unsigned short* __restrict__ d1,
    unsigned short* __restrict__ d2, unsigned short* __restrict__ d3)
{
    int sel = blockIdx.y;
    const float* in = (sel == 0) ? s0 : (sel == 1) ? s1 : (sel == 2) ? s2 : s3;
    unsigned short* out = (sel == 0) ? d0 : (sel == 1) ? d1 : (sel == 2) ? d2 : d3;
    int i = (blockIdx.x * 256 + threadIdx.x) * 4;
    f32x4 v = *(const f32x4*)(in + i);
    short4v o;
    #pragma unroll
    for (int j = 0; j < 4; ++j) o[j] = (short)f2b(v[j]);
    *(short4v*)(out + i) = o;
}

// ---------- all 8 small-weight transposes (+cvt) in one launch ----------
__global__ __launch_bounds__(256) void k_prep(
    const float* __restrict__ w1, const float* __restrict__ w2,
    const float* __restrict__ a1, const float* __restrict__ a2,
    const float* __restrict__ v1, const float* __restrict__ v2,
    const float* __restrict__ g1, const float* __restrict__ g2,
    unsigned short* __restrict__ w1T, unsigned short* __restrict__ w2T,
    unsigned short* __restrict__ a1T, unsigned short* __restrict__ a2T,
    unsigned short* __restrict__ v1T, unsigned short* __restrict__ v2T,
    unsigned short* __restrict__ g1T, unsigned short* __restrict__ g2T)
{
    int idx = blockIdx.x * 256 + threadIdx.x;
    if (idx < 65536) {                       // w1 [1024][64] -> [64][1024]
        int r = idx >> 6, c = idx & 63;
        w1T[c * 1024 + r] = f2b(w1[idx]);
    } else if (idx < 131072) {               // w2 [64][1024] -> [1024][64]
        int j = idx - 65536; int r = j >> 10, c = j & 1023;
        w2T[c * 64 + r] = f2b(w2[j]);
    } else if (idx < 196608) {               // a1
        int j = idx - 131072; int r = j >> 6, c = j & 63;
        a1T[c * 1024 + r] = f2b(a1[j]);
    } else if (idx < 262144) {               // a2
        int j = idx - 196608; int r = j >> 10, c = j & 1023;
        a2T[c * 64 + r] = f2b(a2[j]);
    } else if (idx < 327680) {               // v1
        int j = idx - 262144; int r = j >> 6, c = j & 63;
        v1T[c * 1024 + r] = f2b(v1[j]);
    } else if (idx < 393216) {               // v2
        int j = idx - 327680; int r = j >> 10, c = j & 1023;
        v2T[c * 64 + r] = f2b(v2[j]);
    } else if (idx < 557056) {               // g1 [1024][160] -> [160][1024]
        int j = idx - 393216; int r = j / 160, c = j - r * 160;
        g1T[c * 1024 + r] = f2b(g1[j]);
    } else if (idx < 720896) {               // g2 [160][1024] -> [1024][160]
        int j = idx - 557056; int r = j >> 10, c = j & 1023;
        g2T[c * 160 + r] = f2b(g2[j]);
    }
}

// epi: 0=raw 1=tanh 2=sigmoid 3=bias+sigmoid 4=bias+decay
DEVINL void gemm_epi(f32x4 (&acc)[4][4], int m0, int n0, int N, int ldc,
                     float* Cf, unsigned short* Cb, const float* bias,
                     int lane, int epi, bool outf32)
{
    int r16 = lane & 15;
    #pragma unroll
    for (int mi = 0; mi < 4; ++mi)
        #pragma unroll
        for (int ni = 0; ni < 4; ++ni) {
            int col = n0 + ni * 16 + r16;
            if (col < N) {
                float bv = (epi >= 3) ? bias[col] : 0.f;
                #pragma unroll
                for (int r = 0; r < 4; ++r) {
                    int row = m0 + mi * 16 + (lane >> 4) * 4 + r;
                    float v = acc[mi][ni][r];
                    if (epi == 1) v = tanhf(v);
                    else if (epi == 2) v = 1.f / (1.f + expf(-v));
                    else if (epi == 3) { v += bv; v = 1.f / (1.f + expf(-v)); }
                    else if (epi == 4) { v += bv; v = expf(-0.60653066f / (1.f + expf(-v))); }
                    size_t o = (size_t)row * ldc + col;
                    if (outf32) Cf[o] = v; else Cb[o] = f2b(v);
                }
            }
        }
}

// ---------- LDS-staged GEMM body: 128x128 tile, BK=32, double-buffered,
// global_load_lds width=16 (m97 2-phase structure). M%128==0, N%128==0, K%32==0.
template<int EPI, int OUTF32>
DEVINL void gemm_lds_body(const unsigned short* __restrict__ A, int lda,
                          const unsigned short* __restrict__ Bt, int ldb,
                          float* __restrict__ Cf, unsigned short* __restrict__ Cb,
                          int ldc, const float* __restrict__ bias, int K,
                          int m0, int n0)
{
    __shared__ unsigned short As[2][128 * 32];
    __shared__ unsigned short Bs[2][128 * 32];
    const int tid = threadIdx.x, wid = tid >> 6, lane = tid & 63;
    const int r16 = lane & 15, kg = lane >> 4;
    const int wr = (wid >> 1) * 64, wc = (wid & 1) * 64;

    // staging coords: wave wid, issue j covers LDS elems [wid*1024 + j*512 + lane*8]
    // = tile row (wid*32 + j*16 + (lane>>2)), cols (lane&3)*8 .. +8
    const int srow = wid * 32 + (lane >> 2);
    const int scol = (lane & 3) * 8;
    const int lbase = wid * 1024 + lane * 8;
    const unsigned short* aS = A + (size_t)(m0 + srow) * lda + scol;
    const unsigned short* bS = Bt + (size_t)(n0 + srow) * ldb + scol;

    f32x4 acc[4][4];
    #pragma unroll
    for (int a = 0; a < 4; ++a)
        #pragma unroll
        for (int b = 0; b < 4; ++b) acc[a][b] = (f32x4){0.f, 0.f, 0.f, 0.f};

    const int nk = K >> 5;
    // prologue: stage k=0 into buf 0
    stage16(aS, &As[0][lbase]);
    stage16(aS + (size_t)16 * lda, &As[0][lbase + 512]);
    stage16(bS, &Bs[0][lbase]);
    stage16(bS + (size_t)16 * ldb, &Bs[0][lbase + 512]);
    __syncthreads();

    for (int kk = 0; kk < nk; ++kk) {
        const int buf = kk & 1;
        if (kk + 1 < nk) {   // prefetch next K-tile into other buffer
            const int k0 = (kk + 1) * 32;
            stage16(aS + k0, &As[buf ^ 1][lbase]);
            stage16(aS + k0 + (size_t)16 * lda, &As[buf ^ 1][lbase + 512]);
            stage16(bS + k0, &Bs[buf ^ 1][lbase]);
            stage16(bS + k0 + (size_t)16 * ldb, &Bs[buf ^ 1][lbase + 512]);
        }
        short8 af[4], bf[4];
        #pragma unroll
        for (int mi = 0; mi < 4; ++mi)
            af[mi] = *(const short8*)&As[buf][(wr + mi * 16 + r16) * 32 + kg * 8];
        #pragma unroll
        for (int ni = 0; ni < 4; ++ni)
            bf[ni] = *(const short8*)&Bs[buf][(wc + ni * 16 + r16) * 32 + kg * 8];
        #pragma unroll
        for (int mi = 0; mi < 4; ++mi)
            #pragma unroll
            for (int ni = 0; ni < 4; ++ni)
                acc[mi][ni] = __builtin_amdgcn_mfma_f32_16x16x32_bf16(af[mi], bf[ni], acc[mi][ni], 0, 0, 0);
        __syncthreads();   // drains prefetch vmcnt + protects buffers
    }
    gemm_epi(acc, m0 + wr, n0 + wc, 1 << 30, ldc, Cf, Cb, bias, lane, EPI, OUTF32 != 0);
}

// ---------- R/K/V GEMMs in one launch (grid.z selects), LDS-staged ----------
__global__ __launch_bounds__(256) void gemm_rkv(
    const unsigned short* __restrict__ A0, const unsigned short* __restrict__ A1,
    const unsigned short* __restrict__ A2,
    const unsigned short* __restrict__ B0, const unsigned short* __restrict__ B1,
    const unsigned short* __restrict__ B2,
    unsigned short* __restrict__ D0, unsigned short* __restrict__ D1,
    unsigned short* __restrict__ D2)
{
    int z = blockIdx.z;
    const unsigned short* A = (z == 0) ? A0 : (z == 1) ? A1 : A2;
    const unsigned short* Bt = (z == 0) ? B0 : (z == 1) ? B1 : B2;
    unsigned short* D = (z == 0) ? D0 : (z == 1) ? D1 : D2;
    gemm_lds_body<0, 0>(A, Cn, Bt, Cn, nullptr, D, Cn, nullptr, Cn,
                        blockIdx.x * 128, blockIdx.y * 128);
}

// ---------- generic LDS-staged 128x128 GEMM (stage-2 + Wo) ----------
template<int EPI, int OUTF32>
__global__ __launch_bounds__(256) void gemm2(
    const unsigned short* __restrict__ A, int lda,
    const unsigned short* __restrict__ Bt, int ldb,
    float* __restrict__ Cf, unsigned short* __restrict__ Cb, int ldc,
    const float* __restrict__ bias, int K)
{
    gemm_lds_body<EPI, OUTF32>(A, lda, Bt, ldb, Cf, Cb, ldc, bias, K,
                               blockIdx.x * 128, blockIdx.y * 128);
}

// ---------- direct-global MFMA core (kept for tall-skinny stage-1) ----------
DEVINL void gemm_core(const unsigned short* __restrict__ A, int lda,
                      const unsigned short* __restrict__ Bt, int ldb,
                      int m0, int n0, int N, int K, int r16, int k8,
                      f32x4 (&acc)[4][4])
{
    for (int k0 = 0; k0 < K; k0 += 32) {
        short8 af[4], bf[4];
        #pragma unroll
        for (int mi = 0; mi < 4; ++mi)
            af[mi] = *(const short8*)(A + (size_t)(m0 + mi * 16 + r16) * lda + k0 + k8);
        #pragma unroll
        for (int ni = 0; ni < 4; ++ni) {
            int rn = n0 + ni * 16 + r16;
            if (rn >= N) rn = N - 1;
            bf[ni] = *(const short8*)(Bt + (size_t)rn * ldb + k0 + k8);
        }
        #pragma unroll
        for (int mi = 0; mi < 4; ++mi)
            #pragma unroll
            for (int ni = 0; ni < 4; ++ni)
                acc[mi][ni] = __builtin_amdgcn_mfma_f32_16x16x32_bf16(af[mi], bf[ni], acc[mi][ni], 0, 0, 0);
    }
}

// ---------- four tall-skinny stage-1 GEMMs in one launch ----------
__global__ __launch_bounds__(256) void gemm_small1(
    const unsigned short* __restrict__ Aw, const unsigned short* __restrict__ Aa,
    const unsigned short* __restrict__ Av, const unsigned short* __restrict__ Ag,
    const unsigned short* __restrict__ Bw, const unsigned short* __restrict__ Ba,
    const unsigned short* __restrict__ Bv, const unsigned short* __restrict__ Bg,
    unsigned short* __restrict__ Dw, unsigned short* __restrict__ Da,
    unsigned short* __restrict__ Dv, unsigned short* __restrict__ Dg)
{
    int z = blockIdx.z;
    if (z < 3 && blockIdx.y > 0) return;
    const unsigned short* A = (z == 0) ? Aw : (z == 1) ? Aa : (z == 2) ? Av : Ag;
    const unsigned short* Bt = (z == 0) ? Bw : (z == 1) ? Ba : (z == 2) ? Bv : Bg;
    unsigned short* D = (z == 0) ? Dw : (z == 1) ? Da : (z == 2) ? Dv : Dg;
    const int N = (z == 3) ? 160 : 64;
    const int epi = (z == 0) ? 1 : (z == 3) ? 2 : 0;
    const int tid = threadIdx.x, wid = tid >> 6, lane = tid & 63;
    const int r16 = lane & 15, k8 = (lane >> 4) * 8;
    const int m0 = blockIdx.x * 256 + wid * 64;
    const int n0 = blockIdx.y * 64;
    f32x4 acc[4][4];
    #pragma unroll
    for (int a = 0; a < 4; ++a)
        #pragma unroll
        for (int b = 0; b < 4; ++b) acc[a][b] = (f32x4){0.f, 0.f, 0.f, 0.f};
    gemm_core(A, Cn, Bt, Cn, m0, n0, N, Cn, r16, k8, acc);
    gemm_epi(acc, m0, n0, N, N, nullptr, D, nullptr, lane, epi, false);
}

// ---------- elementwise stage 1 (bf16 buffers in place; vfirst f32) ----------
__global__ __launch_bounds__(256) void k_elem1(
    unsigned short* __restrict__ Kb, unsigned short* __restrict__ Ab,
    unsigned short* __restrict__ Vb, unsigned short* __restrict__ SVb,
    const float* __restrict__ v_first,
    const float* __restrict__ kkw, const float* __restrict__ kaw)
{
    int tid = threadIdx.x;
    size_t gh = (size_t)blockIdx.x * 4 + (tid >> 6);   // 0 .. B*T*H-1
    int lane = tid & 63;
    int h = (int)(gh & (Hn - 1));
    size_t idx = (gh >> 4) * Cn + (size_t)h * Nn + lane;
    int c = h * Nn + lane;

    float kp = b2f(Kb[idx]);
    float kkv = kp * kkw[c];
    float s = kkv * kkv;
    #pragma unroll
    for (int m = 1; m < 64; m <<= 1) s += __shfl_xor(s, m, 64);
    float kk = kkv / fmaxf(sqrtf(s), 1e-12f);

    float a = b2f(Ab[idx]);
    float kf = kp * (1.f + (a - 1.f) * kaw[c]);
    float vp = b2f(Vb[idx]), sv = b2f(SVb[idx]), vf = v_first[idx];
    float vfin = vp + (vf - vp) * sv;

    Kb[idx] = f2b(kf);
    Vb[idx] = f2b(vfin);
    SVb[idx] = f2b(-kk);
    Ab[idx] = f2b(kk * a);
}

// ================= chunked scan =================
// Phase A: per (chain, chunk): P = prod M_t (M = diag(w)+a b^T), C = local offset.
__global__ __launch_bounds__(256, 1) void kA_chunk(
    const float* __restrict__ Wp, const unsigned short* __restrict__ Kp,
    const unsigned short* __restrict__ Vp, const unsigned short* __restrict__ Ap,
    const unsigned short* __restrict__ Bp,
    float* __restrict__ Pg, float* __restrict__ Cg)
{
    __shared__ float wS[CL][64];
    __shared__ unsigned short kS[CL][64];
    __shared__ unsigned short vS[CL][64];
    __shared__ unsigned short aS[CL][64];
    __shared__ unsigned short bS[CL][64];

    const int tid = threadIdx.x;
    const int bx = blockIdx.x;
    const int bh = bx >> 4, c = bx & 15;
    const size_t base0 = ((size_t)(bh >> 4) * Tn + (size_t)c * CL) * Cn + (size_t)(bh & 15) * Nn;

    {
        const int t = tid >> 2, seg = (tid & 3) * 16;
        const size_t g = base0 + (size_t)t * Cn + seg;
        *(short8*)&kS[t][seg]     = *(const short8*)(Kp + g);
        *(short8*)&kS[t][seg + 8] = *(const short8*)(Kp + g + 8);
        *(short8*)&vS[t][seg]     = *(const short8*)(Vp + g);
        *(short8*)&vS[t][seg + 8] = *(const short8*)(Vp + g + 8);
        *(short8*)&aS[t][seg]     = *(const short8*)(Ap + g);
        *(short8*)&aS[t][seg + 8] = *(const short8*)(Ap + g + 8);
        *(short8*)&bS[t][seg]     = *(const short8*)(Bp + g);
        *(short8*)&bS[t][seg + 8] = *(const short8*)(Bp + g + 8);
        #pragma unroll
        for (int u = 0; u < 4; ++u)
            *(f32x4*)&wS[t][seg + u * 4] = *(const f32x4*)(Wp + g + u * 4);
    }
    __syncthreads();

    const int q = tid & 3, i = tid >> 2;
    float P[16], C[16];
    #pragma unroll
    for (int u = 0; u < 16; ++u) {
        int j = q * 16 + u;
        P[u] = (j == i) ? 1.f : 0.f;
        C[u] = 0.f;
    }

    for (int t = 0; t < CL; ++t) {
        float a16[16], k16[16], b16[16], w16[16];
        short8 t0 = *(const short8*)&aS[t][q * 16];
        short8 t1 = *(const short8*)&aS[t][q * 16 + 8];
        #pragma unroll
        for (int j = 0; j < 8; ++j) { a16[j] = b2f((unsigned short)t0[j]); a16[8 + j] = b2f((unsigned short)t1[j]); }

        float pa = 0.f, ca = 0.f;
        #pragma unroll
        for (int u = 0; u < 16; ++u) { pa += P[u] * a16[u]; ca += C[u] * a16[u]; }
        pa += __shfl_xor(pa, 1, 64); pa += __shfl_xor(pa, 2, 64);
        ca += __shfl_xor(ca, 1, 64); ca += __shfl_xor(ca, 2, 64);

        float vi = b2f(vS[t][i]);
        t0 = *(const short8*)&kS[t][q * 16];
        t1 = *(const short8*)&kS[t][q * 16 + 8];
        #pragma unroll
        for (int j = 0; j < 8; ++j) { k16[j] = b2f((unsigned short)t0[j]); k16[8 + j] = b2f((unsigned short)t1[j]); }
        t0 = *(const short8*)&bS[t][q * 16];
        t1 = *(const short8*)&bS[t][q * 16 + 8];
        #pragma unroll
        for (int j = 0; j < 8; ++j) { b16[j] = b2f((unsigned short)t0[j]); b16[8 + j] = b2f((unsigned short)t1[j]); }
        #pragma unroll
        for (int u = 0; u < 4; ++u) {
            f32x4 w4 = *(const f32x4*)&wS[t][q * 16 + u * 4];
            #pragma unroll
            for (int e = 0; e < 4; ++e) w16[u * 4 + e] = w4[e];
        }

        #pragma unroll
        for (int u = 0; u < 16; ++u) {
            C[u] = C[u] * w16[u] + ca * b16[u] + vi * k16[u];
            P[u] = P[u] * w16[u] + pa * b16[u];
        }
    }

    const size_t ob = (size_t)bx * 4096 + (size_t)i * 64 + q * 16;
    #pragma unroll
    for (int u = 0; u < 4; ++u) {
        *(f32x4*)(Pg + ob + u * 4) = (f32x4){P[u * 4], P[u * 4 + 1], P[u * 4 + 2], P[u * 4 + 3]};
        *(f32x4*)(Cg + ob + u * 4) = (f32x4){C[u * 4], C[u * 4 + 1], C[u * 4 + 2], C[u * 4 + 3]};
    }
}

// Phase B (MFMA): sequential chunk combine S <- S*P_c + C_c via matrix pipe.
__global__ __launch_bounds__(256, 1) void kB_combine(
    const float* __restrict__ Pg, const float* __restrict__ Cg,
    float* __restrict__ Sinit)
{
    __shared__ float Sl[64 * 65];    // S rows for A-frags
    __shared__ float PT[64 * 65];    // P^T rows for B-frags
    const int tid = threadIdx.x;
    const int w = tid >> 6;          // wave -> owns S rows [16w,16w+16)
    const int l = tid & 63;
    const int lr = l & 15;
    const int lg = l >> 4;
    const int bh = blockIdx.x;

    f32x4 acc[4];
    #pragma unroll
    for (int t = 0; t < 4; ++t) acc[t] = (f32x4){0.f, 0.f, 0.f, 0.f};

    f32x4 pr[4]; f32x4 cr[4];
    {
        const size_t ob = (size_t)(bh * 16) * 4096;
        #pragma unroll
        for (int u = 0; u < 4; ++u)
            pr[u] = *(const f32x4*)(Pg + ob + (size_t)tid * 16 + u * 4);
        #pragma unroll
        for (int t = 0; t < 4; ++t)
            #pragma unroll
            for (int r = 0; r < 4; ++r)
                cr[t][r] = Cg[ob + (size_t)(16 * w + 4 * lg + r) * 64 + 16 * t + lr];
    }

    for (int c = 0; c < NCHUNK; ++c) {
        const size_t ob = (size_t)(bh * 16 + c) * 4096;
        #pragma unroll
        for (int t = 0; t < 4; ++t)
            #pragma unroll
            for (int r = 0; r < 4; ++r)
                Sinit[ob + (size_t)(16 * w + 4 * lg + r) * 64 + 16 * t + lr] = acc[t][r];
        if (c == NCHUNK - 1) break;

        #pragma unroll
        for (int t = 0; t < 4; ++t)
            #pragma unroll
            for (int r = 0; r < 4; ++r)
                Sl[(16 * w + 4 * lg + r) * 65 + 16 * t + lr] = acc[t][r];
        {
            const int m = tid >> 2, j0 = (tid & 3) * 16;
            #pragma unroll
            for (int u = 0; u < 4; ++u)
                #pragma unroll
                for (int e = 0; e < 4; ++e)
                    PT[(j0 + u * 4 + e) * 65 + m] = pr[u][e];
        }
        __syncthreads();

        f32x4 prn[4] = {}, crn[4] = {};
        if (c + 1 < NCHUNK - 1) {
            const size_t obn = (size_t)(bh * 16 + c + 1) * 4096;
            #pragma unroll
            for (int u = 0; u < 4; ++u)
                prn[u] = *(const f32x4*)(Pg + obn + (size_t)tid * 16 + u * 4);
            #pragma unroll
            for (int t = 0; t < 4; ++t)
                #pragma unroll
                for (int r = 0; r < 4; ++r)
                    crn[t][r] = Cg[obn + (size_t)(16 * w + 4 * lg + r) * 64 + 16 * t + lr];
        }

        short8 ahi[2], alo[2];
        #pragma unroll
        for (int k0 = 0; k0 < 2; ++k0) {
            const float* sp = &Sl[(16 * w + lr) * 65 + k0 * 32 + lg * 8];
            #pragma unroll
            for (int j = 0; j < 8; ++j) {
                float s = sp[j];
                unsigned short h = f2bh(s);
                ahi[k0][j] = (short)h;
                alo[k0][j] = (short)f2bh(s - b2f(h));
            }
        }

        #pragma unroll
        for (int t = 0; t < 4; ++t) {
            f32x4 nacc = cr[t];
            #pragma unroll
            for (int k0 = 0; k0 < 2; ++k0) {
                short8 bhi, blo;
                const float* pp = &PT[(16 * t + lr) * 65 + k0 * 32 + lg * 8];
                #pragma unroll
                for (int j = 0; j < 8; ++j) {
                    float p = pp[j];
                    unsigned short h = f2bh(p);
                    bhi[j] = (short)h;
                    blo[j] = (short)f2bh(p - b2f(h));
                }
                nacc = __builtin_amdgcn_mfma_f32_16x16x32_bf16(ahi[k0], bhi, nacc, 0, 0, 0);
                nacc = __builtin_amdgcn_mfma_f32_16x16x32_bf16(ahi[k0], blo, nacc, 0, 0, 0);
                nacc = __builtin_amdgcn_mfma_f32_16x16x32_bf16(alo[k0], bhi, nacc, 0, 0, 0);
            }
            acc[t] = nacc;
        }
        __syncthreads();
        #pragma unroll
        for (int u = 0; u < 4; ++u) { pr[u] = prn[u]; cr[u] = crn[u]; }
    }
}

// Phase C: per (chain, chunk): run the exact recurrence from S_init, emit y & sa.
__global__ __launch_bounds__(256, 2) void kC_scan(
    const float* __restrict__ Sinit,
    const unsigned short* __restrict__ Rp, const float* __restrict__ Wp,
    const unsigned short* __restrict__ Kp, const unsigned short* __restrict__ Vp,
    const unsigned short* __restrict__ Ap, const unsigned short* __restrict__ Bp,
    float* __restrict__ Yp, float* __restrict__ SAp)
{
    __shared__ float wS[CL][64];
    __shared__ unsigned short rS[CL][64];
    __shared__ unsigned short kS[CL][64];
    __shared__ unsigned short vS[CL][64];
    __shared__ unsigned short aS[CL][64];
    __shared__ unsigned short bS[CL][64];

    const int tid = threadIdx.x;
    const int bx = blockIdx.x;
    const int bh = bx >> 4, c = bx & 15;
    const size_t base0 = ((size_t)(bh >> 4) * Tn + (size_t)c * CL) * Cn + (size_t)(bh & 15) * Nn;

    {
        const int t = tid >> 2, seg = (tid & 3) * 16;
        const size_t g = base0 + (size_t)t * Cn + seg;
        *(short8*)&rS[t][seg]     = *(const short8*)(Rp + g);
        *(short8*)&rS[t][seg + 8] = *(const short8*)(Rp + g + 8);
        *(short8*)&kS[t][seg]     = *(const short8*)(Kp + g);
        *(short8*)&kS[t][seg + 8] = *(const short8*)(Kp + g + 8);
        *(short8*)&vS[t][seg]     = *(const short8*)(Vp + g);
        *(short8*)&vS[t][seg + 8] = *(const short8*)(Vp + g + 8);
        *(short8*)&aS[t][seg]     = *(const short8*)(Ap + g);
        *(short8*)&aS[t][seg + 8] = *(const short8*)(Ap + g + 8);
        *(short8*)&bS[t][seg]     = *(const short8*)(Bp + g);
        *(short8*)&bS[t][seg + 8] = *(const short8*)(Bp + g + 8);
        #pragma unroll
        for (int u = 0; u < 4; ++u)
            *(f32x4*)&wS[t][seg + u * 4] = *(const f32x4*)(Wp + g + u * 4);
    }

    const int q = tid & 3, i = tid >> 2;
    float S[16];
    {
        const size_t sb = (size_t)bx * 4096 + (size_t)i * 64 + q * 16;
        #pragma unroll
        for (int u = 0; u < 4; ++u) {
            f32x4 s4 = *(const f32x4*)(Sinit + sb + u * 4);
            #pragma unroll
            for (int e = 0; e < 4; ++e) S[u * 4 + e] = s4[e];
        }
    }
    __syncthreads();

    float* ybase = Yp + base0 + i;
    float* sabase = SAp + base0 + i;

    for (int t = 0; t < CL; ++t) {
        float a16[16], k16[16], b16[16], w16[16], r16[16];
        short8 t0 = *(const short8*)&aS[t][q * 16];
        short8 t1 = *(const short8*)&aS[t][q * 16 + 8];
        #pragma unroll
        for (int j = 0; j < 8; ++j) { a16[j] = b2f((unsigned short)t0[j]); a16[8 + j] = b2f((unsigned short)t1[j]); }

        float sa = 0.f;
        #pragma unroll
        for (int u = 0; u < 16; ++u) sa += S[u] * a16[u];
        sa += __shfl_xor(sa, 1, 64); sa += __shfl_xor(sa, 2, 64);

        float vi = b2f(vS[t][i]);
        t0 = *(const short8*)&kS[t][q * 16];
        t1 = *(const short8*)&kS[t][q * 16 + 8];
        #pragma unroll
        for (int j = 0; j < 8; ++j) { k16[j] = b2f((unsigned short)t0[j]); k16[8 + j] = b2f((unsigned short)t1[j]); }
        t0 = *(const short8*)&bS[t][q * 16];
        t1 = *(const short8*)&bS[t][q * 16 + 8];
        #pragma unroll
        for (int j = 0; j < 8; ++j) { b16[j] = b2f((unsigned short)t0[j]); b16[8 + j] = b2f((unsigned short)t1[j]); }
        t0 = *(const short8*)&rS[t][q * 16];
        t1 = *(const short8*)&rS[t][q * 16 + 8];
        #pragma unroll
        for (int j = 0; j < 8; ++j) { r16[j] = b2f((unsigned short)t0[j]); r16[8 + j] = b2f((unsigned short)t1[j]); }
        #pragma unroll
        for (int u = 0; u < 4; ++u) {
            f32x4 w4 = *(const f32x4*)&wS[t][q * 16 + u * 4];
            #pragma unroll
            for (int e = 0; e < 4; ++e) w16[u * 4 + e] = w4[e];
        }

        float y = 0.f;
        #pragma unroll
        for (int u = 0; u < 16; ++u) {
            float s = S[u] * w16[u] + sa * b16[u] + vi * k16[u];
            S[u] = s;
            y += s * r16[u];
        }
        y += __shfl_xor(y, 1, 64); y += __shfl_xor(y, 2, 64);

        if (q == 0) {
            ybase[(size_t)t * Cn] = y;
            sabase[(size_t)t * Cn] = sa;
        }
    }
}

// ---------- elementwise stage 2: groupnorm + bonus + (x_att*g) -> AG (bf16) ----------
__global__ __launch_bounds__(256) void k_elem2(
    const float* __restrict__ Yb, const unsigned short* __restrict__ Rb,
    const unsigned short* __restrict__ Kb, const unsigned short* __restrict__ Vb,
    const unsigned short* __restrict__ Gb,
    const float* __restrict__ gnw, const float* __restrict__ gnb,
    const float* __restrict__ rk,
    unsigned short* __restrict__ AG)
{
    int tid = threadIdx.x;
    size_t gh = (size_t)blockIdx.x * 4 + (tid >> 6);
    int lane = tid & 63;
    int h = (int)(gh & (Hn - 1));
    size_t idx = (gh >> 4) * Cn + (size_t)h * Nn + lane;
    int c = h * Nn + lane;

    float y = Yb[idx];
    float s1 = y, s2 = y * y;
    float p = b2f(Rb[idx]) * b2f(Kb[idx]) * rk[c];
    #pragma unroll
    for (int m = 1; m < 64; m <<= 1) {
        s1 += __shfl_xor(s1, m, 64);
        s2 += __shfl_xor(s2, m, 64);
        p  += __shfl_xor(p, m, 64);
    }
    float mean = s1 * (1.f / 64.f);
    float var = s2 * (1.f / 64.f) - mean * mean;
    float xn = (y - mean) * rsqrtf(var + 0.00064f) * gnw[c] + gnb[c];
    float xatt = xn + p * b2f(Vb[idx]);
    AG[idx] = f2b(xatt * b2f(Gb[idx]));
}

// ---------- layernorm of sa_out -> state_rep (f32, in place in d_out) ----------
__global__ __launch_bounds__(256) void k_ln(
    const float* __restrict__ SAp,
    const float* __restrict__ lnw, const float* __restrict__ lnb,
    float* __restrict__ outp)
{
    __shared__ float red1[4], red2[4];
    int tid = threadIdx.x;
    size_t row = blockIdx.x;
    f32x4 v = *(const f32x4*)(SAp + row * Cn + tid * 4);
    float s1 = v[0] + v[1] + v[2] + v[3];
    float s2 = v[0] * v[0] + v[1] * v[1] + v[2] * v[2] + v[3] * v[3];
    #pragma unroll
    for (int m = 1; m < 64; m <<= 1) {
        s1 += __shfl_xor(s1, m, 64);
        s2 += __shfl_xor(s2, m, 64);
    }
    if ((tid & 63) == 0) { red1[tid >> 6] = s1; red2[tid >> 6] = s2; }
    __syncthreads();
    s1 = red1[0] + red1[1] + red1[2] + red1[3];
    s2 = red2[0] + red2[1] + red2[2] + red2[3];
    float mean = s1 * (1.f / 1024.f);
    float var = s2 * (1.f / 1024.f) - mean * mean;
    float rs = rsqrtf(var + 1e-5f);
    f32x4 o;
    #pragma unroll
    for (int u = 0; u < 4; ++u) {
        int c = tid * 4 + u;
        o[u] = (v[u] - mean) * rs * lnw[c] + lnb[c];
    }
    *(f32x4*)(outp + row * Cn + tid * 4) = o;
}

// ---------- v_first passthrough copy (f32) ----------
__global__ __launch_bounds__(256) void k_copy(
    const float* __restrict__ in, float* __restrict__ out)
{
    size_t e = ((size_t)blockIdx.x * 256 + threadIdx.x) * 4;
    if (e < MX) *(f32x4*)(out + e) = *(const f32x4*)(in + e);
}

// ---------- launcher ----------
extern "C" void kernel_launch(void* const* d_in, const int* in_sizes, int n_in,
                              void* d_out, int out_size, void* d_ws, size_t ws_size,
                              hipStream_t stream)
{
    (void)in_sizes; (void)n_in; (void)out_size; (void)ws_size;
    const float* x      = (const float*)d_in[0];
    const float* vfirst = (const float*)d_in[1];
    const float* x_r    = (const float*)d_in[2];
    const float* x_w    = (const float*)d_in[3];
    const float* x_k    = (const float*)d_in[4];
    const float* x_v    = (const float*)d_in[5];
    const float* x_a    = (const float*)d_in[6];
    const float* x_g    = (const float*)d_in[7];
    const float* w0     = (const float*)d_in[8];
    const float* w1     = (const float*)d_in[9];
    const float* w2     = (const float*)d_in[10];
    const float* a0     = (const float*)d_in[11];
    const float* a1     = (const float*)d_in[12];
    const float* a2     = (const float*)d_in[13];
    const float* v0     = (const float*)d_in[14];
    const float* v1     = (const float*)d_in[15];
    const float* v2     = (const float*)d_in[16];
    const float* g1     = (const float*)d_in[17];
    const float* g2     = (const float*)d_in[18];
    const float* k_k    = (const float*)d_in[19];
    const float* k_a    = (const float*)d_in[20];
    const float* r_k    = (const float*)d_in[21];
    const float* Wr     = (const float*)d_in[22];
    const float* Wk     = (const float*)d_in[23];
    const float* Wv     = (const float*)d_in[24];
    const float* Wo     = (const float*)d_in[25];
    const float* gn_w   = (const float*)d_in[26];
    const float* gn_b   = (const float*)d_in[27];
    const float* ln_w   = (const float*)d_in[28];
    const float* ln_b   = (const float*)d_in[29];

    char* ws = (char*)d_ws;
    size_t off = 0;
    auto alloc = [&](size_t bytes) -> void* {
        void* p = ws + off;
        off += (bytes + 255) & ~(size_t)255;
        return p;
    };
    // bf16 big buffers (8 MiB each)
    unsigned short* Rb  = (unsigned short*)alloc(MX * 2);  // raw r; reused as AG
    unsigned short* Kb  = (unsigned short*)alloc(MX * 2);
    unsigned short* Vb  = (unsigned short*)alloc(MX * 2);
    unsigned short* SVb = (unsigned short*)alloc(MX * 2);  // v-gate sigmoid -> aa
    unsigned short* Ab  = (unsigned short*)alloc(MX * 2);  // a sigmoid -> bb
    unsigned short* Gb  = (unsigned short*)alloc(MX * 2);  // g
    float* Wdec = (float*)alloc(MX * 4);                   // decay (f32)
    float* Cg   = (float*)alloc(MX * 4);                   // chunk offsets
    // small intermediates (bf16)
    unsigned short* hw = (unsigned short*)alloc((size_t)Mrows * 64 * 2);
    unsigned short* ha = (unsigned short*)alloc((size_t)Mrows * 64 * 2);
    unsigned short* hv = (unsigned short*)alloc((size_t)Mrows * 64 * 2);
    unsigned short* hg = (unsigned short*)alloc((size_t)Mrows * 160 * 2);
    // bf16 weights
    unsigned short* WrB = (unsigned short*)alloc(1048576 * 2);
    unsigned short* WkB = (unsigned short*)alloc(1048576 * 2);
    unsigned short* WvB = (unsigned short*)alloc(1048576 * 2);
    unsigned short* WoB = (unsigned short*)alloc(1048576 * 2);
    unsigned short* w1T = (unsigned short*)alloc(65536 * 2);
    unsigned short* w2T = (unsigned short*)alloc(65536 * 2);
    unsigned short* a1T = (unsigned short*)alloc(65536 * 2);
    unsigned short* a2T = (unsigned short*)alloc(65536 * 2);
    unsigned short* v1T = (unsigned short*)alloc(65536 * 2);
    unsigned short* v2T = (unsigned short*)alloc(65536 * 2);
    unsigned short* g1T = (unsigned short*)alloc(163840 * 2);
    unsigned short* g2T = (unsigned short*)alloc(163840 * 2);
    // ~92 MiB total

    // premix buffers alias later-written regions (dead before those writes):
    unsigned short* xrB = (unsigned short*)Cg;             // dead before kA writes Cg
    unsigned short* xkB = (unsigned short*)Cg + MX;
    unsigned short* xvB = (unsigned short*)Wdec;           // dead before gemm2-Wdec
    unsigned short* xgB = (unsigned short*)Wdec + MX;
    unsigned short* xwB = Ab;                              // dead before gemm2-Ab
    unsigned short* xaB = Gb;                              // dead before gemm2-Gb

    float* out_o  = (float*)d_out;
    float* out_vf = out_o + MX;
    float* out_sr = out_o + 2 * MX;
    float* Pg    = out_o;                   // phase A transfer mats (dead after kB)
    float* Sinit = out_vf;                  // chunk-initial states (dead after kC)
    float* Yb    = out_o;                   // phase C y (consumed by k_elem2)
    float* SAb   = out_sr;                  // phase C sa (layernormed in place)
    unsigned short* AG = Rb;

    // prep
    k_mix<<<dim3(2048), 256, 0, stream>>>(x, x_r, x_w, x_k, x_v, x_a, x_g,
                                          xrB, xwB, xkB, xvB, xaB, xgB);
    k_cvt4<<<dim3(1024, 4), 256, 0, stream>>>(Wr, Wk, Wv, Wo, WrB, WkB, WvB, WoB);
    k_prep<<<dim3(2816), 256, 0, stream>>>(w1, w2, a1, a2, v1, v2, g1, g2,
                                           w1T, w2T, a1T, a2T, v1T, v2T, g1T, g2T);

    // stage-1 GEMMs (small first: consumes xw/xa/xv/xg before rkv writes R/K/V)
    gemm_small1<<<dim3(16, 3, 4), 256, 0, stream>>>(xwB, xaB, xvB, xgB,
                                                    w1T, a1T, v1T, g1T,
                                                    hw, ha, hv, hg);
    gemm_rkv<<<dim3(32, 8, 3), 256, 0, stream>>>(xrB, xkB, xvB, WrB, WkB, WvB,
                                                 Rb, Kb, Vb);

    // stage-2 small GEMMs (LDS-staged)
    gemm2<4, 1><<<dim3(32, 8), 256, 0, stream>>>(hw, 64, w2T, 64, Wdec, nullptr, Cn, w0, 64);
    gemm2<3, 0><<<dim3(32, 8), 256, 0, stream>>>(ha, 64, a2T, 64, nullptr, Ab, Cn, a0, 64);
    gemm2<3, 0><<<dim3(32, 8), 256, 0, stream>>>(hv, 64, v2T, 64, nullptr, SVb, Cn, v0, 64);
    gemm2<0, 0><<<dim3(32, 8), 256, 0, stream>>>(hg, 160, g2T, 160, nullptr, Gb, Cn, nullptr, 160);

    k_elem1<<<dim3(16384), 256, 0, stream>>>(Kb, Ab, Vb, SVb, vfirst, k_k, k_a);

    // chunked scan
    kA_chunk<<<dim3(1024), 256, 0, stream>>>(Wdec, Kb, Vb, SVb, Ab, Pg, Cg);
    kB_combine<<<dim3(64), 256, 0, stream>>>(Pg, Cg, Sinit);
    kC_scan<<<dim3(1024), 256, 0, stream>>>(Sinit, Rb, Wdec, Kb, Vb, SVb, Ab, Yb, SAb);

    k_elem2<<<dim3(16384), 256, 0, stream>>>(Yb, Rb, Kb, Vb, Gb, gn_w, gn_b, r_k, AG);

    // real outputs
    k_ln<<<dim3(4096), 256, 0, stream>>>(SAb, ln_w, ln_b, out_sr);
    k_copy<<<dim3(4096), 256, 0, stream>>>(vfirst, out_vf);
    gemm2<0, 1><<<dim3(32, 8), 256, 0, stream>>>(AG, Cn, WoB, Cn, out_o, nullptr, Cn, nullptr, Cn);
}

// Round 8
// 401.182 us; speedup vs baseline: 3.7667x; 1.0197x over previous
//
#include <hip/hip_runtime.h>
#include <hip/hip_bf16.h>
#include <cstdint>
#include <cstddef>

// ---------- types & helpers ----------
typedef __attribute__((ext_vector_type(8))) short short8;   // 8 x bf16
typedef __attribute__((ext_vector_type(4))) short short4v;  // 4 x bf16 (8B)
typedef __attribute__((ext_vector_type(4))) float f32x4;

#define DEVINL static __device__ __forceinline__

DEVINL float b2f(unsigned short u) {
    union { unsigned int i; float f; } v; v.i = ((unsigned int)u) << 16; return v.f;
}
DEVINL unsigned short f2b(float f) {
    union { float f; unsigned int i; } v; v.f = f;
    unsigned int x = v.i;
    return (unsigned short)((x + 0x7FFFu + ((x >> 16) & 1u)) >> 16);
}
// hardware cvt (compiler emits single-instr bf16 convert)
DEVINL unsigned short f2bh(float f) {
    __hip_bfloat16 h = __float2bfloat16(f);
    union { __hip_bfloat16 h; unsigned short u; } v; v.h = h; return v.u;
}
// short8 (8 bf16) -> two f32x4
DEVINL void cv8(short8 h, f32x4& lo, f32x4& hi) {
    #pragma unroll
    for (int j = 0; j < 4; ++j) {
        lo[j] = b2f((unsigned short)h[j]);
        hi[j] = b2f((unsigned short)h[j + 4]);
    }
}
// async global->LDS, 16B per lane; LDS dest is wave-uniform base + lane*16
DEVINL void stage16(const unsigned short* g, unsigned short* l) {
    __builtin_amdgcn_global_load_lds(
        (const __attribute__((address_space(1))) unsigned int*)g,
        (__attribute__((address_space(3))) unsigned int*)l,
        16, 0, 0);
}

static constexpr int Bsz = 4, Tn = 1024, Cn = 1024, Hn = 16, Nn = 64;
static constexpr int Mrows = Bsz * Tn;             // 4096
static constexpr size_t MX = (size_t)Mrows * Cn;   // 4,194,304
static constexpr int NCHUNK = 16, CL = 64;         // 16 chunks x 64 steps

// ---------- token-shift premix: f32 x -> 6 bf16 mixed buffers ----------
__global__ __launch_bounds__(256) void k_mix(
    const float* __restrict__ x,
    const float* __restrict__ mr, const float* __restrict__ mw,
    const float* __restrict__ mk, const float* __restrict__ mv,
    const float* __restrict__ ma, const float* __restrict__ mg,
    unsigned short* __restrict__ xr, unsigned short* __restrict__ xw,
    unsigned short* __restrict__ xk, unsigned short* __restrict__ xv,
    unsigned short* __restrict__ xa, unsigned short* __restrict__ xg)
{
    size_t e = ((size_t)blockIdx.x * 256 + threadIdx.x) * 8;
    if (e >= MX) return;
    int c = (int)(e & (Cn - 1));
    int t = (int)((e >> 10) & (Tn - 1));
    float xf[8], d[8];
    {
        f32x4 x0 = *(const f32x4*)(x + e);
        f32x4 x1 = *(const f32x4*)(x + e + 4);
        #pragma unroll
        for (int j = 0; j < 4; ++j) { xf[j] = x0[j]; xf[4 + j] = x1[j]; }
    }
    if (t > 0) {
        f32x4 p0 = *(const f32x4*)(x + e - Cn);
        f32x4 p1 = *(const f32x4*)(x + e - Cn + 4);
        #pragma unroll
        for (int j = 0; j < 4; ++j) { d[j] = p0[j] - xf[j]; d[4 + j] = p1[j] - xf[4 + j]; }
    } else {
        #pragma unroll
        for (int j = 0; j < 8; ++j) d[j] = -xf[j];
    }
    const float* ms[6] = { mr, mw, mk, mv, ma, mg };
    unsigned short* ds[6] = { xr, xw, xk, xv, xa, xg };
    #pragma unroll
    for (int p = 0; p < 6; ++p) {
        f32x4 m0 = *(const f32x4*)(ms[p] + c);
        f32x4 m1 = *(const f32x4*)(ms[p] + c + 4);
        short8 o;
        #pragma unroll
        for (int j = 0; j < 4; ++j) {
            o[j]     = (short)f2b(xf[j]     + d[j]     * m0[j]);
            o[4 + j] = (short)f2b(xf[4 + j] + d[4 + j] * m1[j]);
        }
        *(short8*)(ds[p] + e) = o;
    }
}

// ---------- 4 big weights f32->bf16 in one launch ----------
__global__ __launch_bounds__(256) void k_cvt4(
    const float* __restrict__ s0, const float* __restrict__ s1,
    const float* __restrict__ s2, const float* __restrict__ s3,
    unsigned short* __restrict__ d0, unsigned short* __restrict__ d1,
    unsigned short* __restrict__ d2, unsigned short* __restrict__ d3)
{
    int sel = blockIdx.y;
    const float* in = (sel == 0) ? s0 : (sel == 1) ? s1 : (sel == 2) ? s2 : s3;
    unsigned short* out = (sel == 0) ? d0 : (sel == 1) ? d1 : (sel == 2) ? d2 : d3;
    int i = (blockIdx.x * 256 + threadIdx.x) * 4;
    f32x4 v = *(const f32x4*)(in + i);
    short4v o;
    #pragma unroll
    for (int j = 0; j < 4; ++j) o[j] = (short)f2b(v[j]);
    *(short4v*)(out + i) = o;
}

// ---------- all 8 small-weight transposes (+cvt) in one launch ----------
__global__ __launch_bounds__(256) void k_prep(
    const float* __restrict__ w1, const float* __restrict__ w2,
    const float* __restrict__ a1, const float* __restrict__ a2,
    const float* __restrict__ v1, const float* __restrict__ v2,
    const float* __restrict__ g1, const float* __restrict__ g2,
    unsigned short* __restrict__ w1T, unsigned short* __restrict__ w2T,
    unsigned short* __restrict__ a1T, unsigned short* __restrict__ a2T,
    unsigned short* __restrict__ v1T, unsigned short* __restrict__ v2T,
    unsigned short* __restrict__ g1T, unsigned short* __restrict__ g2T)
{
    int idx = blockIdx.x * 256 + threadIdx.x;
    if (idx < 65536) {                       // w1 [1024][64] -> [64][1024]
        int r = idx >> 6, c = idx & 63;
        w1T[c * 1024 + r] = f2b(w1[idx]);
    } else if (idx < 131072) {               // w2 [64][1024] -> [1024][64]
        int j = idx - 65536; int r = j >> 10, c = j & 1023;
        w2T[c * 64 + r] = f2b(w2[j]);
    } else if (idx < 196608) {               // a1
        int j = idx - 131072; int r = j >> 6, c = j & 63;
        a1T[c * 1024 + r] = f2b(a1[j]);
    } else if (idx < 262144) {               // a2
        int j = idx - 196608; int r = j >> 10, c = j & 1023;
        a2T[c * 64 + r] = f2b(a2[j]);
    } else if (idx < 327680) {               // v1
        int j = idx - 262144; int r = j >> 6, c = j & 63;
        v1T[c * 1024 + r] = f2b(v1[j]);
    } else if (idx < 393216) {               // v2
        int j = idx - 327680; int r = j >> 10, c = j & 1023;
        v2T[c * 64 + r] = f2b(v2[j]);
    } else if (idx < 557056) {               // g1 [1024][160] -> [160][1024]
        int j = idx - 393216; int r = j / 160, c = j - r * 160;
        g1T[c * 1024 + r] = f2b(g1[j]);
    } else if (idx < 720896) {               // g2 [160][1024] -> [1024][160]
        int j = idx - 557056; int r = j >> 10, c = j & 1023;
        g2T[c * 160 + r] = f2b(g2[j]);
    }
}

// epi: 0=raw 1=tanh 2=sigmoid 3=bias+sigmoid 4=bias+decay
DEVINL void gemm_epi(f32x4 (&acc)[4][4], int m0, int n0, int N, int ldc,
                     float* Cf, unsigned short* Cb, const float* bias,
                     int lane, int epi, bool outf32)
{
    int r16 = lane & 15;
    #pragma unroll
    for (int mi = 0; mi < 4; ++mi)
        #pragma unroll
        for (int ni = 0; ni < 4; ++ni) {
            int col = n0 + ni * 16 + r16;
            if (col < N) {
                float bv = (epi >= 3) ? bias[col] : 0.f;
                #pragma unroll
                for (int r = 0; r < 4; ++r) {
                    int row = m0 + mi * 16 + (lane >> 4) * 4 + r;
                    float v = acc[mi][ni][r];
                    if (epi == 1) v = tanhf(v);
                    else if (epi == 2) v = 1.f / (1.f + expf(-v));
                    else if (epi == 3) { v += bv; v = 1.f / (1.f + expf(-v)); }
                    else if (epi == 4) { v += bv; v = expf(-0.60653066f / (1.f + expf(-v))); }
                    size_t o = (size_t)row * ldc + col;
                    if (outf32) Cf[o] = v; else Cb[o] = f2b(v);
                }
            }
        }
}

// ---------- LDS-staged GEMM body: 128x128 tile, BK=32, double-buffered ----------
template<int EPI, int OUTF32>
DEVINL void gemm_lds_body(const unsigned short* __restrict__ A, int lda,
                          const unsigned short* __restrict__ Bt, int ldb,
                          float* __restrict__ Cf, unsigned short* __restrict__ Cb,
                          int ldc, const float* __restrict__ bias, int K,
                          int m0, int n0)
{
    __shared__ unsigned short As[2][128 * 32];
    __shared__ unsigned short Bs[2][128 * 32];
    const int tid = threadIdx.x, wid = tid >> 6, lane = tid & 63;
    const int r16 = lane & 15, kg = lane >> 4;
    const int wr = (wid >> 1) * 64, wc = (wid & 1) * 64;

    const int srow = wid * 32 + (lane >> 2);
    const int scol = (lane & 3) * 8;
    const int lbase = wid * 1024 + lane * 8;
    const unsigned short* aS = A + (size_t)(m0 + srow) * lda + scol;
    const unsigned short* bS = Bt + (size_t)(n0 + srow) * ldb + scol;

    f32x4 acc[4][4];
    #pragma unroll
    for (int a = 0; a < 4; ++a)
        #pragma unroll
        for (int b = 0; b < 4; ++b) acc[a][b] = (f32x4){0.f, 0.f, 0.f, 0.f};

    const int nk = K >> 5;
    stage16(aS, &As[0][lbase]);
    stage16(aS + (size_t)16 * lda, &As[0][lbase + 512]);
    stage16(bS, &Bs[0][lbase]);
    stage16(bS + (size_t)16 * ldb, &Bs[0][lbase + 512]);
    __syncthreads();

    for (int kk = 0; kk < nk; ++kk) {
        const int buf = kk & 1;
        if (kk + 1 < nk) {
            const int k0 = (kk + 1) * 32;
            stage16(aS + k0, &As[buf ^ 1][lbase]);
            stage16(aS + k0 + (size_t)16 * lda, &As[buf ^ 1][lbase + 512]);
            stage16(bS + k0, &Bs[buf ^ 1][lbase]);
            stage16(bS + k0 + (size_t)16 * ldb, &Bs[buf ^ 1][lbase + 512]);
        }
        short8 af[4], bf[4];
        #pragma unroll
        for (int mi = 0; mi < 4; ++mi)
            af[mi] = *(const short8*)&As[buf][(wr + mi * 16 + r16) * 32 + kg * 8];
        #pragma unroll
        for (int ni = 0; ni < 4; ++ni)
            bf[ni] = *(const short8*)&Bs[buf][(wc + ni * 16 + r16) * 32 + kg * 8];
        #pragma unroll
        for (int mi = 0; mi < 4; ++mi)
            #pragma unroll
            for (int ni = 0; ni < 4; ++ni)
                acc[mi][ni] = __builtin_amdgcn_mfma_f32_16x16x32_bf16(af[mi], bf[ni], acc[mi][ni], 0, 0, 0);
        __syncthreads();
    }
    gemm_epi(acc, m0 + wr, n0 + wc, 1 << 30, ldc, Cf, Cb, bias, lane, EPI, OUTF32 != 0);
}

// ---------- R/K/V GEMMs in one launch (grid.z selects), LDS-staged ----------
__global__ __launch_bounds__(256) void gemm_rkv(
    const unsigned short* __restrict__ A0, const unsigned short* __restrict__ A1,
    const unsigned short* __restrict__ A2,
    const unsigned short* __restrict__ B0, const unsigned short* __restrict__ B1,
    const unsigned short* __restrict__ B2,
    unsigned short* __restrict__ D0, unsigned short* __restrict__ D1,
    unsigned short* __restrict__ D2)
{
    int z = blockIdx.z;
    const unsigned short* A = (z == 0) ? A0 : (z == 1) ? A1 : A2;
    const unsigned short* Bt = (z == 0) ? B0 : (z == 1) ? B1 : B2;
    unsigned short* D = (z == 0) ? D0 : (z == 1) ? D1 : D2;
    gemm_lds_body<0, 0>(A, Cn, Bt, Cn, nullptr, D, Cn, nullptr, Cn,
                        blockIdx.x * 128, blockIdx.y * 128);
}

// ---------- generic LDS-staged 128x128 GEMM (stage-2 + Wo) ----------
template<int EPI, int OUTF32>
__global__ __launch_bounds__(256) void gemm2(
    const unsigned short* __restrict__ A, int lda,
    const unsigned short* __restrict__ Bt, int ldb,
    float* __restrict__ Cf, unsigned short* __restrict__ Cb, int ldc,
    const float* __restrict__ bias, int K)
{
    gemm_lds_body<EPI, OUTF32>(A, lda, Bt, ldb, Cf, Cb, ldc, bias, K,
                               blockIdx.x * 128, blockIdx.y * 128);
}

// ---------- direct-global MFMA core (kept for tall-skinny stage-1) ----------
DEVINL void gemm_core(const unsigned short* __restrict__ A, int lda,
                      const unsigned short* __restrict__ Bt, int ldb,
                      int m0, int n0, int N, int K, int r16, int k8,
                      f32x4 (&acc)[4][4])
{
    for (int k0 = 0; k0 < K; k0 += 32) {
        short8 af[4], bf[4];
        #pragma unroll
        for (int mi = 0; mi < 4; ++mi)
            af[mi] = *(const short8*)(A + (size_t)(m0 + mi * 16 + r16) * lda + k0 + k8);
        #pragma unroll
        for (int ni = 0; ni < 4; ++ni) {
            int rn = n0 + ni * 16 + r16;
            if (rn >= N) rn = N - 1;
            bf[ni] = *(const short8*)(Bt + (size_t)rn * ldb + k0 + k8);
        }
        #pragma unroll
        for (int mi = 0; mi < 4; ++mi)
            #pragma unroll
            for (int ni = 0; ni < 4; ++ni)
                acc[mi][ni] = __builtin_amdgcn_mfma_f32_16x16x32_bf16(af[mi], bf[ni], acc[mi][ni], 0, 0, 0);
    }
}

// ---------- four tall-skinny stage-1 GEMMs in one launch ----------
__global__ __launch_bounds__(256) void gemm_small1(
    const unsigned short* __restrict__ Aw, const unsigned short* __restrict__ Aa,
    const unsigned short* __restrict__ Av, const unsigned short* __restrict__ Ag,
    const unsigned short* __restrict__ Bw, const unsigned short* __restrict__ Ba,
    const unsigned short* __restrict__ Bv, const unsigned short* __restrict__ Bg,
    unsigned short* __restrict__ Dw, unsigned short* __restrict__ Da,
    unsigned short* __restrict__ Dv, unsigned short* __restrict__ Dg)
{
    int z = blockIdx.z;
    if (z < 3 && blockIdx.y > 0) return;
    const unsigned short* A = (z == 0) ? Aw : (z == 1) ? Aa : (z == 2) ? Av : Ag;
    const unsigned short* Bt = (z == 0) ? Bw : (z == 1) ? Ba : (z == 2) ? Bv : Bg;
    unsigned short* D = (z == 0) ? Dw : (z == 1) ? Da : (z == 2) ? Dv : Dg;
    const int N = (z == 3) ? 160 : 64;
    const int epi = (z == 0) ? 1 : (z == 3) ? 2 : 0;
    const int tid = threadIdx.x, wid = tid >> 6, lane = tid & 63;
    const int r16 = lane & 15, k8 = (lane >> 4) * 8;
    const int m0 = blockIdx.x * 256 + wid * 64;
    const int n0 = blockIdx.y * 64;
    f32x4 acc[4][4];
    #pragma unroll
    for (int a = 0; a < 4; ++a)
        #pragma unroll
        for (int b = 0; b < 4; ++b) acc[a][b] = (f32x4){0.f, 0.f, 0.f, 0.f};
    gemm_core(A, Cn, Bt, Cn, m0, n0, N, Cn, r16, k8, acc);
    gemm_epi(acc, m0, n0, N, N, nullptr, D, nullptr, lane, epi, false);
}

// ---------- elementwise stage 1 (bf16 buffers in place; vfirst f32) ----------
__global__ __launch_bounds__(256) void k_elem1(
    unsigned short* __restrict__ Kb, unsigned short* __restrict__ Ab,
    unsigned short* __restrict__ Vb, unsigned short* __restrict__ SVb,
    const float* __restrict__ v_first,
    const float* __restrict__ kkw, const float* __restrict__ kaw)
{
    int tid = threadIdx.x;
    size_t gh = (size_t)blockIdx.x * 4 + (tid >> 6);   // 0 .. B*T*H-1
    int lane = tid & 63;
    int h = (int)(gh & (Hn - 1));
    size_t idx = (gh >> 4) * Cn + (size_t)h * Nn + lane;
    int c = h * Nn + lane;

    float kp = b2f(Kb[idx]);
    float kkv = kp * kkw[c];
    float s = kkv * kkv;
    #pragma unroll
    for (int m = 1; m < 64; m <<= 1) s += __shfl_xor(s, m, 64);
    float kk = kkv / fmaxf(sqrtf(s), 1e-12f);

    float a = b2f(Ab[idx]);
    float kf = kp * (1.f + (a - 1.f) * kaw[c]);
    float vp = b2f(Vb[idx]), sv = b2f(SVb[idx]), vf = v_first[idx];
    float vfin = vp + (vf - vp) * sv;

    Kb[idx] = f2b(kf);
    Vb[idx] = f2b(vfin);
    SVb[idx] = f2b(-kk);
    Ab[idx] = f2b(kk * a);
}

// ================= chunked scan =================
// Phase A (512 thr): per (chain, chunk): P = prod M_t, C = local offset.
// Thread (i=tid>>3, o=tid&7) owns row i, cols o*8..o*8+8 (vector f32x4 pairs).
__global__ __launch_bounds__(512) void kA_chunk(
    const float* __restrict__ Wp, const unsigned short* __restrict__ Kp,
    const unsigned short* __restrict__ Vp, const unsigned short* __restrict__ Ap,
    const unsigned short* __restrict__ Bp,
    float* __restrict__ Pg, float* __restrict__ Cg)
{
    __shared__ float wS[CL][64];             // 16KB
    __shared__ unsigned short kS[CL][64];    // 8KB each
    __shared__ unsigned short vS[CL][64];
    __shared__ unsigned short aS[CL][64];
    __shared__ unsigned short bS[CL][64];    // total 48KB -> 3 blocks/CU

    const int tid = threadIdx.x;
    const int bx = blockIdx.x;
    const int bh = bx >> 4, c = bx & 15;
    const size_t base0 = ((size_t)(bh >> 4) * Tn + (size_t)c * CL) * Cn + (size_t)(bh & 15) * Nn;

    {
        const int t = tid >> 3, seg = (tid & 7) * 8;
        const size_t g = base0 + (size_t)t * Cn + seg;
        *(short8*)&kS[t][seg] = *(const short8*)(Kp + g);
        *(short8*)&vS[t][seg] = *(const short8*)(Vp + g);
        *(short8*)&aS[t][seg] = *(const short8*)(Ap + g);
        *(short8*)&bS[t][seg] = *(const short8*)(Bp + g);
        *(f32x4*)&wS[t][seg]     = *(const f32x4*)(Wp + g);
        *(f32x4*)&wS[t][seg + 4] = *(const f32x4*)(Wp + g + 4);
    }
    __syncthreads();

    const int o = tid & 7, i = tid >> 3;
    f32x4 P0, P1, C0, C1;
    #pragma unroll
    for (int u = 0; u < 4; ++u) {
        P0[u] = (o * 8 + u == i) ? 1.f : 0.f;
        P1[u] = (o * 8 + 4 + u == i) ? 1.f : 0.f;
    }
    C0 = (f32x4){0.f, 0.f, 0.f, 0.f};
    C1 = C0;

    for (int t = 0; t < CL; ++t) {
        f32x4 a0, a1;
        cv8(*(const short8*)&aS[t][o * 8], a0, a1);
        f32x4 dp = P0 * a0 + P1 * a1;
        f32x4 dc = C0 * a0 + C1 * a1;
        float pa = dp[0] + dp[1] + dp[2] + dp[3];
        float ca = dc[0] + dc[1] + dc[2] + dc[3];
        pa += __shfl_xor(pa, 1, 64); pa += __shfl_xor(pa, 2, 64); pa += __shfl_xor(pa, 4, 64);
        ca += __shfl_xor(ca, 1, 64); ca += __shfl_xor(ca, 2, 64); ca += __shfl_xor(ca, 4, 64);

        float vi = b2f(vS[t][i]);
        f32x4 k0, k1, b0, b1;
        cv8(*(const short8*)&kS[t][o * 8], k0, k1);
        cv8(*(const short8*)&bS[t][o * 8], b0, b1);
        f32x4 w0 = *(const f32x4*)&wS[t][o * 8];
        f32x4 w1 = *(const f32x4*)&wS[t][o * 8 + 4];

        C0 = C0 * w0 + b0 * ca + k0 * vi;
        C1 = C1 * w1 + b1 * ca + k1 * vi;
        P0 = P0 * w0 + b0 * pa;
        P1 = P1 * w1 + b1 * pa;
    }

    const size_t ob = (size_t)bx * 4096 + (size_t)i * 64 + o * 8;
    *(f32x4*)(Pg + ob)     = P0;
    *(f32x4*)(Pg + ob + 4) = P1;
    *(f32x4*)(Cg + ob)     = C0;
    *(f32x4*)(Cg + ob + 4) = C1;
}

// Phase B (MFMA): sequential chunk combine S <- S*P_c + C_c via matrix pipe.
__global__ __launch_bounds__(256, 1) void kB_combine(
    const float* __restrict__ Pg, const float* __restrict__ Cg,
    float* __restrict__ Sinit)
{
    __shared__ float Sl[64 * 65];
    __shared__ float PT[64 * 65];
    const int tid = threadIdx.x;
    const int w = tid >> 6;
    const int l = tid & 63;
    const int lr = l & 15;
    const int lg = l >> 4;
    const int bh = blockIdx.x;

    f32x4 acc[4];
    #pragma unroll
    for (int t = 0; t < 4; ++t) acc[t] = (f32x4){0.f, 0.f, 0.f, 0.f};

    f32x4 pr[4]; f32x4 cr[4];
    {
        const size_t ob = (size_t)(bh * 16) * 4096;
        #pragma unroll
        for (int u = 0; u < 4; ++u)
            pr[u] = *(const f32x4*)(Pg + ob + (size_t)tid * 16 + u * 4);
        #pragma unroll
        for (int t = 0; t < 4; ++t)
            #pragma unroll
            for (int r = 0; r < 4; ++r)
                cr[t][r] = Cg[ob + (size_t)(16 * w + 4 * lg + r) * 64 + 16 * t + lr];
    }

    for (int c = 0; c < NCHUNK; ++c) {
        const size_t ob = (size_t)(bh * 16 + c) * 4096;
        #pragma unroll
        for (int t = 0; t < 4; ++t)
            #pragma unroll
            for (int r = 0; r < 4; ++r)
                Sinit[ob + (size_t)(16 * w + 4 * lg + r) * 64 + 16 * t + lr] = acc[t][r];
        if (c == NCHUNK - 1) break;

        #pragma unroll
        for (int t = 0; t < 4; ++t)
            #pragma unroll
            for (int r = 0; r < 4; ++r)
                Sl[(16 * w + 4 * lg + r) * 65 + 16 * t + lr] = acc[t][r];
        {
            const int m = tid >> 2, j0 = (tid & 3) * 16;
            #pragma unroll
            for (int u = 0; u < 4; ++u)
                #pragma unroll
                for (int e = 0; e < 4; ++e)
                    PT[(j0 + u * 4 + e) * 65 + m] = pr[u][e];
        }
        __syncthreads();

        f32x4 prn[4] = {}, crn[4] = {};
        if (c + 1 < NCHUNK - 1) {
            const size_t obn = (size_t)(bh * 16 + c + 1) * 4096;
            #pragma unroll
            for (int u = 0; u < 4; ++u)
                prn[u] = *(const f32x4*)(Pg + obn + (size_t)tid * 16 + u * 4);
            #pragma unroll
            for (int t = 0; t < 4; ++t)
                #pragma unroll
                for (int r = 0; r < 4; ++r)
                    crn[t][r] = Cg[obn + (size_t)(16 * w + 4 * lg + r) * 64 + 16 * t + lr];
        }

        short8 ahi[2], alo[2];
        #pragma unroll
        for (int k0 = 0; k0 < 2; ++k0) {
            const float* sp = &Sl[(16 * w + lr) * 65 + k0 * 32 + lg * 8];
            #pragma unroll
            for (int j = 0; j < 8; ++j) {
                float s = sp[j];
                unsigned short h = f2bh(s);
                ahi[k0][j] = (short)h;
                alo[k0][j] = (short)f2bh(s - b2f(h));
            }
        }

        #pragma unroll
        for (int t = 0; t < 4; ++t) {
            f32x4 nacc = cr[t];
            #pragma unroll
            for (int k0 = 0; k0 < 2; ++k0) {
                short8 bhi, blo;
                const float* pp = &PT[(16 * t + lr) * 65 + k0 * 32 + lg * 8];
                #pragma unroll
                for (int j = 0; j < 8; ++j) {
                    float p = pp[j];
                    unsigned short h = f2bh(p);
                    bhi[j] = (short)h;
                    blo[j] = (short)f2bh(p - b2f(h));
                }
                nacc = __builtin_amdgcn_mfma_f32_16x16x32_bf16(ahi[k0], bhi, nacc, 0, 0, 0);
                nacc = __builtin_amdgcn_mfma_f32_16x16x32_bf16(ahi[k0], blo, nacc, 0, 0, 0);
                nacc = __builtin_amdgcn_mfma_f32_16x16x32_bf16(alo[k0], bhi, nacc, 0, 0, 0);
            }
            acc[t] = nacc;
        }
        __syncthreads();
        #pragma unroll
        for (int u = 0; u < 4; ++u) { pr[u] = prn[u]; cr[u] = crn[u]; }
    }
}

// Phase C (512 thr): per (chain, chunk): exact recurrence from S_init, emit y & sa.
// r read directly from global (L1-hot, prefetched one step ahead) -> LDS 48KB.
__global__ __launch_bounds__(512) void kC_scan(
    const float* __restrict__ Sinit,
    const unsigned short* __restrict__ Rp, const float* __restrict__ Wp,
    const unsigned short* __restrict__ Kp, const unsigned short* __restrict__ Vp,
    const unsigned short* __restrict__ Ap, const unsigned short* __restrict__ Bp,
    float* __restrict__ Yp, float* __restrict__ SAp)
{
    __shared__ float wS[CL][64];
    __shared__ unsigned short kS[CL][64];
    __shared__ unsigned short vS[CL][64];
    __shared__ unsigned short aS[CL][64];
    __shared__ unsigned short bS[CL][64];    // 48KB

    const int tid = threadIdx.x;
    const int bx = blockIdx.x;
    const int bh = bx >> 4, c = bx & 15;
    const size_t base0 = ((size_t)(bh >> 4) * Tn + (size_t)c * CL) * Cn + (size_t)(bh & 15) * Nn;

    {
        const int t = tid >> 3, seg = (tid & 7) * 8;
        const size_t g = base0 + (size_t)t * Cn + seg;
        *(short8*)&kS[t][seg] = *(const short8*)(Kp + g);
        *(short8*)&vS[t][seg] = *(const short8*)(Vp + g);
        *(short8*)&aS[t][seg] = *(const short8*)(Ap + g);
        *(short8*)&bS[t][seg] = *(const short8*)(Bp + g);
        *(f32x4*)&wS[t][seg]     = *(const f32x4*)(Wp + g);
        *(f32x4*)&wS[t][seg + 4] = *(const f32x4*)(Wp + g + 4);
    }

    const int o = tid & 7, i = tid >> 3;
    f32x4 S0, S1;
    {
        const size_t sb = (size_t)bx * 4096 + (size_t)i * 64 + o * 8;
        S0 = *(const f32x4*)(Sinit + sb);
        S1 = *(const f32x4*)(Sinit + sb + 4);
    }
    __syncthreads();

    const unsigned short* rp = Rp + base0 + o * 8;
    float* ybase = Yp + base0 + i;
    float* sabase = SAp + base0 + i;

    short8 rnx = *(const short8*)rp;
    for (int t = 0; t < CL; ++t) {
        short8 rc = rnx;
        if (t + 1 < CL) rnx = *(const short8*)(rp + (size_t)(t + 1) * Cn);

        f32x4 a0, a1;
        cv8(*(const short8*)&aS[t][o * 8], a0, a1);
        f32x4 d = S0 * a0 + S1 * a1;
        float sa = d[0] + d[1] + d[2] + d[3];
        sa += __shfl_xor(sa, 1, 64); sa += __shfl_xor(sa, 2, 64); sa += __shfl_xor(sa, 4, 64);

        float vi = b2f(vS[t][i]);
        f32x4 k0, k1, b0, b1, r0, r1;
        cv8(*(const short8*)&kS[t][o * 8], k0, k1);
        cv8(*(const short8*)&bS[t][o * 8], b0, b1);
        cv8(rc, r0, r1);
        f32x4 w0 = *(const f32x4*)&wS[t][o * 8];
        f32x4 w1 = *(const f32x4*)&wS[t][o * 8 + 4];

        S0 = S0 * w0 + b0 * sa + k0 * vi;
        S1 = S1 * w1 + b1 * sa + k1 * vi;

        f32x4 yv = S0 * r0 + S1 * r1;
        float y = yv[0] + yv[1] + yv[2] + yv[3];
        y += __shfl_xor(y, 1, 64); y += __shfl_xor(y, 2, 64); y += __shfl_xor(y, 4, 64);

        if (o == 0) {
            ybase[(size_t)t * Cn] = y;
            sabase[(size_t)t * Cn] = sa;
        }
    }
}

// ---------- elementwise stage 2: groupnorm + bonus + (x_att*g) -> AG (bf16) ----------
__global__ __launch_bounds__(256) void k_elem2(
    const float* __restrict__ Yb, const unsigned short* __restrict__ Rb,
    const unsigned short* __restrict__ Kb, const unsigned short* __restrict__ Vb,
    const unsigned short* __restrict__ Gb,
    const float* __restrict__ gnw, const float* __restrict__ gnb,
    const float* __restrict__ rk,
    unsigned short* __restrict__ AG)
{
    int tid = threadIdx.x;
    size_t gh = (size_t)blockIdx.x * 4 + (tid >> 6);
    int lane = tid & 63;
    int h = (int)(gh & (Hn - 1));
    size_t idx = (gh >> 4) * Cn + (size_t)h * Nn + lane;
    int c = h * Nn + lane;

    float y = Yb[idx];
    float s1 = y, s2 = y * y;
    float p = b2f(Rb[idx]) * b2f(Kb[idx]) * rk[c];
    #pragma unroll
    for (int m = 1; m < 64; m <<= 1) {
        s1 += __shfl_xor(s1, m, 64);
        s2 += __shfl_xor(s2, m, 64);
        p  += __shfl_xor(p, m, 64);
    }
    float mean = s1 * (1.f / 64.f);
    float var = s2 * (1.f / 64.f) - mean * mean;
    float xn = (y - mean) * rsqrtf(var + 0.00064f) * gnw[c] + gnb[c];
    float xatt = xn + p * b2f(Vb[idx]);
    AG[idx] = f2b(xatt * b2f(Gb[idx]));
}

// ---------- layernorm of sa_out -> state_rep + fused v_first copy ----------
__global__ __launch_bounds__(256) void k_ln(
    const float* __restrict__ SAp,
    const float* __restrict__ lnw, const float* __restrict__ lnb,
    const float* __restrict__ vf_in, float* __restrict__ vf_out,
    float* __restrict__ outp)
{
    __shared__ float red1[4], red2[4];
    int tid = threadIdx.x;
    size_t row = blockIdx.x;
    // fused v_first passthrough (independent of the LN below)
    *(f32x4*)(vf_out + row * Cn + tid * 4) = *(const f32x4*)(vf_in + row * Cn + tid * 4);

    f32x4 v = *(const f32x4*)(SAp + row * Cn + tid * 4);
    float s1 = v[0] + v[1] + v[2] + v[3];
    float s2 = v[0] * v[0] + v[1] * v[1] + v[2] * v[2] + v[3] * v[3];
    #pragma unroll
    for (int m = 1; m < 64; m <<= 1) {
        s1 += __shfl_xor(s1, m, 64);
        s2 += __shfl_xor(s2, m, 64);
    }
    if ((tid & 63) == 0) { red1[tid >> 6] = s1; red2[tid >> 6] = s2; }
    __syncthreads();
    s1 = red1[0] + red1[1] + red1[2] + red1[3];
    s2 = red2[0] + red2[1] + red2[2] + red2[3];
    float mean = s1 * (1.f / 1024.f);
    float var = s2 * (1.f / 1024.f) - mean * mean;
    float rs = rsqrtf(var + 1e-5f);
    f32x4 o;
    #pragma unroll
    for (int u = 0; u < 4; ++u) {
        int c = tid * 4 + u;
        o[u] = (v[u] - mean) * rs * lnw[c] + lnb[c];
    }
    *(f32x4*)(outp + row * Cn + tid * 4) = o;
}

// ---------- launcher ----------
extern "C" void kernel_launch(void* const* d_in, const int* in_sizes, int n_in,
                              void* d_out, int out_size, void* d_ws, size_t ws_size,
                              hipStream_t stream)
{
    (void)in_sizes; (void)n_in; (void)out_size; (void)ws_size;
    const float* x      = (const float*)d_in[0];
    const float* vfirst = (const float*)d_in[1];
    const float* x_r    = (const float*)d_in[2];
    const float* x_w    = (const float*)d_in[3];
    const float* x_k    = (const float*)d_in[4];
    const float* x_v    = (const float*)d_in[5];
    const float* x_a    = (const float*)d_in[6];
    const float* x_g    = (const float*)d_in[7];
    const float* w0     = (const float*)d_in[8];
    const float* w1     = (const float*)d_in[9];
    const float* w2     = (const float*)d_in[10];
    const float* a0     = (const float*)d_in[11];
    const float* a1     = (const float*)d_in[12];
    const float* a2     = (const float*)d_in[13];
    const float* v0     = (const float*)d_in[14];
    const float* v1     = (const float*)d_in[15];
    const float* v2     = (const float*)d_in[16];
    const float* g1     = (const float*)d_in[17];
    const float* g2     = (const float*)d_in[18];
    const float* k_k    = (const float*)d_in[19];
    const float* k_a    = (const float*)d_in[20];
    const float* r_k    = (const float*)d_in[21];
    const float* Wr     = (const float*)d_in[22];
    const float* Wk     = (const float*)d_in[23];
    const float* Wv     = (const float*)d_in[24];
    const float* Wo     = (const float*)d_in[25];
    const float* gn_w   = (const float*)d_in[26];
    const float* gn_b   = (const float*)d_in[27];
    const float* ln_w   = (const float*)d_in[28];
    const float* ln_b   = (const float*)d_in[29];

    char* ws = (char*)d_ws;
    size_t off = 0;
    auto alloc = [&](size_t bytes) -> void* {
        void* p = ws + off;
        off += (bytes + 255) & ~(size_t)255;
        return p;
    };
    // bf16 big buffers (8 MiB each)
    unsigned short* Rb  = (unsigned short*)alloc(MX * 2);  // raw r; reused as AG
    unsigned short* Kb  = (unsigned short*)alloc(MX * 2);
    unsigned short* Vb  = (unsigned short*)alloc(MX * 2);
    unsigned short* SVb = (unsigned short*)alloc(MX * 2);  // v-gate sigmoid -> aa
    unsigned short* Ab  = (unsigned short*)alloc(MX * 2);  // a sigmoid -> bb
    unsigned short* Gb  = (unsigned short*)alloc(MX * 2);  // g
    float* Wdec = (float*)alloc(MX * 4);                   // decay (f32)
    float* Cg   = (float*)alloc(MX * 4);                   // chunk offsets
    // small intermediates (bf16)
    unsigned short* hw = (unsigned short*)alloc((size_t)Mrows * 64 * 2);
    unsigned short* ha = (unsigned short*)alloc((size_t)Mrows * 64 * 2);
    unsigned short* hv = (unsigned short*)alloc((size_t)Mrows * 64 * 2);
    unsigned short* hg = (unsigned short*)alloc((size_t)Mrows * 160 * 2);
    // bf16 weights
    unsigned short* WrB = (unsigned short*)alloc(1048576 * 2);
    unsigned short* WkB = (unsigned short*)alloc(1048576 * 2);
    unsigned short* WvB = (unsigned short*)alloc(1048576 * 2);
    unsigned short* WoB = (unsigned short*)alloc(1048576 * 2);
    unsigned short* w1T = (unsigned short*)alloc(65536 * 2);
    unsigned short* w2T = (unsigned short*)alloc(65536 * 2);
    unsigned short* a1T = (unsigned short*)alloc(65536 * 2);
    unsigned short* a2T = (unsigned short*)alloc(65536 * 2);
    unsigned short* v1T = (unsigned short*)alloc(65536 * 2);
    unsigned short* v2T = (unsigned short*)alloc(65536 * 2);
    unsigned short* g1T = (unsigned short*)alloc(163840 * 2);
    unsigned short* g2T = (unsigned short*)alloc(163840 * 2);
    // ~92 MiB total

    // premix buffers alias later-written regions (dead before those writes):
    unsigned short* xrB = (unsigned short*)Cg;             // dead before kA writes Cg
    unsigned short* xkB = (unsigned short*)Cg + MX;
    unsigned short* xvB = (unsigned short*)Wdec;           // dead before gemm2-Wdec
    unsigned short* xgB = (unsigned short*)Wdec + MX;
    unsigned short* xwB = Ab;                              // dead before gemm2-Ab
    unsigned short* xaB = Gb;                              // dead before gemm2-Gb

    float* out_o  = (float*)d_out;
    float* out_vf = out_o + MX;
    float* out_sr = out_o + 2 * MX;
    float* Pg    = out_o;                   // phase A transfer mats (dead after kB)
    float* Sinit = out_vf;                  // chunk-initial states (dead after kC)
    float* Yb    = out_o;                   // phase C y (consumed by k_elem2)
    float* SAb   = out_sr;                  // phase C sa (layernormed in place)
    unsigned short* AG = Rb;

    // prep
    k_mix<<<dim3(2048), 256, 0, stream>>>(x, x_r, x_w, x_k, x_v, x_a, x_g,
                                          xrB, xwB, xkB, xvB, xaB, xgB);
    k_cvt4<<<dim3(1024, 4), 256, 0, stream>>>(Wr, Wk, Wv, Wo, WrB, WkB, WvB, WoB);
    k_prep<<<dim3(2816), 256, 0, stream>>>(w1, w2, a1, a2, v1, v2, g1, g2,
                                           w1T, w2T, a1T, a2T, v1T, v2T, g1T, g2T);

    // stage-1 GEMMs (small first: consumes xw/xa/xv/xg before rkv writes R/K/V)
    gemm_small1<<<dim3(16, 3, 4), 256, 0, stream>>>(xwB, xaB, xvB, xgB,
                                                    w1T, a1T, v1T, g1T,
                                                    hw, ha, hv, hg);
    gemm_rkv<<<dim3(32, 8, 3), 256, 0, stream>>>(xrB, xkB, xvB, WrB, WkB, WvB,
                                                 Rb, Kb, Vb);

    // stage-2 small GEMMs (LDS-staged)
    gemm2<4, 1><<<dim3(32, 8), 256, 0, stream>>>(hw, 64, w2T, 64, Wdec, nullptr, Cn, w0, 64);
    gemm2<3, 0><<<dim3(32, 8), 256, 0, stream>>>(ha, 64, a2T, 64, nullptr, Ab, Cn, a0, 64);
    gemm2<3, 0><<<dim3(32, 8), 256, 0, stream>>>(hv, 64, v2T, 64, nullptr, SVb, Cn, v0, 64);
    gemm2<0, 0><<<dim3(32, 8), 256, 0, stream>>>(hg, 160, g2T, 160, nullptr, Gb, Cn, nullptr, 160);

    k_elem1<<<dim3(16384), 256, 0, stream>>>(Kb, Ab, Vb, SVb, vfirst, k_k, k_a);

    // chunked scan
    kA_chunk<<<dim3(1024), 512, 0, stream>>>(Wdec, Kb, Vb, SVb, Ab, Pg, Cg);
    kB_combine<<<dim3(64), 256, 0, stream>>>(Pg, Cg, Sinit);
    kC_scan<<<dim3(1024), 512, 0, stream>>>(Sinit, Rb, Wdec, Kb, Vb, SVb, Ab, Yb, SAb);

    k_elem2<<<dim3(16384), 256, 0, stream>>>(Yb, Rb, Kb, Vb, Gb, gn_w, gn_b, r_k, AG);

    // real outputs (k_ln also copies v_first; Sinit in out_vf is dead after kC)
    k_ln<<<dim3(4096), 256, 0, stream>>>(SAb, ln_w, ln_b, vfirst, out_vf, out_sr);
    gemm2<0, 1><<<dim3(32, 8), 256, 0, stream>>>(AG, Cn, WoB, Cn, out_o, nullptr, Cn, nullptr, Cn);
}

// Round 9
// 382.838 us; speedup vs baseline: 3.9472x; 1.0479x over previous
//
#include <hip/hip_runtime.h>
#include <hip/hip_bf16.h>
#include <cstdint>
#include <cstddef>

// ---------- types & helpers ----------
typedef __attribute__((ext_vector_type(8))) short short8;   // 8 x bf16
typedef __attribute__((ext_vector_type(4))) short short4v;  // 4 x bf16 (8B)
typedef __attribute__((ext_vector_type(4))) float f32x4;

#define DEVINL static __device__ __forceinline__

DEVINL float b2f(unsigned short u) {
    union { unsigned int i; float f; } v; v.i = ((unsigned int)u) << 16; return v.f;
}
DEVINL unsigned short f2b(float f) {
    union { float f; unsigned int i; } v; v.f = f;
    unsigned int x = v.i;
    return (unsigned short)((x + 0x7FFFu + ((x >> 16) & 1u)) >> 16);
}
// hardware cvt (compiler emits single-instr bf16 convert)
DEVINL unsigned short f2bh(float f) {
    __hip_bfloat16 h = __float2bfloat16(f);
    union { __hip_bfloat16 h; unsigned short u; } v; v.h = h; return v.u;
}
// short8 (8 bf16) -> two f32x4
DEVINL void cv8(short8 h, f32x4& lo, f32x4& hi) {
    #pragma unroll
    for (int j = 0; j < 4; ++j) {
        lo[j] = b2f((unsigned short)h[j]);
        hi[j] = b2f((unsigned short)h[j + 4]);
    }
}
// async global->LDS, 16B per lane; LDS dest is wave-uniform base + lane*16
DEVINL void stage16(const unsigned short* g, unsigned short* l) {
    __builtin_amdgcn_global_load_lds(
        (const __attribute__((address_space(1))) unsigned int*)g,
        (__attribute__((address_space(3))) unsigned int*)l,
        16, 0, 0);
}

static constexpr int Bsz = 4, Tn = 1024, Cn = 1024, Hn = 16, Nn = 64;
static constexpr int Mrows = Bsz * Tn;             // 4096
static constexpr size_t MX = (size_t)Mrows * Cn;   // 4,194,304
static constexpr int NCHUNK = 16, CL = 64;         // 16 chunks x 64 steps

// ---------- token-shift premix: f32 x -> 6 bf16 mixed buffers ----------
__global__ __launch_bounds__(256) void k_mix(
    const float* __restrict__ x,
    const float* __restrict__ mr, const float* __restrict__ mw,
    const float* __restrict__ mk, const float* __restrict__ mv,
    const float* __restrict__ ma, const float* __restrict__ mg,
    unsigned short* __restrict__ xr, unsigned short* __restrict__ xw,
    unsigned short* __restrict__ xk, unsigned short* __restrict__ xv,
    unsigned short* __restrict__ xa, unsigned short* __restrict__ xg)
{
    size_t e = ((size_t)blockIdx.x * 256 + threadIdx.x) * 8;
    if (e >= MX) return;
    int c = (int)(e & (Cn - 1));
    int t = (int)((e >> 10) & (Tn - 1));
    float xf[8], d[8];
    {
        f32x4 x0 = *(const f32x4*)(x + e);
        f32x4 x1 = *(const f32x4*)(x + e + 4);
        #pragma unroll
        for (int j = 0; j < 4; ++j) { xf[j] = x0[j]; xf[4 + j] = x1[j]; }
    }
    if (t > 0) {
        f32x4 p0 = *(const f32x4*)(x + e - Cn);
        f32x4 p1 = *(const f32x4*)(x + e - Cn + 4);
        #pragma unroll
        for (int j = 0; j < 4; ++j) { d[j] = p0[j] - xf[j]; d[4 + j] = p1[j] - xf[4 + j]; }
    } else {
        #pragma unroll
        for (int j = 0; j < 8; ++j) d[j] = -xf[j];
    }
    const float* ms[6] = { mr, mw, mk, mv, ma, mg };
    unsigned short* ds[6] = { xr, xw, xk, xv, xa, xg };
    #pragma unroll
    for (int p = 0; p < 6; ++p) {
        f32x4 m0 = *(const f32x4*)(ms[p] + c);
        f32x4 m1 = *(const f32x4*)(ms[p] + c + 4);
        short8 o;
        #pragma unroll
        for (int j = 0; j < 4; ++j) {
            o[j]     = (short)f2b(xf[j]     + d[j]     * m0[j]);
            o[4 + j] = (short)f2b(xf[4 + j] + d[4 + j] * m1[j]);
        }
        *(short8*)(ds[p] + e) = o;
    }
}

// ---------- 4 big weights f32->bf16 in one launch ----------
__global__ __launch_bounds__(256) void k_cvt4(
    const float* __restrict__ s0, const float* __restrict__ s1,
    const float* __restrict__ s2, const float* __restrict__ s3,
    unsigned short* __restrict__ d0, unsigned short* __restrict__ d1,
    unsigned short* __restrict__ d2, unsigned short* __restrict__ d3)
{
    int sel = blockIdx.y;
    const float* in = (sel == 0) ? s0 : (sel == 1) ? s1 : (sel == 2) ? s2 : s3;
    unsigned short* out = (sel == 0) ? d0 : (sel == 1) ? d1 : (sel == 2) ? d2 : d3;
    int i = (blockIdx.x * 256 + threadIdx.x) * 4;
    f32x4 v = *(const f32x4*)(in + i);
    short4v o;
    #pragma unroll
    for (int j = 0; j < 4; ++j) o[j] = (short)f2b(v[j]);
    *(short4v*)(out + i) = o;
}

// ---------- all 8 small-weight transposes (+cvt) in one launch ----------
__global__ __launch_bounds__(256) void k_prep(
    const float* __restrict__ w1, const float* __restrict__ w2,
    const float* __restrict__ a1, const float* __restrict__ a2,
    const float* __restrict__ v1, const float* __restrict__ v2,
    const float* __restrict__ g1, const float* __restrict__ g2,
    unsigned short* __restrict__ w1T, unsigned short* __restrict__ w2T,
    unsigned short* __restrict__ a1T, unsigned short* __restrict__ a2T,
    unsigned short* __restrict__ v1T, unsigned short* __restrict__ v2T,
    unsigned short* __restrict__ g1T, unsigned short* __restrict__ g2T)
{
    int idx = blockIdx.x * 256 + threadIdx.x;
    if (idx < 65536) {                       // w1 [1024][64] -> [64][1024]
        int r = idx >> 6, c = idx & 63;
        w1T[c * 1024 + r] = f2b(w1[idx]);
    } else if (idx < 131072) {               // w2 [64][1024] -> [1024][64]
        int j = idx - 65536; int r = j >> 10, c = j & 1023;
        w2T[c * 64 + r] = f2b(w2[j]);
    } else if (idx < 196608) {               // a1
        int j = idx - 131072; int r = j >> 6, c = j & 63;
        a1T[c * 1024 + r] = f2b(a1[j]);
    } else if (idx < 262144) {               // a2
        int j = idx - 196608; int r = j >> 10, c = j & 1023;
        a2T[c * 64 + r] = f2b(a2[j]);
    } else if (idx < 327680) {               // v1
        int j = idx - 262144; int r = j >> 6, c = j & 63;
        v1T[c * 1024 + r] = f2b(v1[j]);
    } else if (idx < 393216) {               // v2
        int j = idx - 327680; int r = j >> 10, c = j & 1023;
        v2T[c * 64 + r] = f2b(v2[j]);
    } else if (idx < 557056) {               // g1 [1024][160] -> [160][1024]
        int j = idx - 393216; int r = j / 160, c = j - r * 160;
        g1T[c * 1024 + r] = f2b(g1[j]);
    } else if (idx < 720896) {               // g2 [160][1024] -> [1024][160]
        int j = idx - 557056; int r = j >> 10, c = j & 1023;
        g2T[c * 160 + r] = f2b(g2[j]);
    }
}

// epi: 0=raw 1=tanh 2=sigmoid 3=bias+sigmoid 4=bias+decay
DEVINL void gemm_epi(f32x4 (&acc)[4][4], int m0, int n0, int N, int ldc,
                     float* Cf, unsigned short* Cb, const float* bias,
                     int lane, int epi, bool outf32)
{
    int r16 = lane & 15;
    #pragma unroll
    for (int mi = 0; mi < 4; ++mi)
        #pragma unroll
        for (int ni = 0; ni < 4; ++ni) {
            int col = n0 + ni * 16 + r16;
            if (col < N) {
                float bv = (epi >= 3) ? bias[col] : 0.f;
                #pragma unroll
                for (int r = 0; r < 4; ++r) {
                    int row = m0 + mi * 16 + (lane >> 4) * 4 + r;
                    float v = acc[mi][ni][r];
                    if (epi == 1) v = tanhf(v);
                    else if (epi == 2) v = 1.f / (1.f + expf(-v));
                    else if (epi == 3) { v += bv; v = 1.f / (1.f + expf(-v)); }
                    else if (epi == 4) { v += bv; v = expf(-0.60653066f / (1.f + expf(-v))); }
                    size_t o = (size_t)row * ldc + col;
                    if (outf32) Cf[o] = v; else Cb[o] = f2b(v);
                }
            }
        }
}

// ---------- LDS-staged GEMM body: 128x128 tile, BK=32, double-buffered ----------
template<int EPI, int OUTF32>
DEVINL void gemm_lds_body(const unsigned short* __restrict__ A, int lda,
                          const unsigned short* __restrict__ Bt, int ldb,
                          float* __restrict__ Cf, unsigned short* __restrict__ Cb,
                          int ldc, const float* __restrict__ bias, int K,
                          int m0, int n0)
{
    __shared__ unsigned short As[2][128 * 32];
    __shared__ unsigned short Bs[2][128 * 32];
    const int tid = threadIdx.x, wid = tid >> 6, lane = tid & 63;
    const int r16 = lane & 15, kg = lane >> 4;
    const int wr = (wid >> 1) * 64, wc = (wid & 1) * 64;

    const int srow = wid * 32 + (lane >> 2);
    const int scol = (lane & 3) * 8;
    const int lbase = wid * 1024 + lane * 8;
    const unsigned short* aS = A + (size_t)(m0 + srow) * lda + scol;
    const unsigned short* bS = Bt + (size_t)(n0 + srow) * ldb + scol;

    f32x4 acc[4][4];
    #pragma unroll
    for (int a = 0; a < 4; ++a)
        #pragma unroll
        for (int b = 0; b < 4; ++b) acc[a][b] = (f32x4){0.f, 0.f, 0.f, 0.f};

    const int nk = K >> 5;
    stage16(aS, &As[0][lbase]);
    stage16(aS + (size_t)16 * lda, &As[0][lbase + 512]);
    stage16(bS, &Bs[0][lbase]);
    stage16(bS + (size_t)16 * ldb, &Bs[0][lbase + 512]);
    __syncthreads();

    for (int kk = 0; kk < nk; ++kk) {
        const int buf = kk & 1;
        if (kk + 1 < nk) {
            const int k0 = (kk + 1) * 32;
            stage16(aS + k0, &As[buf ^ 1][lbase]);
            stage16(aS + k0 + (size_t)16 * lda, &As[buf ^ 1][lbase + 512]);
            stage16(bS + k0, &Bs[buf ^ 1][lbase]);
            stage16(bS + k0 + (size_t)16 * ldb, &Bs[buf ^ 1][lbase + 512]);
        }
        short8 af[4], bf[4];
        #pragma unroll
        for (int mi = 0; mi < 4; ++mi)
            af[mi] = *(const short8*)&As[buf][(wr + mi * 16 + r16) * 32 + kg * 8];
        #pragma unroll
        for (int ni = 0; ni < 4; ++ni)
            bf[ni] = *(const short8*)&Bs[buf][(wc + ni * 16 + r16) * 32 + kg * 8];
        #pragma unroll
        for (int mi = 0; mi < 4; ++mi)
            #pragma unroll
            for (int ni = 0; ni < 4; ++ni)
                acc[mi][ni] = __builtin_amdgcn_mfma_f32_16x16x32_bf16(af[mi], bf[ni], acc[mi][ni], 0, 0, 0);
        __syncthreads();
    }
    gemm_epi(acc, m0 + wr, n0 + wc, 1 << 30, ldc, Cf, Cb, bias, lane, EPI, OUTF32 != 0);
}

// ---------- R/K/V GEMMs in one launch (grid.z selects), LDS-staged ----------
__global__ __launch_bounds__(256) void gemm_rkv(
    const unsigned short* __restrict__ A0, const unsigned short* __restrict__ A1,
    const unsigned short* __restrict__ A2,
    const unsigned short* __restrict__ B0, const unsigned short* __restrict__ B1,
    const unsigned short* __restrict__ B2,
    unsigned short* __restrict__ D0, unsigned short* __restrict__ D1,
    unsigned short* __restrict__ D2)
{
    int z = blockIdx.z;
    const unsigned short* A = (z == 0) ? A0 : (z == 1) ? A1 : A2;
    const unsigned short* Bt = (z == 0) ? B0 : (z == 1) ? B1 : B2;
    unsigned short* D = (z == 0) ? D0 : (z == 1) ? D1 : D2;
    gemm_lds_body<0, 0>(A, Cn, Bt, Cn, nullptr, D, Cn, nullptr, Cn,
                        blockIdx.x * 128, blockIdx.y * 128);
}

// ---------- generic LDS-staged 128x128 GEMM (stage-2 + Wo) ----------
template<int EPI, int OUTF32>
__global__ __launch_bounds__(256) void gemm2(
    const unsigned short* __restrict__ A, int lda,
    const unsigned short* __restrict__ Bt, int ldb,
    float* __restrict__ Cf, unsigned short* __restrict__ Cb, int ldc,
    const float* __restrict__ bias, int K)
{
    gemm_lds_body<EPI, OUTF32>(A, lda, Bt, ldb, Cf, Cb, ldc, bias, K,
                               blockIdx.x * 128, blockIdx.y * 128);
}

// ---------- direct-global MFMA core (kept for tall-skinny stage-1) ----------
DEVINL void gemm_core(const unsigned short* __restrict__ A, int lda,
                      const unsigned short* __restrict__ Bt, int ldb,
                      int m0, int n0, int N, int K, int r16, int k8,
                      f32x4 (&acc)[4][4])
{
    for (int k0 = 0; k0 < K; k0 += 32) {
        short8 af[4], bf[4];
        #pragma unroll
        for (int mi = 0; mi < 4; ++mi)
            af[mi] = *(const short8*)(A + (size_t)(m0 + mi * 16 + r16) * lda + k0 + k8);
        #pragma unroll
        for (int ni = 0; ni < 4; ++ni) {
            int rn = n0 + ni * 16 + r16;
            if (rn >= N) rn = N - 1;
            bf[ni] = *(const short8*)(Bt + (size_t)rn * ldb + k0 + k8);
        }
        #pragma unroll
        for (int mi = 0; mi < 4; ++mi)
            #pragma unroll
            for (int ni = 0; ni < 4; ++ni)
                acc[mi][ni] = __builtin_amdgcn_mfma_f32_16x16x32_bf16(af[mi], bf[ni], acc[mi][ni], 0, 0, 0);
    }
}

// ---------- four tall-skinny stage-1 GEMMs in one launch ----------
__global__ __launch_bounds__(256) void gemm_small1(
    const unsigned short* __restrict__ Aw, const unsigned short* __restrict__ Aa,
    const unsigned short* __restrict__ Av, const unsigned short* __restrict__ Ag,
    const unsigned short* __restrict__ Bw, const unsigned short* __restrict__ Ba,
    const unsigned short* __restrict__ Bv, const unsigned short* __restrict__ Bg,
    unsigned short* __restrict__ Dw, unsigned short* __restrict__ Da,
    unsigned short* __restrict__ Dv, unsigned short* __restrict__ Dg)
{
    int z = blockIdx.z;
    if (z < 3 && blockIdx.y > 0) return;
    const unsigned short* A = (z == 0) ? Aw : (z == 1) ? Aa : (z == 2) ? Av : Ag;
    const unsigned short* Bt = (z == 0) ? Bw : (z == 1) ? Ba : (z == 2) ? Bv : Bg;
    unsigned short* D = (z == 0) ? Dw : (z == 1) ? Da : (z == 2) ? Dv : Dg;
    const int N = (z == 3) ? 160 : 64;
    const int epi = (z == 0) ? 1 : (z == 3) ? 2 : 0;
    const int tid = threadIdx.x, wid = tid >> 6, lane = tid & 63;
    const int r16 = lane & 15, k8 = (lane >> 4) * 8;
    const int m0 = blockIdx.x * 256 + wid * 64;
    const int n0 = blockIdx.y * 64;
    f32x4 acc[4][4];
    #pragma unroll
    for (int a = 0; a < 4; ++a)
        #pragma unroll
        for (int b = 0; b < 4; ++b) acc[a][b] = (f32x4){0.f, 0.f, 0.f, 0.f};
    gemm_core(A, Cn, Bt, Cn, m0, n0, N, Cn, r16, k8, acc);
    gemm_epi(acc, m0, n0, N, N, nullptr, D, nullptr, lane, epi, false);
}

// ---------- elementwise stage 1 (bf16 buffers in place; vfirst f32) ----------
__global__ __launch_bounds__(256) void k_elem1(
    unsigned short* __restrict__ Kb, unsigned short* __restrict__ Ab,
    unsigned short* __restrict__ Vb, unsigned short* __restrict__ SVb,
    const float* __restrict__ v_first,
    const float* __restrict__ kkw, const float* __restrict__ kaw)
{
    int tid = threadIdx.x;
    size_t gh = (size_t)blockIdx.x * 4 + (tid >> 6);   // 0 .. B*T*H-1
    int lane = tid & 63;
    int h = (int)(gh & (Hn - 1));
    size_t idx = (gh >> 4) * Cn + (size_t)h * Nn + lane;
    int c = h * Nn + lane;

    float kp = b2f(Kb[idx]);
    float kkv = kp * kkw[c];
    float s = kkv * kkv;
    #pragma unroll
    for (int m = 1; m < 64; m <<= 1) s += __shfl_xor(s, m, 64);
    float kk = kkv / fmaxf(sqrtf(s), 1e-12f);

    float a = b2f(Ab[idx]);
    float kf = kp * (1.f + (a - 1.f) * kaw[c]);
    float vp = b2f(Vb[idx]), sv = b2f(SVb[idx]), vf = v_first[idx];
    float vfin = vp + (vf - vp) * sv;

    Kb[idx] = f2b(kf);
    Vb[idx] = f2b(vfin);
    SVb[idx] = f2b(-kk);
    Ab[idx] = f2b(kk * a);
}

// ================= chunked scan =================
// Phase A2 (512 thr): per (chain, chunk): zero-init recurrence producing
//   P (prefix transfer product), Z (zero-init state), and per step:
//   sa0_t = Z_{t-1}a_t  -> SAp     (exact sa for S0=0)
//   q_t   = P_{t-1}a_t  -> Qg      (correction basis: sa_t = sa0_t + S0 q_t)
//   y0_t  = Z_t r_t     -> Yp
//   g_t   = P_t r_t     -> Gg      (y_t = y0_t + S0 g_t)
// Thread (i=tid>>3, o=tid&7) owns row i, cols o*8..o*8+8.
__global__ __launch_bounds__(512) void kA_chunk(
    const float* __restrict__ Wp, const unsigned short* __restrict__ Kp,
    const unsigned short* __restrict__ Vp, const unsigned short* __restrict__ Ap,
    const unsigned short* __restrict__ Bp, const unsigned short* __restrict__ Rp,
    float* __restrict__ Pg, float* __restrict__ Cg,
    float* __restrict__ Qg, float* __restrict__ Gg,
    float* __restrict__ Yp, float* __restrict__ SAp)
{
    __shared__ float wS[CL][64];             // 16KB
    __shared__ unsigned short kS[CL][64];    // 8KB each
    __shared__ unsigned short vS[CL][64];
    __shared__ unsigned short aS[CL][64];
    __shared__ unsigned short bS[CL][64];    // total 48KB -> 3 blocks/CU

    const int tid = threadIdx.x;
    const int bx = blockIdx.x;
    const int bh = bx >> 4, c = bx & 15;
    const size_t base0 = ((size_t)(bh >> 4) * Tn + (size_t)c * CL) * Cn + (size_t)(bh & 15) * Nn;

    {
        const int t = tid >> 3, seg = (tid & 7) * 8;
        const size_t g = base0 + (size_t)t * Cn + seg;
        *(short8*)&kS[t][seg] = *(const short8*)(Kp + g);
        *(short8*)&vS[t][seg] = *(const short8*)(Vp + g);
        *(short8*)&aS[t][seg] = *(const short8*)(Ap + g);
        *(short8*)&bS[t][seg] = *(const short8*)(Bp + g);
        *(f32x4*)&wS[t][seg]     = *(const f32x4*)(Wp + g);
        *(f32x4*)&wS[t][seg + 4] = *(const f32x4*)(Wp + g + 4);
    }
    __syncthreads();

    const int o = tid & 7, i = tid >> 3;
    f32x4 P0, P1, C0, C1;
    #pragma unroll
    for (int u = 0; u < 4; ++u) {
        P0[u] = (o * 8 + u == i) ? 1.f : 0.f;
        P1[u] = (o * 8 + 4 + u == i) ? 1.f : 0.f;
    }
    C0 = (f32x4){0.f, 0.f, 0.f, 0.f};
    C1 = C0;

    const unsigned short* rp = Rp + base0 + o * 8;
    float* ybase = Yp + base0 + i;
    float* sabase = SAp + base0 + i;
    float* qbase = Qg + (size_t)bx * 4096 + i;
    float* gbase = Gg + (size_t)bx * 4096 + i;

    short8 rnx = *(const short8*)rp;
    for (int t = 0; t < CL; ++t) {
        short8 rc = rnx;
        if (t + 1 < CL) rnx = *(const short8*)(rp + (size_t)(t + 1) * Cn);

        f32x4 a0, a1;
        cv8(*(const short8*)&aS[t][o * 8], a0, a1);
        f32x4 dp = P0 * a0 + P1 * a1;
        f32x4 dc = C0 * a0 + C1 * a1;
        float pa = dp[0] + dp[1] + dp[2] + dp[3];
        float ca = dc[0] + dc[1] + dc[2] + dc[3];
        pa += __shfl_xor(pa, 1, 64); pa += __shfl_xor(pa, 2, 64); pa += __shfl_xor(pa, 4, 64);
        ca += __shfl_xor(ca, 1, 64); ca += __shfl_xor(ca, 2, 64); ca += __shfl_xor(ca, 4, 64);

        float vi = b2f(vS[t][i]);
        f32x4 k0, k1, b0, b1, r0, r1;
        cv8(*(const short8*)&kS[t][o * 8], k0, k1);
        cv8(*(const short8*)&bS[t][o * 8], b0, b1);
        cv8(rc, r0, r1);
        f32x4 w0 = *(const f32x4*)&wS[t][o * 8];
        f32x4 w1 = *(const f32x4*)&wS[t][o * 8 + 4];

        C0 = C0 * w0 + b0 * ca + k0 * vi;
        C1 = C1 * w1 + b1 * ca + k1 * vi;
        P0 = P0 * w0 + b0 * pa;
        P1 = P1 * w1 + b1 * pa;

        f32x4 yv = C0 * r0 + C1 * r1;
        f32x4 gv = P0 * r0 + P1 * r1;
        float y = yv[0] + yv[1] + yv[2] + yv[3];
        float g = gv[0] + gv[1] + gv[2] + gv[3];
        y += __shfl_xor(y, 1, 64); y += __shfl_xor(y, 2, 64); y += __shfl_xor(y, 4, 64);
        g += __shfl_xor(g, 1, 64); g += __shfl_xor(g, 2, 64); g += __shfl_xor(g, 4, 64);

        if (o == 0) {
            ybase[(size_t)t * Cn] = y;
            sabase[(size_t)t * Cn] = ca;
            qbase[t * 64] = pa;
            gbase[t * 64] = g;
        }
    }

    const size_t ob = (size_t)bx * 4096 + (size_t)i * 64 + o * 8;
    *(f32x4*)(Pg + ob)     = P0;
    *(f32x4*)(Pg + ob + 4) = P1;
    *(f32x4*)(Cg + ob)     = C0;
    *(f32x4*)(Cg + ob + 4) = C1;
}

// Phase B (MFMA): sequential chunk combine S <- S*P_c + C_c via matrix pipe.
__global__ __launch_bounds__(256, 1) void kB_combine(
    const float* __restrict__ Pg, const float* __restrict__ Cg,
    float* __restrict__ Sinit)
{
    __shared__ float Sl[64 * 65];
    __shared__ float PT[64 * 65];
    const int tid = threadIdx.x;
    const int w = tid >> 6;
    const int l = tid & 63;
    const int lr = l & 15;
    const int lg = l >> 4;
    const int bh = blockIdx.x;

    f32x4 acc[4];
    #pragma unroll
    for (int t = 0; t < 4; ++t) acc[t] = (f32x4){0.f, 0.f, 0.f, 0.f};

    f32x4 pr[4]; f32x4 cr[4];
    {
        const size_t ob = (size_t)(bh * 16) * 4096;
        #pragma unroll
        for (int u = 0; u < 4; ++u)
            pr[u] = *(const f32x4*)(Pg + ob + (size_t)tid * 16 + u * 4);
        #pragma unroll
        for (int t = 0; t < 4; ++t)
            #pragma unroll
            for (int r = 0; r < 4; ++r)
                cr[t][r] = Cg[ob + (size_t)(16 * w + 4 * lg + r) * 64 + 16 * t + lr];
    }

    for (int c = 0; c < NCHUNK; ++c) {
        const size_t ob = (size_t)(bh * 16 + c) * 4096;
        #pragma unroll
        for (int t = 0; t < 4; ++t)
            #pragma unroll
            for (int r = 0; r < 4; ++r)
                Sinit[ob + (size_t)(16 * w + 4 * lg + r) * 64 + 16 * t + lr] = acc[t][r];
        if (c == NCHUNK - 1) break;

        #pragma unroll
        for (int t = 0; t < 4; ++t)
            #pragma unroll
            for (int r = 0; r < 4; ++r)
                Sl[(16 * w + 4 * lg + r) * 65 + 16 * t + lr] = acc[t][r];
        {
            const int m = tid >> 2, j0 = (tid & 3) * 16;
            #pragma unroll
            for (int u = 0; u < 4; ++u)
                #pragma unroll
                for (int e = 0; e < 4; ++e)
                    PT[(j0 + u * 4 + e) * 65 + m] = pr[u][e];
        }
        __syncthreads();

        f32x4 prn[4] = {}, crn[4] = {};
        if (c + 1 < NCHUNK - 1) {
            const size_t obn = (size_t)(bh * 16 + c + 1) * 4096;
            #pragma unroll
            for (int u = 0; u < 4; ++u)
                prn[u] = *(const f32x4*)(Pg + obn + (size_t)tid * 16 + u * 4);
            #pragma unroll
            for (int t = 0; t < 4; ++t)
                #pragma unroll
                for (int r = 0; r < 4; ++r)
                    crn[t][r] = Cg[obn + (size_t)(16 * w + 4 * lg + r) * 64 + 16 * t + lr];
        }

        short8 ahi[2], alo[2];
        #pragma unroll
        for (int k0 = 0; k0 < 2; ++k0) {
            const float* sp = &Sl[(16 * w + lr) * 65 + k0 * 32 + lg * 8];
            #pragma unroll
            for (int j = 0; j < 8; ++j) {
                float s = sp[j];
                unsigned short h = f2bh(s);
                ahi[k0][j] = (short)h;
                alo[k0][j] = (short)f2bh(s - b2f(h));
            }
        }

        #pragma unroll
        for (int t = 0; t < 4; ++t) {
            f32x4 nacc = cr[t];
            #pragma unroll
            for (int k0 = 0; k0 < 2; ++k0) {
                short8 bhi, blo;
                const float* pp = &PT[(16 * t + lr) * 65 + k0 * 32 + lg * 8];
                #pragma unroll
                for (int j = 0; j < 8; ++j) {
                    float p = pp[j];
                    unsigned short h = f2bh(p);
                    bhi[j] = (short)h;
                    blo[j] = (short)f2bh(p - b2f(h));
                }
                nacc = __builtin_amdgcn_mfma_f32_16x16x32_bf16(ahi[k0], bhi, nacc, 0, 0, 0);
                nacc = __builtin_amdgcn_mfma_f32_16x16x32_bf16(ahi[k0], blo, nacc, 0, 0, 0);
                nacc = __builtin_amdgcn_mfma_f32_16x16x32_bf16(alo[k0], bhi, nacc, 0, 0, 0);
            }
            acc[t] = nacc;
        }
        __syncthreads();
        #pragma unroll
        for (int u = 0; u < 4; ++u) { pr[u] = prn[u]; cr[u] = crn[u]; }
    }
}

// Phase D (MFMA): exact correction per (chain, chunk>=1):
//   SA_chunk[t][i] += sum_l Q[t][l] * S0[i][l]
//   Y_chunk[t][i]  += sum_l G[t][l] * S0[i][l]
// hi/lo bf16 split on both operands (3-term) for ~f32 accuracy.
__global__ __launch_bounds__(256) void kD_corr(
    const float* __restrict__ Sinit, const float* __restrict__ Qg,
    const float* __restrict__ Gg,
    float* __restrict__ SAp, float* __restrict__ Yp)
{
    __shared__ float Ql[64 * 65];
    __shared__ float Gl[64 * 65];
    __shared__ float S0l[64 * 65];
    const int tid = threadIdx.x;
    const int bx = blockIdx.x;          // 0..959
    const int bh = bx / 15;
    const int c  = 1 + bx % 15;
    const size_t mb = (size_t)(bh * 16 + c) * 4096;
    const size_t base0 = ((size_t)(bh >> 4) * Tn + (size_t)c * CL) * Cn + (size_t)(bh & 15) * Nn;

    {
        const int r = tid >> 2, c4 = (tid & 3) * 16;
        #pragma unroll
        for (int u = 0; u < 4; ++u) {
            *(f32x4*)&Ql[r * 65 + c4 + u * 4]  = *(const f32x4*)(Qg + mb + (size_t)r * 64 + c4 + u * 4);
            *(f32x4*)&Gl[r * 65 + c4 + u * 4]  = *(const f32x4*)(Gg + mb + (size_t)r * 64 + c4 + u * 4);
            *(f32x4*)&S0l[r * 65 + c4 + u * 4] = *(const f32x4*)(Sinit + mb + (size_t)r * 64 + c4 + u * 4);
        }
    }
    __syncthreads();

    const int w = tid >> 6, l = tid & 63, lr = l & 15, lg = l >> 4;

    // A-frags (rows 16w+lr of Q and G), hi/lo
    short8 qhi[2], qlo[2], ghi[2], glo[2];
    #pragma unroll
    for (int k0 = 0; k0 < 2; ++k0) {
        const float* qp = &Ql[(16 * w + lr) * 65 + k0 * 32 + lg * 8];
        const float* gp = &Gl[(16 * w + lr) * 65 + k0 * 32 + lg * 8];
        #pragma unroll
        for (int j = 0; j < 8; ++j) {
            float q = qp[j];
            unsigned short h = f2bh(q);
            qhi[k0][j] = (short)h;
            qlo[k0][j] = (short)f2bh(q - b2f(h));
            float g = gp[j];
            unsigned short h2 = f2bh(g);
            ghi[k0][j] = (short)h2;
            glo[k0][j] = (short)f2bh(g - b2f(h2));
        }
    }

    #pragma unroll
    for (int tt = 0; tt < 4; ++tt) {
        f32x4 accQ = (f32x4){0.f, 0.f, 0.f, 0.f};
        f32x4 accG = (f32x4){0.f, 0.f, 0.f, 0.f};
        #pragma unroll
        for (int k0 = 0; k0 < 2; ++k0) {
            short8 bhi, blo;
            const float* sp = &S0l[(16 * tt + lr) * 65 + k0 * 32 + lg * 8];
            #pragma unroll
            for (int j = 0; j < 8; ++j) {
                float s = sp[j];
                unsigned short h = f2bh(s);
                bhi[j] = (short)h;
                blo[j] = (short)f2bh(s - b2f(h));
            }
            accQ = __builtin_amdgcn_mfma_f32_16x16x32_bf16(qhi[k0], bhi, accQ, 0, 0, 0);
            accQ = __builtin_amdgcn_mfma_f32_16x16x32_bf16(qhi[k0], blo, accQ, 0, 0, 0);
            accQ = __builtin_amdgcn_mfma_f32_16x16x32_bf16(qlo[k0], bhi, accQ, 0, 0, 0);
            accG = __builtin_amdgcn_mfma_f32_16x16x32_bf16(ghi[k0], bhi, accG, 0, 0, 0);
            accG = __builtin_amdgcn_mfma_f32_16x16x32_bf16(ghi[k0], blo, accG, 0, 0, 0);
            accG = __builtin_amdgcn_mfma_f32_16x16x32_bf16(glo[k0], bhi, accG, 0, 0, 0);
        }
        #pragma unroll
        for (int r = 0; r < 4; ++r) {
            const size_t off = base0 + (size_t)(16 * w + 4 * lg + r) * Cn + 16 * tt + lr;
            SAp[off] += accQ[r];
            Yp[off]  += accG[r];
        }
    }
}

// ---------- elementwise stage 2: groupnorm + bonus + (x_att*g) -> AG (bf16) ----------
__global__ __launch_bounds__(256) void k_elem2(
    const float* __restrict__ Yb, const unsigned short* __restrict__ Rb,
    const unsigned short* __restrict__ Kb, const unsigned short* __restrict__ Vb,
    const unsigned short* __restrict__ Gb,
    const float* __restrict__ gnw, const float* __restrict__ gnb,
    const float* __restrict__ rk,
    unsigned short* __restrict__ AG)
{
    int tid = threadIdx.x;
    size_t gh = (size_t)blockIdx.x * 4 + (tid >> 6);
    int lane = tid & 63;
    int h = (int)(gh & (Hn - 1));
    size_t idx = (gh >> 4) * Cn + (size_t)h * Nn + lane;
    int c = h * Nn + lane;

    float y = Yb[idx];
    float s1 = y, s2 = y * y;
    float p = b2f(Rb[idx]) * b2f(Kb[idx]) * rk[c];
    #pragma unroll
    for (int m = 1; m < 64; m <<= 1) {
        s1 += __shfl_xor(s1, m, 64);
        s2 += __shfl_xor(s2, m, 64);
        p  += __shfl_xor(p, m, 64);
    }
    float mean = s1 * (1.f / 64.f);
    float var = s2 * (1.f / 64.f) - mean * mean;
    float xn = (y - mean) * rsqrtf(var + 0.00064f) * gnw[c] + gnb[c];
    float xatt = xn + p * b2f(Vb[idx]);
    AG[idx] = f2b(xatt * b2f(Gb[idx]));
}

// ---------- layernorm of sa_out -> state_rep + fused v_first copy ----------
__global__ __launch_bounds__(256) void k_ln(
    const float* __restrict__ SAp,
    const float* __restrict__ lnw, const float* __restrict__ lnb,
    const float* __restrict__ vf_in, float* __restrict__ vf_out,
    float* __restrict__ outp)
{
    __shared__ float red1[4], red2[4];
    int tid = threadIdx.x;
    size_t row = blockIdx.x;
    *(f32x4*)(vf_out + row * Cn + tid * 4) = *(const f32x4*)(vf_in + row * Cn + tid * 4);

    f32x4 v = *(const f32x4*)(SAp + row * Cn + tid * 4);
    float s1 = v[0] + v[1] + v[2] + v[3];
    float s2 = v[0] * v[0] + v[1] * v[1] + v[2] * v[2] + v[3] * v[3];
    #pragma unroll
    for (int m = 1; m < 64; m <<= 1) {
        s1 += __shfl_xor(s1, m, 64);
        s2 += __shfl_xor(s2, m, 64);
    }
    if ((tid & 63) == 0) { red1[tid >> 6] = s1; red2[tid >> 6] = s2; }
    __syncthreads();
    s1 = red1[0] + red1[1] + red1[2] + red1[3];
    s2 = red2[0] + red2[1] + red2[2] + red2[3];
    float mean = s1 * (1.f / 1024.f);
    float var = s2 * (1.f / 1024.f) - mean * mean;
    float rs = rsqrtf(var + 1e-5f);
    f32x4 o;
    #pragma unroll
    for (int u = 0; u < 4; ++u) {
        int c = tid * 4 + u;
        o[u] = (v[u] - mean) * rs * lnw[c] + lnb[c];
    }
    *(f32x4*)(outp + row * Cn + tid * 4) = o;
}

// ---------- launcher ----------
extern "C" void kernel_launch(void* const* d_in, const int* in_sizes, int n_in,
                              void* d_out, int out_size, void* d_ws, size_t ws_size,
                              hipStream_t stream)
{
    (void)in_sizes; (void)n_in; (void)out_size; (void)ws_size;
    const float* x      = (const float*)d_in[0];
    const float* vfirst = (const float*)d_in[1];
    const float* x_r    = (const float*)d_in[2];
    const float* x_w    = (const float*)d_in[3];
    const float* x_k    = (const float*)d_in[4];
    const float* x_v    = (const float*)d_in[5];
    const float* x_a    = (const float*)d_in[6];
    const float* x_g    = (const float*)d_in[7];
    const float* w0     = (const float*)d_in[8];
    const float* w1     = (const float*)d_in[9];
    const float* w2     = (const float*)d_in[10];
    const float* a0     = (const float*)d_in[11];
    const float* a1     = (const float*)d_in[12];
    const float* a2     = (const float*)d_in[13];
    const float* v0     = (const float*)d_in[14];
    const float* v1     = (const float*)d_in[15];
    const float* v2     = (const float*)d_in[16];
    const float* g1     = (const float*)d_in[17];
    const float* g2     = (const float*)d_in[18];
    const float* k_k    = (const float*)d_in[19];
    const float* k_a    = (const float*)d_in[20];
    const float* r_k    = (const float*)d_in[21];
    const float* Wr     = (const float*)d_in[22];
    const float* Wk     = (const float*)d_in[23];
    const float* Wv     = (const float*)d_in[24];
    const float* Wo     = (const float*)d_in[25];
    const float* gn_w   = (const float*)d_in[26];
    const float* gn_b   = (const float*)d_in[27];
    const float* ln_w   = (const float*)d_in[28];
    const float* ln_b   = (const float*)d_in[29];

    char* ws = (char*)d_ws;
    size_t off = 0;
    auto alloc = [&](size_t bytes) -> void* {
        void* p = ws + off;
        off += (bytes + 255) & ~(size_t)255;
        return p;
    };
    // bf16 big buffers (8 MiB each)
    unsigned short* Rb  = (unsigned short*)alloc(MX * 2);  // raw r; reused as AG
    unsigned short* Kb  = (unsigned short*)alloc(MX * 2);
    unsigned short* Vb  = (unsigned short*)alloc(MX * 2);
    unsigned short* SVb = (unsigned short*)alloc(MX * 2);  // v-gate sigmoid -> aa
    unsigned short* Ab  = (unsigned short*)alloc(MX * 2);  // a sigmoid -> bb
    unsigned short* Gb  = (unsigned short*)alloc(MX * 2);  // g
    float* Wdec = (float*)alloc(MX * 4);                   // decay (f32)
    float* Cg   = (float*)alloc(MX * 4);                   // chunk offsets Z
    float* Pg   = (float*)alloc(MX * 4);                   // chunk transfer mats
    float* Qg   = (float*)alloc(MX * 4);                   // q_t vectors
    float* Gg   = (float*)alloc(MX * 4);                   // g_t vectors
    // small intermediates (bf16)
    unsigned short* hw = (unsigned short*)alloc((size_t)Mrows * 64 * 2);
    unsigned short* ha = (unsigned short*)alloc((size_t)Mrows * 64 * 2);
    unsigned short* hv = (unsigned short*)alloc((size_t)Mrows * 64 * 2);
    unsigned short* hg = (unsigned short*)alloc((size_t)Mrows * 160 * 2);
    // bf16 weights
    unsigned short* WrB = (unsigned short*)alloc(1048576 * 2);
    unsigned short* WkB = (unsigned short*)alloc(1048576 * 2);
    unsigned short* WvB = (unsigned short*)alloc(1048576 * 2);
    unsigned short* WoB = (unsigned short*)alloc(1048576 * 2);
    unsigned short* w1T = (unsigned short*)alloc(65536 * 2);
    unsigned short* w2T = (unsigned short*)alloc(65536 * 2);
    unsigned short* a1T = (unsigned short*)alloc(65536 * 2);
    unsigned short* a2T = (unsigned short*)alloc(65536 * 2);
    unsigned short* v1T = (unsigned short*)alloc(65536 * 2);
    unsigned short* v2T = (unsigned short*)alloc(65536 * 2);
    unsigned short* g1T = (unsigned short*)alloc(163840 * 2);
    unsigned short* g2T = (unsigned short*)alloc(163840 * 2);
    // ~140 MiB total

    // premix buffers alias later-written regions (dead before those writes):
    unsigned short* xrB = (unsigned short*)Cg;             // dead before kA writes Cg
    unsigned short* xkB = (unsigned short*)Cg + MX;
    unsigned short* xvB = (unsigned short*)Wdec;           // dead before gemm2-Wdec
    unsigned short* xgB = (unsigned short*)Wdec + MX;
    unsigned short* xwB = Ab;                              // dead before gemm2-Ab
    unsigned short* xaB = Gb;                              // dead before gemm2-Gb

    float* out_o  = (float*)d_out;
    float* out_vf = out_o + MX;
    float* out_sr = out_o + 2 * MX;
    float* Sinit = out_vf;                  // chunk-initial states (dead after kD)
    float* Yb    = out_o;                   // y0 + corrections (consumed by k_elem2)
    float* SAb   = out_sr;                  // sa0 + corrections (LN'd in place)
    unsigned short* AG = Rb;

    // prep
    k_mix<<<dim3(2048), 256, 0, stream>>>(x, x_r, x_w, x_k, x_v, x_a, x_g,
                                          xrB, xwB, xkB, xvB, xaB, xgB);
    k_cvt4<<<dim3(1024, 4), 256, 0, stream>>>(Wr, Wk, Wv, Wo, WrB, WkB, WvB, WoB);
    k_prep<<<dim3(2816), 256, 0, stream>>>(w1, w2, a1, a2, v1, v2, g1, g2,
                                           w1T, w2T, a1T, a2T, v1T, v2T, g1T, g2T);

    // stage-1 GEMMs (small first: consumes xw/xa/xv/xg before rkv writes R/K/V)
    gemm_small1<<<dim3(16, 3, 4), 256, 0, stream>>>(xwB, xaB, xvB, xgB,
                                                    w1T, a1T, v1T, g1T,
                                                    hw, ha, hv, hg);
    gemm_rkv<<<dim3(32, 8, 3), 256, 0, stream>>>(xrB, xkB, xvB, WrB, WkB, WvB,
                                                 Rb, Kb, Vb);

    // stage-2 small GEMMs (LDS-staged)
    gemm2<4, 1><<<dim3(32, 8), 256, 0, stream>>>(hw, 64, w2T, 64, Wdec, nullptr, Cn, w0, 64);
    gemm2<3, 0><<<dim3(32, 8), 256, 0, stream>>>(ha, 64, a2T, 64, nullptr, Ab, Cn, a0, 64);
    gemm2<3, 0><<<dim3(32, 8), 256, 0, stream>>>(hv, 64, v2T, 64, nullptr, SVb, Cn, v0, 64);
    gemm2<0, 0><<<dim3(32, 8), 256, 0, stream>>>(hg, 160, g2T, 160, nullptr, Gb, Cn, nullptr, 160);

    k_elem1<<<dim3(16384), 256, 0, stream>>>(Kb, Ab, Vb, SVb, vfirst, k_k, k_a);

    // chunked scan: A2 (zero-init recurrence + outputs), B (combine), D (correct)
    kA_chunk<<<dim3(1024), 512, 0, stream>>>(Wdec, Kb, Vb, SVb, Ab, Rb,
                                             Pg, Cg, Qg, Gg, Yb, SAb);
    kB_combine<<<dim3(64), 256, 0, stream>>>(Pg, Cg, Sinit);
    kD_corr<<<dim3(960), 256, 0, stream>>>(Sinit, Qg, Gg, SAb, Yb);

    k_elem2<<<dim3(16384), 256, 0, stream>>>(Yb, Rb, Kb, Vb, Gb, gn_w, gn_b, r_k, AG);

    // real outputs (k_ln also copies v_first; Sinit in out_vf is dead after kD)
    k_ln<<<dim3(4096), 256, 0, stream>>>(SAb, ln_w, ln_b, vfirst, out_vf, out_sr);
    gemm2<0, 1><<<dim3(32, 8), 256, 0, stream>>>(AG, Cn, WoB, Cn, out_o, nullptr, Cn, nullptr, Cn);
}